// Round 1
// baseline (1332.230 us; speedup 1.0000x reference)
//
#include <hip/hip_runtime.h>

// Problem constants
#define BATCH 4096
#define SEQL  60
#define VOC   512
#define EMBD  128
#define HID   64
#define GATES 256

__device__ __forceinline__ float sigm(float x) {
  return __builtin_amdgcn_rcpf(1.f + __expf(-x));
}
__device__ __forceinline__ float tanh_(float x) {
  float e = __expf(2.f * x);
  return 1.f - 2.f * __builtin_amdgcn_rcpf(e + 1.f);
}

// ---------------------------------------------------------------------------
// Kernel 1: per-row sequence statistics. One thread per row, 64 rows/block.
// Mirrors _sequence_stats exactly. Exports entropy, raw vlen, pattern[6],
// complexity[4], and raw counts (bytes) for the c-MLP.
// ---------------------------------------------------------------------------
__global__ __launch_bounds__(64) void k_stats(
    const int* __restrict__ x,
    float* __restrict__ ent_o, float* __restrict__ vlen_o,
    float* __restrict__ pat_o, float* __restrict__ cpx_o,
    unsigned int* __restrict__ cnt_o) {
  __shared__ unsigned char cnt[64 * 516];     // per-thread 512B counts (+4 pad)
  __shared__ unsigned short cs[64 * 60];      // per-thread compacted sequence
  const int tid = threadIdx.x;
  const int row = blockIdx.x * 64 + tid;
  unsigned char* c = cnt + tid * 516;
  unsigned short* q = cs + tid * 60;
  unsigned int* cw = (unsigned int*)c;
  for (int i = 0; i < 129; i++) cw[i] = 0u;

  const int* xr = x + row * SEQL;
  int n = 0;
  for (int t = 0; t < SEQL; t++) {
    int v = xr[t];
    if (v != 0) { q[n] = (unsigned short)v; n++; c[v] = (unsigned char)(c[v] + 1); }
  }
  float vlenf = (float)(n >= 1 ? n : 1);
  float inv = 1.f / vlenf;

  float ent = 0.f; int distinct = 0;
  for (int v = 0; v < VOC; v++) {
    int cv = c[v];
    if (cv) {
      distinct++;
      float p = (float)cv * inv;
      ent -= p * __logf(p + 1e-8f);
    }
  }
  int rep = 0, incs = 0, decs = 0, per2 = 0;
  for (int i = 0; i + 1 < n; i++) {
    int a = q[i], b = q[i + 1];
    rep += (a == b); incs += (b > a); decs += (b < a);
  }
  for (int i = 0; i + 2 < n; i++) per2 += (q[i] == q[i + 2]);
  int run = 1, maxrun = (n > 0) ? 1 : 0;
  for (int i = 1; i < n; i++) {
    run = (q[i] == q[i - 1]) ? run + 1 : 1;
    if (run > maxrun) maxrun = run;
  }
  float den1 = (float)((n - 1) >= 1 ? (n - 1) : 1);
  float repeat = (float)rep / den1;
  float incf = (float)incs / den1;
  float decf = (float)decs / den1;
  float per = (n >= 4) ? (float)per2 / (float)((n - 2) >= 1 ? (n - 2) : 1) : 0.f;
  float diversity = (float)distinct * inv;
  float max_rep = (float)maxrun * inv;

  // distinct adjacent-pair codes (== sorted-unique count of a*V+b)
  int dc = 0;
  for (int i = 0; i + 1 < n; i++) {
    int uq = 1;
    for (int jj = 0; jj < i; jj++)
      if (q[jj] == q[i] && q[jj + 1] == q[i + 1]) { uq = 0; break; }
    dc += uq;
  }
  float comp_ratio = (float)dc / den1;
  float entz = (n > 1) ? ent : 0.f;
  float info_density = entz / __logf((float)(n >= 2 ? n : 2));

  int w = n >> 1; if (w > 5) w = 5;
  float local = 0.f;
  if (w >= 2) {
    int usum = 0;
    for (int p = 0; p + w <= n; p++) {
      int u = 1;
      for (int k = 1; k < w; k++) {
        int isnew = 1;
        for (int m = 0; m < k; m++) isnew &= (q[p + k] != q[p + m]);
        u += isnew;
      }
      usum += u;
    }
    local = (float)usum / (float)w / (float)((n - w + 1) >= 1 ? (n - w + 1) : 1);
  }
  float z = (n > 1) ? 1.f : 0.f;
  ent_o[row] = entz;
  vlen_o[row] = (float)n;
  pat_o[row * 6 + 0] = repeat * z;
  pat_o[row * 6 + 1] = incf * z;
  pat_o[row * 6 + 2] = decf * z;
  pat_o[row * 6 + 3] = per * z;
  pat_o[row * 6 + 4] = diversity * z;
  pat_o[row * 6 + 5] = max_rep * z;
  cpx_o[row * 4 + 0] = comp_ratio * z;
  cpx_o[row * 4 + 1] = info_density * z;
  cpx_o[row * 4 + 2] = local * z;
  cpx_o[row * 4 + 3] = (1.f - repeat) * z;
  unsigned int* co = cnt_o + row * 128;
  for (int i = 0; i < 128; i++) co[i] = cw[i];
}

// ---------------------------------------------------------------------------
// Kernel 2: G[v][j] = w_ih[j,:]·emb[v,:] + b_ih[j] + b_hh[j]  (both dirs)
// Grid: 2 dirs x 16 v-chunks(32) x 4 j-chunks(64) = 128 blocks, 256 threads.
// ---------------------------------------------------------------------------
__global__ __launch_bounds__(256) void k_gtab(
    const float* __restrict__ emb,
    const float* __restrict__ wf, const float* __restrict__ bif, const float* __restrict__ bhf,
    const float* __restrict__ wr, const float* __restrict__ bir, const float* __restrict__ bhr,
    float* __restrict__ G_f, float* __restrict__ G_r) {
  __shared__ float e_lds[32 * 128];
  __shared__ float w_lds[64 * 129];
  const int bx = blockIdx.x;
  const int dir = bx >> 6;
  const int rem = bx & 63;
  const int v0 = (rem >> 2) * 32;
  const int j0 = (rem & 3) * 64;
  const float* W = dir ? wr : wf;
  const float* bi = dir ? bir : bif;
  const float* bh = dir ? bhr : bhf;
  float* G = dir ? G_r : G_f;
  const int tid = threadIdx.x;
  for (int i = tid; i < 32 * 128; i += 256) e_lds[i] = emb[v0 * 128 + i];
  for (int i = tid; i < 64 * 128; i += 256)
    w_lds[(i >> 7) * 129 + (i & 127)] = W[j0 * 128 + i];
  __syncthreads();
  for (int oi = tid; oi < 32 * 64; oi += 256) {
    int vloc = oi >> 6, jloc = oi & 63;
    float a = bi[j0 + jloc] + bh[j0 + jloc];
    const float* er = e_lds + vloc * 128;
    const float* wr_ = w_lds + jloc * 129;
    #pragma unroll 4
    for (int d = 0; d < 128; d++) a = fmaf(er[d], wr_[d], a);
    G[(v0 + vloc) * 256 + j0 + jloc] = a;
  }
}

// ---------------------------------------------------------------------------
// Kernel 2b: transpose w_hh (256x64) -> Wt (64x256) so the LSTM K-loop reads
// are coalesced (lane j consecutive).
// ---------------------------------------------------------------------------
__global__ __launch_bounds__(256) void k_wt(
    const float* __restrict__ wf, const float* __restrict__ wr,
    float* __restrict__ Wtf, float* __restrict__ Wtr) {
  const float* w = blockIdx.x ? wr : wf;
  float* o = blockIdx.x ? Wtr : Wtf;
  for (int i = threadIdx.x; i < 64 * 256; i += 256) {
    int k = i >> 8, j = i & 255;
    o[i] = w[j * 64 + k];
  }
}

// ---------------------------------------------------------------------------
// Kernel 3: LSTM recurrence (both directions). 512 blocks x 256 threads,
// 16 rows/block. Thread tid owns gate column j = tid for all 16 rows (GEMM
// phase, W^T streamed coalesced from L2); then re-partitions to (row, unit)
// for the activation phase (c kept in registers). h exchanged via LDS.
// ---------------------------------------------------------------------------
__global__ __launch_bounds__(256) void k_lstm(
    const int* __restrict__ x,
    const float* __restrict__ G_f, const float* __restrict__ G_r,
    const float* __restrict__ Wt_f, const float* __restrict__ Wt_r,
    float* __restrict__ hf_o, float* __restrict__ hr_o) {
  __shared__ float h_lds[16 * 68];
  __shared__ float g_lds[16 * 260];
  __shared__ unsigned short tok[16 * 60];
  const int tid = threadIdx.x;
  const int dir = blockIdx.x >> 8;
  const int blk = blockIdx.x & 255;
  const int b0 = blk << 4;
  const float* Gt = dir ? G_r : G_f;
  const float* Wt = dir ? Wt_r : Wt_f;
  float* ho = dir ? hr_o : hf_o;

  for (int i = tid; i < 16 * 60; i += 256) tok[i] = (unsigned short)x[b0 * 60 + i];
  for (int i = tid; i < 16 * 68; i += 256) h_lds[i] = 0.f;
  const int j = tid;                 // gate column owned in GEMM phase
  const int r_act = tid >> 4;        // activation-phase row
  const int q_act = tid & 15;
  float c[4] = {0.f, 0.f, 0.f, 0.f};
  __syncthreads();

  #pragma unroll 1
  for (int t = 0; t < 60; t++) {
    const int ts = dir ? (59 - t) : t;
    // gate inputs for my column (token-table lookup), issued early
    float gv[16];
    #pragma unroll
    for (int r = 0; r < 16; r++) {
      int tk = tok[r * 60 + ts];
      gv[r] = Gt[tk * 256 + j];
    }
    // GEMM: acc[r] = sum_k h[r][k] * w_hh[j][k]
    float acc[16];
    #pragma unroll
    for (int r = 0; r < 16; r++) acc[r] = 0.f;
    #pragma unroll
    for (int k0 = 0; k0 < 64; k0 += 16) {
      float wreg[16];
      #pragma unroll
      for (int kk = 0; kk < 16; kk++) wreg[kk] = Wt[(k0 + kk) * 256 + j];
      #pragma unroll
      for (int r = 0; r < 16; r++) {
        const float4* hp = (const float4*)(h_lds + r * 68 + k0);
        float4 h0 = hp[0], h1 = hp[1], h2 = hp[2], h3 = hp[3];
        float a = acc[r];
        a = fmaf(h0.x, wreg[0], a);  a = fmaf(h0.y, wreg[1], a);
        a = fmaf(h0.z, wreg[2], a);  a = fmaf(h0.w, wreg[3], a);
        a = fmaf(h1.x, wreg[4], a);  a = fmaf(h1.y, wreg[5], a);
        a = fmaf(h1.z, wreg[6], a);  a = fmaf(h1.w, wreg[7], a);
        a = fmaf(h2.x, wreg[8], a);  a = fmaf(h2.y, wreg[9], a);
        a = fmaf(h2.z, wreg[10], a); a = fmaf(h2.w, wreg[11], a);
        a = fmaf(h3.x, wreg[12], a); a = fmaf(h3.y, wreg[13], a);
        a = fmaf(h3.z, wreg[14], a); a = fmaf(h3.w, wreg[15], a);
        acc[r] = a;
      }
    }
    #pragma unroll
    for (int r = 0; r < 16; r++) g_lds[r * 260 + j] = acc[r] + gv[r];
    __syncthreads();   // g ready; all h reads done
    // activation: thread handles units jh = q_act + 16*jj of row r_act
    const float* gr = g_lds + r_act * 260;
    #pragma unroll
    for (int jj = 0; jj < 4; jj++) {
      int jh = jj * 16 + q_act;
      float gi = gr[jh], gf = gr[64 + jh], gg = gr[128 + jh], go = gr[192 + jh];
      float cn = sigm(gf) * c[jj] + sigm(gi) * tanh_(gg);
      c[jj] = cn;
      h_lds[r_act * 68 + jh] = sigm(go) * tanh_(cn);
    }
    __syncthreads();   // h(t) visible before next GEMM
  }
  for (int i = tid; i < 16 * 64; i += 256) {
    int rr = i >> 6, k = i & 63;
    ho[(b0 + rr) * 64 + k] = h_lds[rr * 68 + k];
  }
}

// ---------------------------------------------------------------------------
// Kernel 4: feature assembly + dense head chain + softmax. 128 blocks x 256
// threads, 32 rows/block. Ping-pong LDS row buffers, W streamed from L2.
// ---------------------------------------------------------------------------
#define STR 185

__device__ __forceinline__ void lay(const float* __restrict__ in,
    float* __restrict__ outb, const float* __restrict__ W,
    const float* __restrict__ bias, int K, int O, bool relu, int tid) {
  for (int idx = tid; idx < 32 * O; idx += 256) {
    int r = idx & 31, o = idx >> 5;
    const float* wr_ = W + o * K;
    const float* ir = in + r * STR;
    float a = bias[o];
    #pragma unroll 4
    for (int k = 0; k < K; k++) a = fmaf(ir[k], wr_[k], a);
    outb[r * STR + o] = relu ? fmaxf(a, 0.f) : a;
  }
  __syncthreads();
}

__global__ __launch_bounds__(256) void k_head(
    const float* __restrict__ hf, const float* __restrict__ hr,
    const float* __restrict__ ent, const float* __restrict__ vlen,
    const float* __restrict__ pat, const float* __restrict__ cpx,
    const unsigned char* __restrict__ cnts,
    const float* __restrict__ e_w1, const float* __restrict__ e_b1,
    const float* __restrict__ e_w2, const float* __restrict__ e_b2,
    const float* __restrict__ l_w1, const float* __restrict__ l_b1,
    const float* __restrict__ l_w2, const float* __restrict__ l_b2,
    const float* __restrict__ c_w1, const float* __restrict__ c_b1,
    const float* __restrict__ c_w2, const float* __restrict__ c_b2,
    const float* __restrict__ p_w1, const float* __restrict__ p_b1,
    const float* __restrict__ p_w2, const float* __restrict__ p_b2,
    const float* __restrict__ x_w1, const float* __restrict__ x_b1,
    const float* __restrict__ x_w2, const float* __restrict__ x_b2,
    const float* __restrict__ fp_w, const float* __restrict__ fp_b,
    const float* __restrict__ attn_w, const float* __restrict__ attn_b,
    const float* __restrict__ out_w, const float* __restrict__ out_b,
    const float* __restrict__ g_w1, const float* __restrict__ g_b1,
    const float* __restrict__ g_w2, const float* __restrict__ g_b2,
    const float* __restrict__ g_w3, const float* __restrict__ g_b3,
    const float* __restrict__ g_w4, const float* __restrict__ g_b4,
    float* __restrict__ out) {
  __shared__ float bufA[32 * STR];
  __shared__ float bufB[32 * STR];
  __shared__ float h1c[32 * 33];
  const int tid = threadIdx.x;
  const int b0 = blockIdx.x * 32;

  // h_f, h_r into feats[0:128)
  for (int i = tid; i < 32 * 64; i += 256) {
    int r = i >> 6, k = i & 63;
    bufA[r * STR + k] = hf[(b0 + r) * 64 + k];
    bufA[r * STR + 64 + k] = hr[(b0 + r) * 64 + k];
  }
  // c-MLP layer 1 from raw counts: h1 = relu((counts·W)/vlenf + b)
  {
    int r = tid >> 3, o0 = (tid & 7) * 4;
    const unsigned int* cb = (const unsigned int*)(cnts + (size_t)(b0 + r) * 512);
    float invv = __builtin_amdgcn_rcpf(fmaxf(vlen[b0 + r], 1.f));
    for (int oo = 0; oo < 4; oo++) {
      int o = o0 + oo;
      const float* wr_ = c_w1 + o * 512;
      float a = 0.f;
      for (int v4 = 0; v4 < 128; v4++) {
        unsigned int u = cb[v4];
        const float* w4 = wr_ + v4 * 4;
        a = fmaf((float)(u & 255u), w4[0], a);
        a = fmaf((float)((u >> 8) & 255u), w4[1], a);
        a = fmaf((float)((u >> 16) & 255u), w4[2], a);
        a = fmaf((float)(u >> 24), w4[3], a);
      }
      h1c[r * 33 + o] = fmaxf(a * invv + c_b1[o], 0.f);
    }
  }
  // small MLPs, one thread per row
  if (tid < 32) {
    const int r = tid, b = b0 + tid;
    float tt[24];
    float ein = ent[b] * 0.25f;
    #pragma unroll
    for (int o = 0; o < 16; o++) tt[o] = fmaxf(e_w1[o] * ein + e_b1[o], 0.f);
    #pragma unroll
    for (int o = 0; o < 8; o++) {
      float a = e_b2[o];
      #pragma unroll
      for (int k = 0; k < 16; k++) a = fmaf(e_w2[o * 16 + k], tt[k], a);
      bufA[r * STR + 128 + o] = a;
    }
    float lin = vlen[b] * (1.f / 60.f);
    #pragma unroll
    for (int o = 0; o < 16; o++) tt[o] = fmaxf(l_w1[o] * lin + l_b1[o], 0.f);
    #pragma unroll
    for (int o = 0; o < 8; o++) {
      float a = l_b2[o];
      #pragma unroll
      for (int k = 0; k < 16; k++) a = fmaf(l_w2[o * 16 + k], tt[k], a);
      bufA[r * STR + 136 + o] = a;
    }
    float pin[6];
    #pragma unroll
    for (int k = 0; k < 6; k++) pin[k] = pat[b * 6 + k];
    #pragma unroll
    for (int o = 0; o < 24; o++) {
      float a = p_b1[o];
      #pragma unroll
      for (int k = 0; k < 6; k++) a = fmaf(p_w1[o * 6 + k], pin[k], a);
      tt[o] = fmaxf(a, 0.f);
    }
    #pragma unroll
    for (int o = 0; o < 12; o++) {
      float a = p_b2[o];
      #pragma unroll
      for (int k = 0; k < 24; k++) a = fmaf(p_w2[o * 24 + k], tt[k], a);
      bufA[r * STR + 160 + o] = a;
    }
    float xin[4];
    #pragma unroll
    for (int k = 0; k < 4; k++) xin[k] = cpx[b * 4 + k];
    #pragma unroll
    for (int o = 0; o < 16; o++) {
      float a = x_b1[o];
      #pragma unroll
      for (int k = 0; k < 4; k++) a = fmaf(x_w1[o * 4 + k], xin[k], a);
      tt[o] = fmaxf(a, 0.f);
    }
    #pragma unroll
    for (int o = 0; o < 8; o++) {
      float a = x_b2[o];
      #pragma unroll
      for (int k = 0; k < 16; k++) a = fmaf(x_w2[o * 16 + k], tt[k], a);
      bufA[r * STR + 172 + o] = a;
    }
  }
  __syncthreads();
  // c-MLP layer 2 -> feats[144:160)
  {
    int r = tid >> 3, o0 = (tid & 7) * 2;
    for (int oo = 0; oo < 2; oo++) {
      int o = o0 + oo;
      float a = c_b2[o];
      #pragma unroll
      for (int k = 0; k < 32; k++) a = fmaf(c_w2[o * 32 + k], h1c[r * 33 + k], a);
      bufA[r * STR + 144 + o] = a;
    }
  }
  __syncthreads();

  lay(bufA, bufB, fp_w, fp_b, 180, 184, false, tid);
  lay(bufB, bufA, attn_w + 368 * 184, attn_b + 368, 184, 184, false, tid);
  lay(bufA, bufB, out_w, out_b, 184, 184, false, tid);
  lay(bufB, bufA, g_w1, g_b1, 184, 128, true, tid);
  lay(bufA, bufB, g_w2, g_b2, 128, 64, true, tid);
  lay(bufB, bufA, g_w3, g_b3, 64, 32, true, tid);
  lay(bufA, bufB, g_w4, g_b4, 32, 4, false, tid);

  if (tid < 32) {
    int r = tid;
    float l0 = bufB[r * STR + 0], l1 = bufB[r * STR + 1];
    float l2 = bufB[r * STR + 2], l3 = bufB[r * STR + 3];
    float m = fmaxf(fmaxf(l0, l1), fmaxf(l2, l3));
    float e0 = __expf(l0 - m), e1 = __expf(l1 - m);
    float e2 = __expf(l2 - m), e3 = __expf(l3 - m);
    float is = __builtin_amdgcn_rcpf(e0 + e1 + e2 + e3);
    float4 o4; o4.x = e0 * is; o4.y = e1 * is; o4.z = e2 * is; o4.w = e3 * is;
    *(float4*)(out + (b0 + r) * 4) = o4;
  }
}

// ---------------------------------------------------------------------------
extern "C" void kernel_launch(void* const* d_in, const int* in_sizes, int n_in,
                              void* d_out, int out_size, void* d_ws, size_t ws_size,
                              hipStream_t stream) {
  const int*   x     = (const int*)d_in[0];
  const float* emb   = (const float*)d_in[1];
  const float* wih_f = (const float*)d_in[2];
  const float* whh_f = (const float*)d_in[3];
  const float* bih_f = (const float*)d_in[4];
  const float* bhh_f = (const float*)d_in[5];
  const float* wih_r = (const float*)d_in[6];
  const float* whh_r = (const float*)d_in[7];
  const float* bih_r = (const float*)d_in[8];
  const float* bhh_r = (const float*)d_in[9];
  const float* e_w1 = (const float*)d_in[10]; const float* e_b1 = (const float*)d_in[11];
  const float* e_w2 = (const float*)d_in[12]; const float* e_b2 = (const float*)d_in[13];
  const float* l_w1 = (const float*)d_in[14]; const float* l_b1 = (const float*)d_in[15];
  const float* l_w2 = (const float*)d_in[16]; const float* l_b2 = (const float*)d_in[17];
  const float* c_w1 = (const float*)d_in[18]; const float* c_b1 = (const float*)d_in[19];
  const float* c_w2 = (const float*)d_in[20]; const float* c_b2 = (const float*)d_in[21];
  const float* p_w1 = (const float*)d_in[22]; const float* p_b1 = (const float*)d_in[23];
  const float* p_w2 = (const float*)d_in[24]; const float* p_b2 = (const float*)d_in[25];
  const float* x_w1 = (const float*)d_in[26]; const float* x_b1 = (const float*)d_in[27];
  const float* x_w2 = (const float*)d_in[28]; const float* x_b2 = (const float*)d_in[29];
  const float* fp_w = (const float*)d_in[30]; const float* fp_b = (const float*)d_in[31];
  const float* attn_w = (const float*)d_in[32]; const float* attn_b = (const float*)d_in[33];
  const float* out_w = (const float*)d_in[34]; const float* out_b = (const float*)d_in[35];
  const float* g_w1 = (const float*)d_in[36]; const float* g_b1 = (const float*)d_in[37];
  const float* g_w2 = (const float*)d_in[38]; const float* g_b2 = (const float*)d_in[39];
  const float* g_w3 = (const float*)d_in[40]; const float* g_b3 = (const float*)d_in[41];
  const float* g_w4 = (const float*)d_in[42]; const float* g_b4 = (const float*)d_in[43];

  // Workspace layout (fp32 elements unless noted)
  float* ws   = (float*)d_ws;
  float* G_f  = ws;                       // 512*256
  float* G_r  = G_f  + 512 * 256;
  float* Wt_f = G_r  + 512 * 256;         // 64*256
  float* Wt_r = Wt_f + 64 * 256;
  float* hfw  = Wt_r + 64 * 256;          // B*64
  float* hrw  = hfw  + BATCH * 64;
  float* entw = hrw  + BATCH * 64;        // B
  float* vlnw = entw + BATCH;             // B (raw vlen as float)
  float* patw = vlnw + BATCH;             // B*6
  float* cpxw = patw + BATCH * 6;         // B*4
  unsigned int* cntw = (unsigned int*)(cpxw + BATCH * 4);  // B*512 bytes

  k_stats<<<dim3(BATCH / 64), dim3(64), 0, stream>>>(x, entw, vlnw, patw, cpxw, cntw);
  k_gtab<<<dim3(128), dim3(256), 0, stream>>>(emb, wih_f, bih_f, bhh_f,
                                              wih_r, bih_r, bhh_r, G_f, G_r);
  k_wt<<<dim3(2), dim3(256), 0, stream>>>(whh_f, whh_r, Wt_f, Wt_r);
  k_lstm<<<dim3(512), dim3(256), 0, stream>>>(x, G_f, G_r, Wt_f, Wt_r, hfw, hrw);
  k_head<<<dim3(BATCH / 32), dim3(256), 0, stream>>>(
      hfw, hrw, entw, vlnw, patw, cpxw, (const unsigned char*)cntw,
      e_w1, e_b1, e_w2, e_b2, l_w1, l_b1, l_w2, l_b2,
      c_w1, c_b1, c_w2, c_b2, p_w1, p_b1, p_w2, p_b2,
      x_w1, x_b1, x_w2, x_b2, fp_w, fp_b, attn_w, attn_b,
      out_w, out_b, g_w1, g_b1, g_w2, g_b2, g_w3, g_b3, g_w4, g_b4,
      (float*)d_out);
}

// Round 2
// 622.497 us; speedup vs baseline: 2.1401x; 2.1401x over previous
//
#include <hip/hip_runtime.h>

// Problem constants
#define BATCH 4096
#define SEQL  60
#define VOC   512
#define EMBD  128
#define HID   64
#define GATES 256
#define ADJ   184

__device__ __forceinline__ float sigm(float x) {
  return __builtin_amdgcn_rcpf(1.f + __expf(-x));
}
__device__ __forceinline__ float tanh_(float x) {
  float e = __expf(2.f * x);
  return 1.f - 2.f * __builtin_amdgcn_rcpf(e + 1.f);
}

__device__ __forceinline__ float wsumf(float v) {
  #pragma unroll
  for (int s = 32; s > 0; s >>= 1) v += __shfl_xor(v, s, 64);
  return v;
}
__device__ __forceinline__ int wsumi(int v) {
  #pragma unroll
  for (int s = 32; s > 0; s >>= 1) v += __shfl_xor(v, s, 64);
  return v;
}
__device__ __forceinline__ int wmaxi(int v) {
  #pragma unroll
  for (int s = 32; s > 0; s >>= 1) v = max(v, __shfl_xor(v, s, 64));
  return v;
}

// ---------------------------------------------------------------------------
// Kernel 1: per-row sequence statistics, one WAVE per row. 4 rows/block,
// 1024 blocks. Ballot-based compaction, LDS-atomic histogram, popcount
// reductions.
// ---------------------------------------------------------------------------
__global__ __launch_bounds__(256) void k_stats(
    const int* __restrict__ x,
    float* __restrict__ ent_o, float* __restrict__ vlen_o,
    float* __restrict__ pat_o, float* __restrict__ cpx_o,
    unsigned int* __restrict__ cnt_o) {
  __shared__ unsigned int cnt[4][512];
  __shared__ unsigned short q[4][68];
  const int tid = threadIdx.x;
  const int lane = tid & 63;
  const int wid = tid >> 6;
  const int row = blockIdx.x * 4 + wid;
  unsigned int* cr = cnt[wid];
  unsigned short* qr = q[wid];

  for (int i = lane; i < 512; i += 64) cr[i] = 0u;
  qr[lane] = 0;
  if (lane < 4) qr[64 + lane] = 0;
  int v = (lane < 60) ? x[row * 60 + lane] : 0;
  bool act = (v != 0);
  unsigned long long amask = __ballot(act);
  int n = __popcll(amask);
  __syncthreads();
  if (act) {
    int pos = __popcll(amask & ((1ull << lane) - 1ull));
    qr[pos] = (unsigned short)v;
    atomicAdd(&cr[v], 1u);
  }
  __syncthreads();

  float vlenf = (float)(n >= 1 ? n : 1);
  float inv = 1.f / vlenf;

  // entropy + distinct (each lane covers 8 vocab slots)
  float ent = 0.f; int distinct = 0;
  #pragma unroll
  for (int j = 0; j < 8; j++) {
    unsigned int c = cr[lane + j * 64];
    if (c) {
      distinct++;
      float p = (float)c * inv;
      ent -= p * __logf(p + 1e-8f);
    }
  }
  ent = wsumf(ent);
  distinct = wsumi(distinct);

  // adjacent-pair stats via ballot popcounts (lane == position i)
  int a = qr[lane], b = qr[lane + 1], c2 = qr[lane + 2];
  bool v1 = (lane + 1 < n);
  bool v2 = (lane + 2 < n);
  int rep  = __popcll(__ballot(v1 && (a == b)));
  int incs = __popcll(__ballot(v1 && (b > a)));
  int decs = __popcll(__ballot(v1 && (b < a)));
  int per2 = __popcll(__ballot(v2 && (a == c2)));

  // max run via run-start mask
  int prev = (lane > 0) ? (int)qr[lane - 1] : -1;
  bool isst = (lane < n) && (lane == 0 || a != prev);
  unsigned long long smask = __ballot(isst);
  int len = 0;
  if (isst) {
    unsigned long long hi = (lane < 63) ? (smask >> (lane + 1)) : 0ull;
    int next = hi ? (lane + __ffsll((unsigned long long)hi)) : n;
    len = next - lane;
  }
  int maxrun = wmaxi(len);

  // distinct adjacent-pair codes: lane i checks bigram vs all earlier ones
  int unique = 1;
  int lim = v1 ? lane : 0;
  for (int jj = 0; jj < lim; jj++) {
    if ((int)qr[jj] == a && (int)qr[jj + 1] == b) { unique = 0; break; }
  }
  int dc = __popcll(__ballot(v1 && unique));

  // local window uniqueness for selected w
  int wl = n >> 1; if (wl > 5) wl = 5;
  float local = 0.f;
  if (wl >= 2) {
    bool pv = (lane + wl <= n);
    int u = 0;
    if (pv) {
      int t0 = qr[lane], t1 = qr[lane + 1], t2 = qr[lane + 2];
      int t3 = qr[lane + 3], t4 = qr[lane + 4];
      u = 1;
      u += (t1 != t0);
      if (wl >= 3) u += (int)((t2 != t1) && (t2 != t0));
      if (wl >= 4) u += (int)((t3 != t2) && (t3 != t1) && (t3 != t0));
      if (wl >= 5) u += (int)((t4 != t3) && (t4 != t2) && (t4 != t1) && (t4 != t0));
    }
    int usum = wsumi(u);
    int denw = n - wl + 1; if (denw < 1) denw = 1;
    local = (float)usum / (float)wl / (float)denw;
  }

  float den1 = (float)((n - 1) >= 1 ? (n - 1) : 1);
  float repeat = (float)rep / den1;
  float incf = (float)incs / den1;
  float decf = (float)decs / den1;
  float per = (n >= 4) ? (float)per2 / (float)((n - 2) >= 1 ? (n - 2) : 1) : 0.f;
  float diversity = (float)distinct * inv;
  float max_rep = (float)maxrun * inv;
  float comp_ratio = (float)dc / den1;
  float entz = (n > 1) ? ent : 0.f;
  float info_density = entz / __logf((float)(n >= 2 ? n : 2));
  float z = (n > 1) ? 1.f : 0.f;

  if (lane == 0) {
    ent_o[row] = entz;
    vlen_o[row] = (float)n;
    pat_o[row * 6 + 0] = repeat * z;
    pat_o[row * 6 + 1] = incf * z;
    pat_o[row * 6 + 2] = decf * z;
    pat_o[row * 6 + 3] = per * z;
    pat_o[row * 6 + 4] = diversity * z;
    pat_o[row * 6 + 5] = max_rep * z;
    cpx_o[row * 4 + 0] = comp_ratio * z;
    cpx_o[row * 4 + 1] = info_density * z;
    cpx_o[row * 4 + 2] = local * z;
    cpx_o[row * 4 + 3] = (1.f - repeat) * z;
  }
  for (int i = lane; i < 128; i += 64) {
    unsigned int p = cr[4 * i] | (cr[4 * i + 1] << 8) |
                     (cr[4 * i + 2] << 16) | (cr[4 * i + 3] << 24);
    cnt_o[row * 128 + i] = p;
  }
}

// ---------------------------------------------------------------------------
// Kernel 2: G[v][j] = w_ih[j,:]·emb[v,:] + b_ih[j] + b_hh[j]  (both dirs)
// ---------------------------------------------------------------------------
__global__ __launch_bounds__(256) void k_gtab(
    const float* __restrict__ emb,
    const float* __restrict__ wf, const float* __restrict__ bif, const float* __restrict__ bhf,
    const float* __restrict__ wr, const float* __restrict__ bir, const float* __restrict__ bhr,
    float* __restrict__ G_f, float* __restrict__ G_r) {
  __shared__ float e_lds[32 * 128];
  __shared__ float w_lds[64 * 129];
  const int bx = blockIdx.x;
  const int dir = bx >> 6;
  const int rem = bx & 63;
  const int v0 = (rem >> 2) * 32;
  const int j0 = (rem & 3) * 64;
  const float* W = dir ? wr : wf;
  const float* bi = dir ? bir : bif;
  const float* bh = dir ? bhr : bhf;
  float* G = dir ? G_r : G_f;
  const int tid = threadIdx.x;
  for (int i = tid; i < 32 * 128; i += 256) e_lds[i] = emb[v0 * 128 + i];
  for (int i = tid; i < 64 * 128; i += 256)
    w_lds[(i >> 7) * 129 + (i & 127)] = W[j0 * 128 + i];
  __syncthreads();
  for (int oi = tid; oi < 32 * 64; oi += 256) {
    int vloc = oi >> 6, jloc = oi & 63;
    float a = bi[j0 + jloc] + bh[j0 + jloc];
    const float* er = e_lds + vloc * 128;
    const float* wr_ = w_lds + jloc * 129;
    #pragma unroll 4
    for (int d = 0; d < 128; d++) a = fmaf(er[d], wr_[d], a);
    G[(v0 + vloc) * 256 + j0 + jloc] = a;
  }
}

// ---------------------------------------------------------------------------
// Kernel 2b: transpose w_hh (256x64) -> Wt (64x256)
// ---------------------------------------------------------------------------
__global__ __launch_bounds__(256) void k_wt(
    const float* __restrict__ wf, const float* __restrict__ wr,
    float* __restrict__ Wtf, float* __restrict__ Wtr) {
  const float* w = blockIdx.x ? wr : wf;
  float* o = blockIdx.x ? Wtr : Wtf;
  for (int i = threadIdx.x; i < 64 * 256; i += 256) {
    int k = i >> 8, j = i & 255;
    o[i] = w[j * 64 + k];
  }
}

// ---------------------------------------------------------------------------
// Kernel 2c: generic small matmul for head collapse:
//   Mo[i][j] = sum_k A[i][k] * Bm[k][j]   (K=184, N=180, rows = gridDim.x)
//   bo[i]    = sum_k A[i][k] * bin[k] + badd[i]
// ---------------------------------------------------------------------------
__global__ __launch_bounds__(192) void k_prep(
    const float* __restrict__ A, const float* __restrict__ Bm,
    const float* __restrict__ bin, const float* __restrict__ badd,
    float* __restrict__ Mo, float* __restrict__ bo) {
  const int i = blockIdx.x, j = threadIdx.x;
  if (j < 180) {
    float a = 0.f;
    for (int k = 0; k < ADJ; k++) a = fmaf(A[i * ADJ + k], Bm[k * 180 + j], a);
    Mo[i * 180 + j] = a;
  } else if (j == 180) {
    float a = badd[i];
    for (int k = 0; k < ADJ; k++) a = fmaf(A[i * ADJ + k], bin[k], a);
    bo[i] = a;
  }
}

// ---------------------------------------------------------------------------
// Kernel 3: LSTM recurrence (both directions). Unchanged from round 1.
// ---------------------------------------------------------------------------
__global__ __launch_bounds__(256) void k_lstm(
    const int* __restrict__ x,
    const float* __restrict__ G_f, const float* __restrict__ G_r,
    const float* __restrict__ Wt_f, const float* __restrict__ Wt_r,
    float* __restrict__ hf_o, float* __restrict__ hr_o) {
  __shared__ float h_lds[16 * 68];
  __shared__ float g_lds[16 * 260];
  __shared__ unsigned short tok[16 * 60];
  const int tid = threadIdx.x;
  const int dir = blockIdx.x >> 8;
  const int blk = blockIdx.x & 255;
  const int b0 = blk << 4;
  const float* Gt = dir ? G_r : G_f;
  const float* Wt = dir ? Wt_r : Wt_f;
  float* ho = dir ? hr_o : hf_o;

  for (int i = tid; i < 16 * 60; i += 256) tok[i] = (unsigned short)x[b0 * 60 + i];
  for (int i = tid; i < 16 * 68; i += 256) h_lds[i] = 0.f;
  const int j = tid;
  const int r_act = tid >> 4;
  const int q_act = tid & 15;
  float c[4] = {0.f, 0.f, 0.f, 0.f};
  __syncthreads();

  #pragma unroll 1
  for (int t = 0; t < 60; t++) {
    const int ts = dir ? (59 - t) : t;
    float gv[16];
    #pragma unroll
    for (int r = 0; r < 16; r++) {
      int tk = tok[r * 60 + ts];
      gv[r] = Gt[tk * 256 + j];
    }
    float acc[16];
    #pragma unroll
    for (int r = 0; r < 16; r++) acc[r] = 0.f;
    #pragma unroll
    for (int k0 = 0; k0 < 64; k0 += 16) {
      float wreg[16];
      #pragma unroll
      for (int kk = 0; kk < 16; kk++) wreg[kk] = Wt[(k0 + kk) * 256 + j];
      #pragma unroll
      for (int r = 0; r < 16; r++) {
        const float4* hp = (const float4*)(h_lds + r * 68 + k0);
        float4 h0 = hp[0], h1 = hp[1], h2 = hp[2], h3 = hp[3];
        float a = acc[r];
        a = fmaf(h0.x, wreg[0], a);  a = fmaf(h0.y, wreg[1], a);
        a = fmaf(h0.z, wreg[2], a);  a = fmaf(h0.w, wreg[3], a);
        a = fmaf(h1.x, wreg[4], a);  a = fmaf(h1.y, wreg[5], a);
        a = fmaf(h1.z, wreg[6], a);  a = fmaf(h1.w, wreg[7], a);
        a = fmaf(h2.x, wreg[8], a);  a = fmaf(h2.y, wreg[9], a);
        a = fmaf(h2.z, wreg[10], a); a = fmaf(h2.w, wreg[11], a);
        a = fmaf(h3.x, wreg[12], a); a = fmaf(h3.y, wreg[13], a);
        a = fmaf(h3.z, wreg[14], a); a = fmaf(h3.w, wreg[15], a);
        acc[r] = a;
      }
    }
    #pragma unroll
    for (int r = 0; r < 16; r++) g_lds[r * 260 + j] = acc[r] + gv[r];
    __syncthreads();
    const float* gr = g_lds + r_act * 260;
    #pragma unroll
    for (int jj = 0; jj < 4; jj++) {
      int jh = jj * 16 + q_act;
      float gi = gr[jh], gf = gr[64 + jh], gg = gr[128 + jh], go = gr[192 + jh];
      float cn = sigm(gf) * c[jj] + sigm(gi) * tanh_(gg);
      c[jj] = cn;
      h_lds[r_act * 68 + jh] = sigm(go) * tanh_(cn);
    }
    __syncthreads();
  }
  for (int i = tid; i < 16 * 64; i += 256) {
    int rr = i >> 6, k = i & 63;
    ho[(b0 + rr) * 64 + k] = h_lds[rr * 68 + k];
  }
}

// ---------------------------------------------------------------------------
// Kernel 4: feature assembly + COLLAPSED head (180->128->64->32->4) + softmax.
// 512 blocks x 256 threads, 8 rows/block. Thread owns output column o;
// input rows are wave-uniform LDS broadcasts (free); W via float4 from L2.
// ---------------------------------------------------------------------------
#define FSTR 192

__global__ __launch_bounds__(256) void k_head(
    const float* __restrict__ hf, const float* __restrict__ hr,
    const float* __restrict__ ent, const float* __restrict__ vlen,
    const float* __restrict__ pat, const float* __restrict__ cpx,
    const unsigned char* __restrict__ cnts,
    const float* __restrict__ e_w1, const float* __restrict__ e_b1,
    const float* __restrict__ e_w2, const float* __restrict__ e_b2,
    const float* __restrict__ l_w1, const float* __restrict__ l_b1,
    const float* __restrict__ l_w2, const float* __restrict__ l_b2,
    const float* __restrict__ c_w1, const float* __restrict__ c_b1,
    const float* __restrict__ c_w2, const float* __restrict__ c_b2,
    const float* __restrict__ p_w1, const float* __restrict__ p_b1,
    const float* __restrict__ p_w2, const float* __restrict__ p_b2,
    const float* __restrict__ x_w1, const float* __restrict__ x_b1,
    const float* __restrict__ x_w2, const float* __restrict__ x_b2,
    const float* __restrict__ C1, const float* __restrict__ c1b,
    const float* __restrict__ g_w2, const float* __restrict__ g_b2,
    const float* __restrict__ g_w3, const float* __restrict__ g_b3,
    const float* __restrict__ g_w4, const float* __restrict__ g_b4,
    float* __restrict__ out) {
  __shared__ float feat[8 * FSTR];
  __shared__ float h1[8 * 128];
  __shared__ float h2[8 * 64];
  __shared__ float h3[8 * 32];
  __shared__ float h1c[8 * 33];
  __shared__ float lg[8 * 4];
  const int tid = threadIdx.x;
  const int b0 = blockIdx.x * 8;

  // h_f / h_r -> feats[0:128)
  if (tid < 128) {
    int r = tid >> 4, c = tid & 15;
    float4 vv = ((const float4*)(hf + (size_t)(b0 + r) * 64))[c];
    *(float4*)(feat + r * FSTR + c * 4) = vv;
  } else {
    int t = tid - 128;
    int r = t >> 4, c = t & 15;
    float4 vv = ((const float4*)(hr + (size_t)(b0 + r) * 64))[c];
    *(float4*)(feat + r * FSTR + 64 + c * 4) = vv;
  }
  // c-MLP layer 1: 8 rows x 32 outputs, one per thread
  {
    int r = tid >> 5, o = tid & 31;
    const unsigned int* cb = (const unsigned int*)(cnts + (size_t)(b0 + r) * 512);
    float invv = __builtin_amdgcn_rcpf(fmaxf(vlen[b0 + r], 1.f));
    const float* wr_ = c_w1 + o * 512;
    float a0 = 0.f, a1 = 0.f;
    for (int v4 = 0; v4 < 128; v4 += 2) {
      unsigned int u0 = cb[v4], u1 = cb[v4 + 1];
      const float* w4 = wr_ + v4 * 4;
      a0 = fmaf((float)(u0 & 255u), w4[0], a0);
      a0 = fmaf((float)((u0 >> 8) & 255u), w4[1], a0);
      a0 = fmaf((float)((u0 >> 16) & 255u), w4[2], a0);
      a0 = fmaf((float)(u0 >> 24), w4[3], a0);
      a1 = fmaf((float)(u1 & 255u), w4[4], a1);
      a1 = fmaf((float)((u1 >> 8) & 255u), w4[5], a1);
      a1 = fmaf((float)((u1 >> 16) & 255u), w4[6], a1);
      a1 = fmaf((float)(u1 >> 24), w4[7], a1);
    }
    h1c[r * 33 + o] = fmaxf((a0 + a1) * invv + c_b1[o], 0.f);
  }
  // small MLPs: 32 threads, (mlp, row) pairs
  if (tid < 32) {
    const int m = tid & 3, r = tid >> 2, b = b0 + r;
    float tt[24];
    if (m == 0) {
      float ein = ent[b] * 0.25f;
      #pragma unroll
      for (int o = 0; o < 16; o++) tt[o] = fmaxf(e_w1[o] * ein + e_b1[o], 0.f);
      #pragma unroll
      for (int o = 0; o < 8; o++) {
        float a = e_b2[o];
        #pragma unroll
        for (int k = 0; k < 16; k++) a = fmaf(e_w2[o * 16 + k], tt[k], a);
        feat[r * FSTR + 128 + o] = a;
      }
    } else if (m == 1) {
      float lin = vlen[b] * (1.f / 60.f);
      #pragma unroll
      for (int o = 0; o < 16; o++) tt[o] = fmaxf(l_w1[o] * lin + l_b1[o], 0.f);
      #pragma unroll
      for (int o = 0; o < 8; o++) {
        float a = l_b2[o];
        #pragma unroll
        for (int k = 0; k < 16; k++) a = fmaf(l_w2[o * 16 + k], tt[k], a);
        feat[r * FSTR + 136 + o] = a;
      }
    } else if (m == 2) {
      float pin[6];
      #pragma unroll
      for (int k = 0; k < 6; k++) pin[k] = pat[b * 6 + k];
      #pragma unroll
      for (int o = 0; o < 24; o++) {
        float a = p_b1[o];
        #pragma unroll
        for (int k = 0; k < 6; k++) a = fmaf(p_w1[o * 6 + k], pin[k], a);
        tt[o] = fmaxf(a, 0.f);
      }
      #pragma unroll
      for (int o = 0; o < 12; o++) {
        float a = p_b2[o];
        #pragma unroll
        for (int k = 0; k < 24; k++) a = fmaf(p_w2[o * 24 + k], tt[k], a);
        feat[r * FSTR + 160 + o] = a;
      }
    } else {
      float xin[4];
      #pragma unroll
      for (int k = 0; k < 4; k++) xin[k] = cpx[b * 4 + k];
      #pragma unroll
      for (int o = 0; o < 16; o++) {
        float a = x_b1[o];
        #pragma unroll
        for (int k = 0; k < 4; k++) a = fmaf(x_w1[o * 4 + k], xin[k], a);
        tt[o] = fmaxf(a, 0.f);
      }
      #pragma unroll
      for (int o = 0; o < 8; o++) {
        float a = x_b2[o];
        #pragma unroll
        for (int k = 0; k < 16; k++) a = fmaf(x_w2[o * 16 + k], tt[k], a);
        feat[r * FSTR + 172 + o] = a;
      }
    }
  }
  __syncthreads();
  // c-MLP layer 2 -> feats[144:160)
  if (tid < 128) {
    int r = tid >> 4, o = tid & 15;
    float a = c_b2[o];
    const float* hh = h1c + r * 33;
    #pragma unroll
    for (int k = 0; k < 32; k++) a = fmaf(c_w2[o * 32 + k], hh[k], a);
    feat[r * FSTR + 144 + o] = a;
  }
  __syncthreads();

  // L1: 180 -> 128, relu   (o = tid&127, row group = tid>>7 -> 4 rows each)
  {
    int o = tid & 127, rg = tid >> 7;
    const float4* w = (const float4*)(C1 + o * 180);
    float a0 = 0.f, a1 = 0.f, a2 = 0.f, a3 = 0.f;
    const float* f0p = feat + (rg * 4 + 0) * FSTR;
    const float* f1p = feat + (rg * 4 + 1) * FSTR;
    const float* f2p = feat + (rg * 4 + 2) * FSTR;
    const float* f3p = feat + (rg * 4 + 3) * FSTR;
    #pragma unroll 5
    for (int k4 = 0; k4 < 45; k4++) {
      float4 w4 = w[k4];
      float4 f0 = *(const float4*)(f0p + k4 * 4);
      float4 f1 = *(const float4*)(f1p + k4 * 4);
      float4 f2 = *(const float4*)(f2p + k4 * 4);
      float4 f3 = *(const float4*)(f3p + k4 * 4);
      a0 = fmaf(w4.x, f0.x, a0); a0 = fmaf(w4.y, f0.y, a0);
      a0 = fmaf(w4.z, f0.z, a0); a0 = fmaf(w4.w, f0.w, a0);
      a1 = fmaf(w4.x, f1.x, a1); a1 = fmaf(w4.y, f1.y, a1);
      a1 = fmaf(w4.z, f1.z, a1); a1 = fmaf(w4.w, f1.w, a1);
      a2 = fmaf(w4.x, f2.x, a2); a2 = fmaf(w4.y, f2.y, a2);
      a2 = fmaf(w4.z, f2.z, a2); a2 = fmaf(w4.w, f2.w, a2);
      a3 = fmaf(w4.x, f3.x, a3); a3 = fmaf(w4.y, f3.y, a3);
      a3 = fmaf(w4.z, f3.z, a3); a3 = fmaf(w4.w, f3.w, a3);
    }
    float bb = c1b[o];
    h1[(rg * 4 + 0) * 128 + o] = fmaxf(a0 + bb, 0.f);
    h1[(rg * 4 + 1) * 128 + o] = fmaxf(a1 + bb, 0.f);
    h1[(rg * 4 + 2) * 128 + o] = fmaxf(a2 + bb, 0.f);
    h1[(rg * 4 + 3) * 128 + o] = fmaxf(a3 + bb, 0.f);
  }
  __syncthreads();
  // L2: 128 -> 64, relu   (o = tid&63, 4 row groups x 2 rows)
  {
    int o = tid & 63, rg = tid >> 6;
    const float4* w = (const float4*)(g_w2 + o * 128);
    float a0 = 0.f, a1 = 0.f;
    const float* f0p = h1 + (rg * 2 + 0) * 128;
    const float* f1p = h1 + (rg * 2 + 1) * 128;
    #pragma unroll 4
    for (int k4 = 0; k4 < 32; k4++) {
      float4 w4 = w[k4];
      float4 f0 = *(const float4*)(f0p + k4 * 4);
      float4 f1 = *(const float4*)(f1p + k4 * 4);
      a0 = fmaf(w4.x, f0.x, a0); a0 = fmaf(w4.y, f0.y, a0);
      a0 = fmaf(w4.z, f0.z, a0); a0 = fmaf(w4.w, f0.w, a0);
      a1 = fmaf(w4.x, f1.x, a1); a1 = fmaf(w4.y, f1.y, a1);
      a1 = fmaf(w4.z, f1.z, a1); a1 = fmaf(w4.w, f1.w, a1);
    }
    float bb = g_b2[o];
    h2[(rg * 2 + 0) * 64 + o] = fmaxf(a0 + bb, 0.f);
    h2[(rg * 2 + 1) * 64 + o] = fmaxf(a1 + bb, 0.f);
  }
  __syncthreads();
  // L3: 64 -> 32, relu   (o = tid&31, 8 row groups x 1 row)
  {
    int o = tid & 31, rg = tid >> 5;
    const float4* w = (const float4*)(g_w3 + o * 64);
    float a = 0.f;
    const float* fp = h2 + rg * 64;
    #pragma unroll 4
    for (int k4 = 0; k4 < 16; k4++) {
      float4 w4 = w[k4];
      float4 f0 = *(const float4*)(fp + k4 * 4);
      a = fmaf(w4.x, f0.x, a); a = fmaf(w4.y, f0.y, a);
      a = fmaf(w4.z, f0.z, a); a = fmaf(w4.w, f0.w, a);
    }
    h3[rg * 32 + o] = fmaxf(a + g_b3[o], 0.f);
  }
  __syncthreads();
  // L4: 32 -> 4 logits
  if (tid < 32) {
    int r = tid >> 2, o = tid & 3;
    const float4* w = (const float4*)(g_w4 + o * 32);
    const float4* hh = (const float4*)(h3 + r * 32);
    float a = g_b4[o];
    #pragma unroll
    for (int k4 = 0; k4 < 8; k4++) {
      float4 w4 = w[k4], x4 = hh[k4];
      a = fmaf(w4.x, x4.x, a); a = fmaf(w4.y, x4.y, a);
      a = fmaf(w4.z, x4.z, a); a = fmaf(w4.w, x4.w, a);
    }
    lg[r * 4 + o] = a;
  }
  __syncthreads();
  if (tid < 8) {
    float l0 = lg[tid * 4 + 0], l1 = lg[tid * 4 + 1];
    float l2 = lg[tid * 4 + 2], l3 = lg[tid * 4 + 3];
    float m = fmaxf(fmaxf(l0, l1), fmaxf(l2, l3));
    float e0 = __expf(l0 - m), e1 = __expf(l1 - m);
    float e2 = __expf(l2 - m), e3 = __expf(l3 - m);
    float is = __builtin_amdgcn_rcpf(e0 + e1 + e2 + e3);
    float4 o4; o4.x = e0 * is; o4.y = e1 * is; o4.z = e2 * is; o4.w = e3 * is;
    *(float4*)(out + (size_t)(b0 + tid) * 4) = o4;
  }
}

// ---------------------------------------------------------------------------
extern "C" void kernel_launch(void* const* d_in, const int* in_sizes, int n_in,
                              void* d_out, int out_size, void* d_ws, size_t ws_size,
                              hipStream_t stream) {
  const int*   x     = (const int*)d_in[0];
  const float* emb   = (const float*)d_in[1];
  const float* wih_f = (const float*)d_in[2];
  const float* whh_f = (const float*)d_in[3];
  const float* bih_f = (const float*)d_in[4];
  const float* bhh_f = (const float*)d_in[5];
  const float* wih_r = (const float*)d_in[6];
  const float* whh_r = (const float*)d_in[7];
  const float* bih_r = (const float*)d_in[8];
  const float* bhh_r = (const float*)d_in[9];
  const float* e_w1 = (const float*)d_in[10]; const float* e_b1 = (const float*)d_in[11];
  const float* e_w2 = (const float*)d_in[12]; const float* e_b2 = (const float*)d_in[13];
  const float* l_w1 = (const float*)d_in[14]; const float* l_b1 = (const float*)d_in[15];
  const float* l_w2 = (const float*)d_in[16]; const float* l_b2 = (const float*)d_in[17];
  const float* c_w1 = (const float*)d_in[18]; const float* c_b1 = (const float*)d_in[19];
  const float* c_w2 = (const float*)d_in[20]; const float* c_b2 = (const float*)d_in[21];
  const float* p_w1 = (const float*)d_in[22]; const float* p_b1 = (const float*)d_in[23];
  const float* p_w2 = (const float*)d_in[24]; const float* p_b2 = (const float*)d_in[25];
  const float* x_w1 = (const float*)d_in[26]; const float* x_b1 = (const float*)d_in[27];
  const float* x_w2 = (const float*)d_in[28]; const float* x_b2 = (const float*)d_in[29];
  const float* fp_w = (const float*)d_in[30]; const float* fp_b = (const float*)d_in[31];
  const float* attn_w = (const float*)d_in[32]; const float* attn_b = (const float*)d_in[33];
  const float* out_w = (const float*)d_in[34]; const float* out_b = (const float*)d_in[35];
  const float* g_w1 = (const float*)d_in[36]; const float* g_b1 = (const float*)d_in[37];
  const float* g_w2 = (const float*)d_in[38]; const float* g_b2 = (const float*)d_in[39];
  const float* g_w3 = (const float*)d_in[40]; const float* g_b3 = (const float*)d_in[41];
  const float* g_w4 = (const float*)d_in[42]; const float* g_b4 = (const float*)d_in[43];

  // Workspace layout (fp32 elements; all sizes multiples of 4 -> 16B aligned)
  float* ws   = (float*)d_ws;
  float* G_f  = ws;                       // 512*256
  float* G_r  = G_f  + 512 * 256;
  float* Wt_f = G_r  + 512 * 256;         // 64*256
  float* Wt_r = Wt_f + 64 * 256;
  float* hfw  = Wt_r + 64 * 256;          // B*64
  float* hrw  = hfw  + BATCH * 64;
  float* entw = hrw  + BATCH * 64;        // B
  float* vlnw = entw + BATCH;             // B
  float* patw = vlnw + BATCH;             // B*6
  float* cpxw = patw + BATCH * 6;         // B*4
  unsigned int* cntw = (unsigned int*)(cpxw + BATCH * 4);  // B*128 uints
  float* M1  = (float*)(cntw + BATCH * 128);  // 184*180
  float* b1  = M1 + 184 * 180;                // 184
  float* M2  = b1 + 184;                      // 184*180
  float* b2  = M2 + 184 * 180;                // 184
  float* C1  = b2 + 184;                      // 128*180
  float* c1b = C1 + 128 * 180;                // 128

  const float* wv = attn_w + 2 * ADJ * ADJ;
  const float* bv = attn_b + 2 * ADJ;

  k_stats<<<dim3(BATCH / 4), dim3(256), 0, stream>>>(x, entw, vlnw, patw, cpxw, cntw);
  k_gtab<<<dim3(128), dim3(256), 0, stream>>>(emb, wih_f, bih_f, bhh_f,
                                              wih_r, bih_r, bhh_r, G_f, G_r);
  k_wt<<<dim3(2), dim3(256), 0, stream>>>(whh_f, whh_r, Wt_f, Wt_r);
  k_prep<<<dim3(ADJ), dim3(192), 0, stream>>>(wv, fp_w, fp_b, bv, M1, b1);
  k_prep<<<dim3(ADJ), dim3(192), 0, stream>>>(out_w, M1, b1, out_b, M2, b2);
  k_prep<<<dim3(128), dim3(192), 0, stream>>>(g_w1, M2, b2, g_b1, C1, c1b);
  k_lstm<<<dim3(512), dim3(256), 0, stream>>>(x, G_f, G_r, Wt_f, Wt_r, hfw, hrw);
  k_head<<<dim3(BATCH / 8), dim3(256), 0, stream>>>(
      hfw, hrw, entw, vlnw, patw, cpxw, (const unsigned char*)cntw,
      e_w1, e_b1, e_w2, e_b2, l_w1, l_b1, l_w2, l_b2,
      c_w1, c_b1, c_w2, c_b2, p_w1, p_b1, p_w2, p_b2,
      x_w1, x_b1, x_w2, x_b2, C1, c1b,
      g_w2, g_b2, g_w3, g_b3, g_w4, g_b4,
      (float*)d_out);
}

// Round 3
// 353.345 us; speedup vs baseline: 3.7703x; 1.7617x over previous
//
#include <hip/hip_runtime.h>

// Problem constants
#define BATCH 4096
#define SEQL  60
#define VOC   512
#define EMBD  128
#define HID   64
#define GATES 256
#define ADJ   184

typedef __attribute__((ext_vector_type(8))) short short8;
typedef __attribute__((ext_vector_type(4))) float f32x4;

__device__ __forceinline__ float sigm(float x) {
  return __builtin_amdgcn_rcpf(1.f + __expf(-x));
}
__device__ __forceinline__ float tanh_(float x) {
  float e = __expf(2.f * x);
  return 1.f - 2.f * __builtin_amdgcn_rcpf(e + 1.f);
}
__device__ __forceinline__ unsigned short f2bf(float f) {
  unsigned int u = __float_as_uint(f);
  unsigned int r = (u + 0x7fffu + ((u >> 16) & 1u)) >> 16;
  return (unsigned short)r;
}
__device__ __forceinline__ float dot4(float4 a, float4 b, float acc) {
  acc = fmaf(a.x, b.x, acc); acc = fmaf(a.y, b.y, acc);
  acc = fmaf(a.z, b.z, acc); acc = fmaf(a.w, b.w, acc);
  return acc;
}

__device__ __forceinline__ float wsumf(float v) {
  #pragma unroll
  for (int s = 32; s > 0; s >>= 1) v += __shfl_xor(v, s, 64);
  return v;
}
__device__ __forceinline__ int wsumi(int v) {
  #pragma unroll
  for (int s = 32; s > 0; s >>= 1) v += __shfl_xor(v, s, 64);
  return v;
}
__device__ __forceinline__ int wmaxi(int v) {
  #pragma unroll
  for (int s = 32; s > 0; s >>= 1) v = max(v, __shfl_xor(v, s, 64));
  return v;
}

// ---------------------------------------------------------------------------
// Kernel 1: per-row sequence statistics, one WAVE per row. (unchanged)
// ---------------------------------------------------------------------------
__global__ __launch_bounds__(256) void k_stats(
    const int* __restrict__ x,
    float* __restrict__ ent_o, float* __restrict__ vlen_o,
    float* __restrict__ pat_o, float* __restrict__ cpx_o,
    unsigned int* __restrict__ cnt_o) {
  __shared__ unsigned int cnt[4][512];
  __shared__ unsigned short q[4][68];
  const int tid = threadIdx.x;
  const int lane = tid & 63;
  const int wid = tid >> 6;
  const int row = blockIdx.x * 4 + wid;
  unsigned int* cr = cnt[wid];
  unsigned short* qr = q[wid];

  for (int i = lane; i < 512; i += 64) cr[i] = 0u;
  qr[lane] = 0;
  if (lane < 4) qr[64 + lane] = 0;
  int v = (lane < 60) ? x[row * 60 + lane] : 0;
  bool act = (v != 0);
  unsigned long long amask = __ballot(act);
  int n = __popcll(amask);
  __syncthreads();
  if (act) {
    int pos = __popcll(amask & ((1ull << lane) - 1ull));
    qr[pos] = (unsigned short)v;
    atomicAdd(&cr[v], 1u);
  }
  __syncthreads();

  float vlenf = (float)(n >= 1 ? n : 1);
  float inv = 1.f / vlenf;

  float ent = 0.f; int distinct = 0;
  #pragma unroll
  for (int j = 0; j < 8; j++) {
    unsigned int c = cr[lane + j * 64];
    if (c) {
      distinct++;
      float p = (float)c * inv;
      ent -= p * __logf(p + 1e-8f);
    }
  }
  ent = wsumf(ent);
  distinct = wsumi(distinct);

  int a = qr[lane], b = qr[lane + 1], c2 = qr[lane + 2];
  bool v1 = (lane + 1 < n);
  bool v2 = (lane + 2 < n);
  int rep  = __popcll(__ballot(v1 && (a == b)));
  int incs = __popcll(__ballot(v1 && (b > a)));
  int decs = __popcll(__ballot(v1 && (b < a)));
  int per2 = __popcll(__ballot(v2 && (a == c2)));

  int prev = (lane > 0) ? (int)qr[lane - 1] : -1;
  bool isst = (lane < n) && (lane == 0 || a != prev);
  unsigned long long smask = __ballot(isst);
  int len = 0;
  if (isst) {
    unsigned long long hi = (lane < 63) ? (smask >> (lane + 1)) : 0ull;
    int next = hi ? (lane + __ffsll((unsigned long long)hi)) : n;
    len = next - lane;
  }
  int maxrun = wmaxi(len);

  int unique = 1;
  int lim = v1 ? lane : 0;
  for (int jj = 0; jj < lim; jj++) {
    if ((int)qr[jj] == a && (int)qr[jj + 1] == b) { unique = 0; break; }
  }
  int dc = __popcll(__ballot(v1 && unique));

  int wl = n >> 1; if (wl > 5) wl = 5;
  float local = 0.f;
  if (wl >= 2) {
    bool pv = (lane + wl <= n);
    int u = 0;
    if (pv) {
      int t0 = qr[lane], t1 = qr[lane + 1], t2 = qr[lane + 2];
      int t3 = qr[lane + 3], t4 = qr[lane + 4];
      u = 1;
      u += (t1 != t0);
      if (wl >= 3) u += (int)((t2 != t1) && (t2 != t0));
      if (wl >= 4) u += (int)((t3 != t2) && (t3 != t1) && (t3 != t0));
      if (wl >= 5) u += (int)((t4 != t3) && (t4 != t2) && (t4 != t1) && (t4 != t0));
    }
    int usum = wsumi(u);
    int denw = n - wl + 1; if (denw < 1) denw = 1;
    local = (float)usum / (float)wl / (float)denw;
  }

  float den1 = (float)((n - 1) >= 1 ? (n - 1) : 1);
  float repeat = (float)rep / den1;
  float incf = (float)incs / den1;
  float decf = (float)decs / den1;
  float per = (n >= 4) ? (float)per2 / (float)((n - 2) >= 1 ? (n - 2) : 1) : 0.f;
  float diversity = (float)distinct * inv;
  float max_rep = (float)maxrun * inv;
  float comp_ratio = (float)dc / den1;
  float entz = (n > 1) ? ent : 0.f;
  float info_density = entz / __logf((float)(n >= 2 ? n : 2));
  float z = (n > 1) ? 1.f : 0.f;

  if (lane == 0) {
    ent_o[row] = entz;
    vlen_o[row] = (float)n;
    pat_o[row * 6 + 0] = repeat * z;
    pat_o[row * 6 + 1] = incf * z;
    pat_o[row * 6 + 2] = decf * z;
    pat_o[row * 6 + 3] = per * z;
    pat_o[row * 6 + 4] = diversity * z;
    pat_o[row * 6 + 5] = max_rep * z;
    cpx_o[row * 4 + 0] = comp_ratio * z;
    cpx_o[row * 4 + 1] = info_density * z;
    cpx_o[row * 4 + 2] = local * z;
    cpx_o[row * 4 + 3] = (1.f - repeat) * z;
  }
  for (int i = lane; i < 128; i += 64) {
    unsigned int p = cr[4 * i] | (cr[4 * i + 1] << 8) |
                     (cr[4 * i + 2] << 16) | (cr[4 * i + 3] << 24);
    cnt_o[row * 128 + i] = p;
  }
}

// ---------------------------------------------------------------------------
// Kernel 2: G[v][j] = w_ih[j,:]·emb[v,:] + b_ih[j] + b_hh[j]  (both dirs).
// Register-blocked, global-direct float4 reads (L1/L2 resident), no LDS.
// Grid 128 = 2 dirs x 16 v-chunks(32) x 4 j-chunks(64); 256 threads.
// Thread computes 2 v-rows x 4 j-cols.
// ---------------------------------------------------------------------------
__global__ __launch_bounds__(256) void k_gtab(
    const float* __restrict__ emb,
    const float* __restrict__ wf, const float* __restrict__ bif, const float* __restrict__ bhf,
    const float* __restrict__ wr, const float* __restrict__ bir, const float* __restrict__ bhr,
    float* __restrict__ G_f, float* __restrict__ G_r) {
  const int bx = blockIdx.x;
  const int dir = bx >> 6;
  const int rem = bx & 63;
  const int v0 = (rem >> 2) * 32;
  const int j0 = (rem & 3) * 64;
  const float* W = dir ? wr : wf;
  const float* bi = dir ? bir : bif;
  const float* bh = dir ? bhr : bhf;
  float* G = dir ? G_r : G_f;
  const int tid = threadIdx.x;
  const int vp = tid >> 4;          // 0..15 -> v pair
  const int jq = tid & 15;          // 0..15 -> j quad
  const int v = v0 + vp * 2;
  const int j = j0 + jq * 4;

  const float4* E0 = (const float4*)(emb + (size_t)v * 128);
  const float4* E1 = (const float4*)(emb + (size_t)(v + 1) * 128);
  const float4* W0 = (const float4*)(W + (size_t)j * 128);
  const float4* W1 = (const float4*)(W + (size_t)(j + 1) * 128);
  const float4* W2 = (const float4*)(W + (size_t)(j + 2) * 128);
  const float4* W3 = (const float4*)(W + (size_t)(j + 3) * 128);

  float a00 = 0.f, a01 = 0.f, a02 = 0.f, a03 = 0.f;
  float a10 = 0.f, a11 = 0.f, a12 = 0.f, a13 = 0.f;
  #pragma unroll 4
  for (int d4 = 0; d4 < 32; d4++) {
    float4 e0 = E0[d4], e1 = E1[d4];
    float4 w0 = W0[d4], w1 = W1[d4], w2 = W2[d4], w3 = W3[d4];
    a00 = dot4(e0, w0, a00); a01 = dot4(e0, w1, a01);
    a02 = dot4(e0, w2, a02); a03 = dot4(e0, w3, a03);
    a10 = dot4(e1, w0, a10); a11 = dot4(e1, w1, a11);
    a12 = dot4(e1, w2, a12); a13 = dot4(e1, w3, a13);
  }
  float4 bb = *(const float4*)(bi + j);
  float4 bh4 = *(const float4*)(bh + j);
  float4 o0, o1;
  o0.x = a00 + bb.x + bh4.x; o0.y = a01 + bb.y + bh4.y;
  o0.z = a02 + bb.z + bh4.z; o0.w = a03 + bb.w + bh4.w;
  o1.x = a10 + bb.x + bh4.x; o1.y = a11 + bb.y + bh4.y;
  o1.z = a12 + bb.z + bh4.z; o1.w = a13 + bb.w + bh4.w;
  *(float4*)(G + (size_t)v * 256 + j) = o0;
  *(float4*)(G + (size_t)(v + 1) * 256 + j) = o1;
}

// ---------------------------------------------------------------------------
// Kernel 2b: precompute W_hh bf16 MFMA B-operand fragments.
// Layout: Wfrag[((dir*4 + w)*4 + gg)*2 + c][lane][j] (8 bf16 = 16 B per lane).
// B[k][n] = whh[n*64 + k], n = gg*64 + w*16 + (lane&15), k = c*32+(lane>>4)*8+j.
// ---------------------------------------------------------------------------
__global__ __launch_bounds__(256) void k_wfrag(
    const float* __restrict__ whh_f, const float* __restrict__ whh_r,
    unsigned short* __restrict__ Wfrag) {
  const int id = blockIdx.x * 256 + threadIdx.x;   // 0..4095
  const int lane = id & 63;
  const int fc = id >> 6;                          // 0..63
  const int c = fc & 1;
  const int gg = (fc >> 1) & 3;
  const int w = (fc >> 3) & 3;
  const int dir = fc >> 5;
  const float* whh = dir ? whh_r : whh_f;
  const int n = gg * 64 + w * 16 + (lane & 15);
  const int kb = c * 32 + (lane >> 4) * 8;
  unsigned short* o = Wfrag + (size_t)id * 8;
  #pragma unroll
  for (int j = 0; j < 8; j++) o[j] = f2bf(whh[n * 64 + kb + j]);
}

// ---------------------------------------------------------------------------
// Kernel 2c: small matmul for head collapse (K=184, N=180). 4 accumulators.
// ---------------------------------------------------------------------------
__global__ __launch_bounds__(192) void k_prep(
    const float* __restrict__ A, const float* __restrict__ Bm,
    const float* __restrict__ bin, const float* __restrict__ badd,
    float* __restrict__ Mo, float* __restrict__ bo) {
  const int i = blockIdx.x, j = threadIdx.x;
  if (j < 180) {
    float a0 = 0.f, a1 = 0.f, a2 = 0.f, a3 = 0.f;
    for (int k = 0; k < ADJ; k += 4) {
      a0 = fmaf(A[i * ADJ + k],     Bm[(k)     * 180 + j], a0);
      a1 = fmaf(A[i * ADJ + k + 1], Bm[(k + 1) * 180 + j], a1);
      a2 = fmaf(A[i * ADJ + k + 2], Bm[(k + 2) * 180 + j], a2);
      a3 = fmaf(A[i * ADJ + k + 3], Bm[(k + 3) * 180 + j], a3);
    }
    Mo[i * 180 + j] = (a0 + a1) + (a2 + a3);
  } else if (j == 180) {
    float a0 = 0.f, a1 = 0.f;
    for (int k = 0; k < ADJ; k += 2) {
      a0 = fmaf(A[i * ADJ + k], bin[k], a0);
      a1 = fmaf(A[i * ADJ + k + 1], bin[k + 1], a1);
    }
    bo[i] = a0 + a1 + badd[i];
  }
}

// ---------------------------------------------------------------------------
// Kernel 3: MFMA LSTM. 512 blocks (256/dir) x 256 threads, 16 rows/block.
// Wave w owns hidden units [w*16, w*16+16) for ALL FOUR gate groups -> the
// activation is fully in-register (c-state in VGPRs). W_hh bf16 B-fragments
// pinned in VGPRs for all 60 steps. h round-trips LDS (bf16, stride 72,
// double-buffered) -> one barrier/step. G (fp32) prefetched one step ahead.
// ---------------------------------------------------------------------------
__global__ __launch_bounds__(256) void k_lstm(
    const int* __restrict__ x,
    const float* __restrict__ G_f, const float* __restrict__ G_r,
    const unsigned short* __restrict__ Wfrag,
    float* __restrict__ hf_o, float* __restrict__ hr_o) {
  __shared__ __align__(16) unsigned short hbuf[2][16 * 72];
  __shared__ unsigned short tokp[60 * 16];
  const int tid = threadIdx.x;
  const int lane = tid & 63;
  const int w = tid >> 6;
  const int dir = blockIdx.x >> 8;
  const int blk = blockIdx.x & 255;
  const int b0 = blk << 4;
  const float* G = dir ? G_r : G_f;
  float* ho = dir ? hr_o : hf_o;

  // tokens, transposed to [t][row]
  for (int i = tid; i < 960; i += 256) {
    int r = i / 60, t = i - r * 60;
    tokp[t * 16 + r] = (unsigned short)x[(size_t)(b0 + r) * 60 + t];
  }
  for (int i = tid; i < 16 * 72; i += 256) hbuf[0][i] = 0;

  // B fragments: 4 gate groups x 2 K-chunks, pinned in registers
  short8 bfr[4][2];
  #pragma unroll
  for (int gg = 0; gg < 4; gg++)
    #pragma unroll
    for (int c = 0; c < 2; c++) {
      int idx = (((dir * 4 + w) * 4 + gg) * 2 + c) * 64 + lane;
      bfr[gg][c] = *(const short8*)(Wfrag + (size_t)idx * 8);
    }

  const int kg = lane >> 4;      // 0..3 (K-chunk group for A; row group for D)
  const int ln = lane & 15;
  const int u = w * 16 + ln;     // hidden unit owned by this lane
  float cst[4] = {0.f, 0.f, 0.f, 0.f};
  float gv[4][4];                // [gate][reg] current-step G values

  __syncthreads();               // tokens + hbuf[0] ready

  {
    int ts0 = dir ? 59 : 0;
    int tk[4];
    #pragma unroll
    for (int r = 0; r < 4; r++) tk[r] = tokp[ts0 * 16 + kg * 4 + r];
    #pragma unroll
    for (int gg = 0; gg < 4; gg++)
      #pragma unroll
      for (int r = 0; r < 4; r++)
        gv[gg][r] = G[(size_t)tk[r] * 256 + gg * 64 + u];
  }

  #pragma unroll 1
  for (int t = 0; t < 60; t++) {
    const unsigned short* hb = hbuf[t & 1];
    // A fragments: A[m=ln][k = c*32 + kg*8 + j]
    short8 a0 = *(const short8*)(hb + ln * 72 + kg * 8);
    short8 a1 = *(const short8*)(hb + ln * 72 + 32 + kg * 8);

    // prefetch next step's G
    float gnx[4][4];
    if (t < 59) {
      int tsn = dir ? (58 - t) : (t + 1);
      int tkn[4];
      #pragma unroll
      for (int r = 0; r < 4; r++) tkn[r] = tokp[tsn * 16 + kg * 4 + r];
      #pragma unroll
      for (int gg = 0; gg < 4; gg++)
        #pragma unroll
        for (int r = 0; r < 4; r++)
          gnx[gg][r] = G[(size_t)tkn[r] * 256 + gg * 64 + u];
    }

    f32x4 acc[4];
    #pragma unroll
    for (int gg = 0; gg < 4; gg++) {
      f32x4 z = {0.f, 0.f, 0.f, 0.f};
      z = __builtin_amdgcn_mfma_f32_16x16x32_bf16(a0, bfr[gg][0], z, 0, 0, 0);
      z = __builtin_amdgcn_mfma_f32_16x16x32_bf16(a1, bfr[gg][1], z, 0, 0, 0);
      acc[gg] = z;
    }

    unsigned short* hw = hbuf[(t + 1) & 1];
    float hout[4];
    #pragma unroll
    for (int r = 0; r < 4; r++) {
      float gi = acc[0][r] + gv[0][r];
      float gf = acc[1][r] + gv[1][r];
      float gc = acc[2][r] + gv[2][r];
      float go = acc[3][r] + gv[3][r];
      float cn = sigm(gf) * cst[r] + sigm(gi) * tanh_(gc);
      cst[r] = cn;
      float h = sigm(go) * tanh_(cn);
      hout[r] = h;
      hw[(kg * 4 + r) * 72 + u] = f2bf(h);   // D row = (lane>>4)*4 + reg
    }
    if (t == 59) {
      #pragma unroll
      for (int r = 0; r < 4; r++)
        ho[(size_t)(b0 + kg * 4 + r) * 64 + u] = hout[r];
    }
    if (t < 59) {
      #pragma unroll
      for (int gg = 0; gg < 4; gg++)
        #pragma unroll
        for (int r = 0; r < 4; r++)
          gv[gg][r] = gnx[gg][r];
    }
    __syncthreads();
  }
}

// ---------------------------------------------------------------------------
// Kernel 4: feature assembly + collapsed head (180->128->64->32->4) + softmax.
// (unchanged from round 2)
// ---------------------------------------------------------------------------
#define FSTR 192

__global__ __launch_bounds__(256) void k_head(
    const float* __restrict__ hf, const float* __restrict__ hr,
    const float* __restrict__ ent, const float* __restrict__ vlen,
    const float* __restrict__ pat, const float* __restrict__ cpx,
    const unsigned char* __restrict__ cnts,
    const float* __restrict__ e_w1, const float* __restrict__ e_b1,
    const float* __restrict__ e_w2, const float* __restrict__ e_b2,
    const float* __restrict__ l_w1, const float* __restrict__ l_b1,
    const float* __restrict__ l_w2, const float* __restrict__ l_b2,
    const float* __restrict__ c_w1, const float* __restrict__ c_b1,
    const float* __restrict__ c_w2, const float* __restrict__ c_b2,
    const float* __restrict__ p_w1, const float* __restrict__ p_b1,
    const float* __restrict__ p_w2, const float* __restrict__ p_b2,
    const float* __restrict__ x_w1, const float* __restrict__ x_b1,
    const float* __restrict__ x_w2, const float* __restrict__ x_b2,
    const float* __restrict__ C1, const float* __restrict__ c1b,
    const float* __restrict__ g_w2, const float* __restrict__ g_b2,
    const float* __restrict__ g_w3, const float* __restrict__ g_b3,
    const float* __restrict__ g_w4, const float* __restrict__ g_b4,
    float* __restrict__ out) {
  __shared__ float feat[8 * FSTR];
  __shared__ float h1[8 * 128];
  __shared__ float h2[8 * 64];
  __shared__ float h3[8 * 32];
  __shared__ float h1c[8 * 33];
  __shared__ float lg[8 * 4];
  const int tid = threadIdx.x;
  const int b0 = blockIdx.x * 8;

  if (tid < 128) {
    int r = tid >> 4, c = tid & 15;
    float4 vv = ((const float4*)(hf + (size_t)(b0 + r) * 64))[c];
    *(float4*)(feat + r * FSTR + c * 4) = vv;
  } else {
    int t = tid - 128;
    int r = t >> 4, c = t & 15;
    float4 vv = ((const float4*)(hr + (size_t)(b0 + r) * 64))[c];
    *(float4*)(feat + r * FSTR + 64 + c * 4) = vv;
  }
  {
    int r = tid >> 5, o = tid & 31;
    const unsigned int* cb = (const unsigned int*)(cnts + (size_t)(b0 + r) * 512);
    float invv = __builtin_amdgcn_rcpf(fmaxf(vlen[b0 + r], 1.f));
    const float* wr_ = c_w1 + o * 512;
    float a0 = 0.f, a1 = 0.f;
    for (int v4 = 0; v4 < 128; v4 += 2) {
      unsigned int u0 = cb[v4], u1 = cb[v4 + 1];
      const float* w4 = wr_ + v4 * 4;
      a0 = fmaf((float)(u0 & 255u), w4[0], a0);
      a0 = fmaf((float)((u0 >> 8) & 255u), w4[1], a0);
      a0 = fmaf((float)((u0 >> 16) & 255u), w4[2], a0);
      a0 = fmaf((float)(u0 >> 24), w4[3], a0);
      a1 = fmaf((float)(u1 & 255u), w4[4], a1);
      a1 = fmaf((float)((u1 >> 8) & 255u), w4[5], a1);
      a1 = fmaf((float)((u1 >> 16) & 255u), w4[6], a1);
      a1 = fmaf((float)(u1 >> 24), w4[7], a1);
    }
    h1c[r * 33 + o] = fmaxf((a0 + a1) * invv + c_b1[o], 0.f);
  }
  if (tid < 32) {
    const int m = tid & 3, r = tid >> 2, b = b0 + r;
    float tt[24];
    if (m == 0) {
      float ein = ent[b] * 0.25f;
      #pragma unroll
      for (int o = 0; o < 16; o++) tt[o] = fmaxf(e_w1[o] * ein + e_b1[o], 0.f);
      #pragma unroll
      for (int o = 0; o < 8; o++) {
        float a = e_b2[o];
        #pragma unroll
        for (int k = 0; k < 16; k++) a = fmaf(e_w2[o * 16 + k], tt[k], a);
        feat[r * FSTR + 128 + o] = a;
      }
    } else if (m == 1) {
      float lin = vlen[b] * (1.f / 60.f);
      #pragma unroll
      for (int o = 0; o < 16; o++) tt[o] = fmaxf(l_w1[o] * lin + l_b1[o], 0.f);
      #pragma unroll
      for (int o = 0; o < 8; o++) {
        float a = l_b2[o];
        #pragma unroll
        for (int k = 0; k < 16; k++) a = fmaf(l_w2[o * 16 + k], tt[k], a);
        feat[r * FSTR + 136 + o] = a;
      }
    } else if (m == 2) {
      float pin[6];
      #pragma unroll
      for (int k = 0; k < 6; k++) pin[k] = pat[b * 6 + k];
      #pragma unroll
      for (int o = 0; o < 24; o++) {
        float a = p_b1[o];
        #pragma unroll
        for (int k = 0; k < 6; k++) a = fmaf(p_w1[o * 6 + k], pin[k], a);
        tt[o] = fmaxf(a, 0.f);
      }
      #pragma unroll
      for (int o = 0; o < 12; o++) {
        float a = p_b2[o];
        #pragma unroll
        for (int k = 0; k < 24; k++) a = fmaf(p_w2[o * 24 + k], tt[k], a);
        feat[r * FSTR + 160 + o] = a;
      }
    } else {
      float xin[4];
      #pragma unroll
      for (int k = 0; k < 4; k++) xin[k] = cpx[b * 4 + k];
      #pragma unroll
      for (int o = 0; o < 16; o++) {
        float a = x_b1[o];
        #pragma unroll
        for (int k = 0; k < 4; k++) a = fmaf(x_w1[o * 4 + k], xin[k], a);
        tt[o] = fmaxf(a, 0.f);
      }
      #pragma unroll
      for (int o = 0; o < 8; o++) {
        float a = x_b2[o];
        #pragma unroll
        for (int k = 0; k < 16; k++) a = fmaf(x_w2[o * 16 + k], tt[k], a);
        feat[r * FSTR + 172 + o] = a;
      }
    }
  }
  __syncthreads();
  if (tid < 128) {
    int r = tid >> 4, o = tid & 15;
    float a = c_b2[o];
    const float* hh = h1c + r * 33;
    #pragma unroll
    for (int k = 0; k < 32; k++) a = fmaf(c_w2[o * 32 + k], hh[k], a);
    feat[r * FSTR + 144 + o] = a;
  }
  __syncthreads();

  {
    int o = tid & 127, rg = tid >> 7;
    const float4* w = (const float4*)(C1 + o * 180);
    float a0 = 0.f, a1 = 0.f, a2 = 0.f, a3 = 0.f;
    const float* f0p = feat + (rg * 4 + 0) * FSTR;
    const float* f1p = feat + (rg * 4 + 1) * FSTR;
    const float* f2p = feat + (rg * 4 + 2) * FSTR;
    const float* f3p = feat + (rg * 4 + 3) * FSTR;
    #pragma unroll 5
    for (int k4 = 0; k4 < 45; k4++) {
      float4 w4 = w[k4];
      float4 f0 = *(const float4*)(f0p + k4 * 4);
      float4 f1 = *(const float4*)(f1p + k4 * 4);
      float4 f2 = *(const float4*)(f2p + k4 * 4);
      float4 f3 = *(const float4*)(f3p + k4 * 4);
      a0 = fmaf(w4.x, f0.x, a0); a0 = fmaf(w4.y, f0.y, a0);
      a0 = fmaf(w4.z, f0.z, a0); a0 = fmaf(w4.w, f0.w, a0);
      a1 = fmaf(w4.x, f1.x, a1); a1 = fmaf(w4.y, f1.y, a1);
      a1 = fmaf(w4.z, f1.z, a1); a1 = fmaf(w4.w, f1.w, a1);
      a2 = fmaf(w4.x, f2.x, a2); a2 = fmaf(w4.y, f2.y, a2);
      a2 = fmaf(w4.z, f2.z, a2); a2 = fmaf(w4.w, f2.w, a2);
      a3 = fmaf(w4.x, f3.x, a3); a3 = fmaf(w4.y, f3.y, a3);
      a3 = fmaf(w4.z, f3.z, a3); a3 = fmaf(w4.w, f3.w, a3);
    }
    float bb = c1b[o];
    h1[(rg * 4 + 0) * 128 + o] = fmaxf(a0 + bb, 0.f);
    h1[(rg * 4 + 1) * 128 + o] = fmaxf(a1 + bb, 0.f);
    h1[(rg * 4 + 2) * 128 + o] = fmaxf(a2 + bb, 0.f);
    h1[(rg * 4 + 3) * 128 + o] = fmaxf(a3 + bb, 0.f);
  }
  __syncthreads();
  {
    int o = tid & 63, rg = tid >> 6;
    const float4* w = (const float4*)(g_w2 + o * 128);
    float a0 = 0.f, a1 = 0.f;
    const float* f0p = h1 + (rg * 2 + 0) * 128;
    const float* f1p = h1 + (rg * 2 + 1) * 128;
    #pragma unroll 4
    for (int k4 = 0; k4 < 32; k4++) {
      float4 w4 = w[k4];
      float4 f0 = *(const float4*)(f0p + k4 * 4);
      float4 f1 = *(const float4*)(f1p + k4 * 4);
      a0 = fmaf(w4.x, f0.x, a0); a0 = fmaf(w4.y, f0.y, a0);
      a0 = fmaf(w4.z, f0.z, a0); a0 = fmaf(w4.w, f0.w, a0);
      a1 = fmaf(w4.x, f1.x, a1); a1 = fmaf(w4.y, f1.y, a1);
      a1 = fmaf(w4.z, f1.z, a1); a1 = fmaf(w4.w, f1.w, a1);
    }
    float bb = g_b2[o];
    h2[(rg * 2 + 0) * 64 + o] = fmaxf(a0 + bb, 0.f);
    h2[(rg * 2 + 1) * 64 + o] = fmaxf(a1 + bb, 0.f);
  }
  __syncthreads();
  {
    int o = tid & 31, rg = tid >> 5;
    const float4* w = (const float4*)(g_w3 + o * 64);
    float a = 0.f;
    const float* fp = h2 + rg * 64;
    #pragma unroll 4
    for (int k4 = 0; k4 < 16; k4++) {
      float4 w4 = w[k4];
      float4 f0 = *(const float4*)(fp + k4 * 4);
      a = fmaf(w4.x, f0.x, a); a = fmaf(w4.y, f0.y, a);
      a = fmaf(w4.z, f0.z, a); a = fmaf(w4.w, f0.w, a);
    }
    h3[rg * 32 + o] = fmaxf(a + g_b3[o], 0.f);
  }
  __syncthreads();
  if (tid < 32) {
    int r = tid >> 2, o = tid & 3;
    const float4* w = (const float4*)(g_w4 + o * 32);
    const float4* hh = (const float4*)(h3 + r * 32);
    float a = g_b4[o];
    #pragma unroll
    for (int k4 = 0; k4 < 8; k4++) {
      float4 w4 = w[k4], x4 = hh[k4];
      a = fmaf(w4.x, x4.x, a); a = fmaf(w4.y, x4.y, a);
      a = fmaf(w4.z, x4.z, a); a = fmaf(w4.w, x4.w, a);
    }
    lg[r * 4 + o] = a;
  }
  __syncthreads();
  if (tid < 8) {
    float l0 = lg[tid * 4 + 0], l1 = lg[tid * 4 + 1];
    float l2 = lg[tid * 4 + 2], l3 = lg[tid * 4 + 3];
    float m = fmaxf(fmaxf(l0, l1), fmaxf(l2, l3));
    float e0 = __expf(l0 - m), e1 = __expf(l1 - m);
    float e2 = __expf(l2 - m), e3 = __expf(l3 - m);
    float is = __builtin_amdgcn_rcpf(e0 + e1 + e2 + e3);
    float4 o4; o4.x = e0 * is; o4.y = e1 * is; o4.z = e2 * is; o4.w = e3 * is;
    *(float4*)(out + (size_t)(b0 + tid) * 4) = o4;
  }
}

// ---------------------------------------------------------------------------
extern "C" void kernel_launch(void* const* d_in, const int* in_sizes, int n_in,
                              void* d_out, int out_size, void* d_ws, size_t ws_size,
                              hipStream_t stream) {
  const int*   x     = (const int*)d_in[0];
  const float* emb   = (const float*)d_in[1];
  const float* wih_f = (const float*)d_in[2];
  const float* whh_f = (const float*)d_in[3];
  const float* bih_f = (const float*)d_in[4];
  const float* bhh_f = (const float*)d_in[5];
  const float* wih_r = (const float*)d_in[6];
  const float* whh_r = (const float*)d_in[7];
  const float* bih_r = (const float*)d_in[8];
  const float* bhh_r = (const float*)d_in[9];
  const float* e_w1 = (const float*)d_in[10]; const float* e_b1 = (const float*)d_in[11];
  const float* e_w2 = (const float*)d_in[12]; const float* e_b2 = (const float*)d_in[13];
  const float* l_w1 = (const float*)d_in[14]; const float* l_b1 = (const float*)d_in[15];
  const float* l_w2 = (const float*)d_in[16]; const float* l_b2 = (const float*)d_in[17];
  const float* c_w1 = (const float*)d_in[18]; const float* c_b1 = (const float*)d_in[19];
  const float* c_w2 = (const float*)d_in[20]; const float* c_b2 = (const float*)d_in[21];
  const float* p_w1 = (const float*)d_in[22]; const float* p_b1 = (const float*)d_in[23];
  const float* p_w2 = (const float*)d_in[24]; const float* p_b2 = (const float*)d_in[25];
  const float* x_w1 = (const float*)d_in[26]; const float* x_b1 = (const float*)d_in[27];
  const float* x_w2 = (const float*)d_in[28]; const float* x_b2 = (const float*)d_in[29];
  const float* fp_w = (const float*)d_in[30]; const float* fp_b = (const float*)d_in[31];
  const float* attn_w = (const float*)d_in[32]; const float* attn_b = (const float*)d_in[33];
  const float* out_w = (const float*)d_in[34]; const float* out_b = (const float*)d_in[35];
  const float* g_w1 = (const float*)d_in[36]; const float* g_b1 = (const float*)d_in[37];
  const float* g_w2 = (const float*)d_in[38]; const float* g_b2 = (const float*)d_in[39];
  const float* g_w3 = (const float*)d_in[40]; const float* g_b3 = (const float*)d_in[41];
  const float* g_w4 = (const float*)d_in[42]; const float* g_b4 = (const float*)d_in[43];

  float* ws   = (float*)d_ws;
  float* G_f  = ws;                       // 512*256
  float* G_r  = G_f  + 512 * 256;
  float* hfw  = G_r  + 512 * 256;         // B*64
  float* hrw  = hfw  + BATCH * 64;
  float* entw = hrw  + BATCH * 64;        // B
  float* vlnw = entw + BATCH;             // B
  float* patw = vlnw + BATCH;             // B*6
  float* cpxw = patw + BATCH * 6;         // B*4
  unsigned int* cntw = (unsigned int*)(cpxw + BATCH * 4);  // B*128 uints
  float* M1  = (float*)(cntw + BATCH * 128);  // 184*180
  float* b1  = M1 + 184 * 180;                // 184
  float* M2  = b1 + 184;                      // 184*180
  float* b2  = M2 + 184 * 180;                // 184
  float* C1  = b2 + 184;                      // 128*180
  float* c1b = C1 + 128 * 180;                // 128
  unsigned short* Wfrag = (unsigned short*)(c1b + 128);  // 32768 bf16 (64KB)

  const float* wv = attn_w + 2 * ADJ * ADJ;
  const float* bv = attn_b + 2 * ADJ;

  k_stats<<<dim3(BATCH / 4), dim3(256), 0, stream>>>(x, entw, vlnw, patw, cpxw, cntw);
  k_gtab<<<dim3(128), dim3(256), 0, stream>>>(emb, wih_f, bih_f, bhh_f,
                                              wih_r, bih_r, bhh_r, G_f, G_r);
  k_wfrag<<<dim3(16), dim3(256), 0, stream>>>(whh_f, whh_r, Wfrag);
  k_prep<<<dim3(ADJ), dim3(192), 0, stream>>>(wv, fp_w, fp_b, bv, M1, b1);
  k_prep<<<dim3(ADJ), dim3(192), 0, stream>>>(out_w, M1, b1, out_b, M2, b2);
  k_prep<<<dim3(128), dim3(192), 0, stream>>>(g_w1, M2, b2, g_b1, C1, c1b);
  k_lstm<<<dim3(512), dim3(256), 0, stream>>>(x, G_f, G_r, Wfrag, hfw, hrw);
  k_head<<<dim3(BATCH / 8), dim3(256), 0, stream>>>(
      hfw, hrw, entw, vlnw, patw, cpxw, (const unsigned char*)cntw,
      e_w1, e_b1, e_w2, e_b2, l_w1, l_b1, l_w2, l_b2,
      c_w1, c_b1, c_w2, c_b2, p_w1, p_b1, p_w2, p_b2,
      x_w1, x_b1, x_w2, x_b2, C1, c1b,
      g_w2, g_b2, g_w3, g_b3, g_w4, g_b4,
      (float*)d_out);
}

// Round 4
// 277.396 us; speedup vs baseline: 4.8026x; 1.2738x over previous
//
#include <hip/hip_runtime.h>

// Problem constants
#define BATCH 4096
#define SEQL  60
#define VOC   512
#define EMBD  128
#define HID   64
#define GATES 256
#define ADJ   184

typedef __attribute__((ext_vector_type(8))) short short8;
typedef __attribute__((ext_vector_type(4))) float f32x4;

__device__ __forceinline__ float sigm(float x) {
  return __builtin_amdgcn_rcpf(1.f + __expf(-x));
}
__device__ __forceinline__ float tanh_(float x) {
  float e = __expf(2.f * x);
  return 1.f - 2.f * __builtin_amdgcn_rcpf(e + 1.f);
}
__device__ __forceinline__ unsigned short f2bf(float f) {
  unsigned int u = __float_as_uint(f);
  unsigned int r = (u + 0x7fffu + ((u >> 16) & 1u)) >> 16;
  return (unsigned short)r;
}
__device__ __forceinline__ float dot4(float4 a, float4 b, float acc) {
  acc = fmaf(a.x, b.x, acc); acc = fmaf(a.y, b.y, acc);
  acc = fmaf(a.z, b.z, acc); acc = fmaf(a.w, b.w, acc);
  return acc;
}
__device__ __forceinline__ float wsumf(float v) {
  #pragma unroll
  for (int s = 32; s > 0; s >>= 1) v += __shfl_xor(v, s, 64);
  return v;
}
__device__ __forceinline__ int wsumi(int v) {
  #pragma unroll
  for (int s = 32; s > 0; s >>= 1) v += __shfl_xor(v, s, 64);
  return v;
}
__device__ __forceinline__ int wmaxi(int v) {
  #pragma unroll
  for (int s = 32; s > 0; s >>= 1) v = max(v, __shfl_xor(v, s, 64));
  return v;
}

// ---------------------------------------------------------------------------
// MEGA kernel: all mutually-independent prep work in ONE launch so
// latency-bound blocks overlap across CUs.
//   [0,1024)      k_stats   (wave-per-row sequence statistics)
//   [1024,1152)   k_gtab    (G[v][u][4 gates] = w_ih·emb + biases, both dirs)
//   [1152,1280)   A = g_w1·out_w (+ avb bias fold)
//   [1280,1464)   B = wv·fp_w    (+ vb bias fold)
//   [1464,1480)   Wfrag     (bf16 MFMA B-operand fragments of w_hh)
//   [1480]        transposes of g_w2/g_w3/g_w4
// ---------------------------------------------------------------------------
__global__ __launch_bounds__(256) void k_mega(
    const int* __restrict__ x, const float* __restrict__ emb,
    const float* __restrict__ wih_f, const float* __restrict__ bif, const float* __restrict__ bhf,
    const float* __restrict__ wih_r, const float* __restrict__ bir, const float* __restrict__ bhr,
    const float* __restrict__ whh_f, const float* __restrict__ whh_r,
    const float* __restrict__ g_w1, const float* __restrict__ g_b1,
    const float* __restrict__ out_w, const float* __restrict__ out_b,
    const float* __restrict__ attn_w, const float* __restrict__ attn_b,
    const float* __restrict__ fp_w, const float* __restrict__ fp_b,
    const float* __restrict__ g_w2, const float* __restrict__ g_w3,
    const float* __restrict__ g_w4,
    float* __restrict__ ent_o, float* __restrict__ vlen_o,
    float* __restrict__ pat_o, float* __restrict__ cpx_o,
    unsigned int* __restrict__ cnt_o,
    float* __restrict__ G_f, float* __restrict__ G_r,
    unsigned short* __restrict__ Wfrag,
    float* __restrict__ A, float* __restrict__ avb,
    float* __restrict__ Bp, float* __restrict__ vb,
    float* __restrict__ g_w2t, float* __restrict__ g_w3t, float* __restrict__ g_w4t) {
  __shared__ unsigned int cnt[4][512];
  __shared__ unsigned short q[4][68];
  const int bid = blockIdx.x;
  const int tid = threadIdx.x;

  if (bid < 1024) {
    // ---------------- per-row sequence statistics ----------------
    const int lane = tid & 63;
    const int wid = tid >> 6;
    const int row = bid * 4 + wid;
    unsigned int* cr = cnt[wid];
    unsigned short* qr = q[wid];

    for (int i = lane; i < 512; i += 64) cr[i] = 0u;
    qr[lane] = 0;
    if (lane < 4) qr[64 + lane] = 0;
    int v = (lane < 60) ? x[row * 60 + lane] : 0;
    bool act = (v != 0);
    unsigned long long amask = __ballot(act);
    int n = __popcll(amask);
    __syncthreads();
    if (act) {
      int pos = __popcll(amask & ((1ull << lane) - 1ull));
      qr[pos] = (unsigned short)v;
      atomicAdd(&cr[v], 1u);
    }
    __syncthreads();

    float vlenf = (float)(n >= 1 ? n : 1);
    float inv = 1.f / vlenf;

    float ent = 0.f; int distinct = 0;
    #pragma unroll
    for (int j = 0; j < 8; j++) {
      unsigned int c = cr[lane + j * 64];
      if (c) {
        distinct++;
        float p = (float)c * inv;
        ent -= p * __logf(p + 1e-8f);
      }
    }
    ent = wsumf(ent);
    distinct = wsumi(distinct);

    int a = qr[lane], b = qr[lane + 1], c2 = qr[lane + 2];
    bool v1 = (lane + 1 < n);
    bool v2 = (lane + 2 < n);
    int rep  = __popcll(__ballot(v1 && (a == b)));
    int incs = __popcll(__ballot(v1 && (b > a)));
    int decs = __popcll(__ballot(v1 && (b < a)));
    int per2 = __popcll(__ballot(v2 && (a == c2)));

    int prev = (lane > 0) ? (int)qr[lane - 1] : -1;
    bool isst = (lane < n) && (lane == 0 || a != prev);
    unsigned long long smask = __ballot(isst);
    int len = 0;
    if (isst) {
      unsigned long long hi = (lane < 63) ? (smask >> (lane + 1)) : 0ull;
      int next = hi ? (lane + __ffsll((unsigned long long)hi)) : n;
      len = next - lane;
    }
    int maxrun = wmaxi(len);

    int unique = 1;
    int lim = v1 ? lane : 0;
    for (int jj = 0; jj < lim; jj++) {
      if ((int)qr[jj] == a && (int)qr[jj + 1] == b) { unique = 0; break; }
    }
    int dc = __popcll(__ballot(v1 && unique));

    int wl = n >> 1; if (wl > 5) wl = 5;
    float local = 0.f;
    if (wl >= 2) {
      bool pv = (lane + wl <= n);
      int u = 0;
      if (pv) {
        int t0 = qr[lane], t1 = qr[lane + 1], t2 = qr[lane + 2];
        int t3 = qr[lane + 3], t4 = qr[lane + 4];
        u = 1;
        u += (t1 != t0);
        if (wl >= 3) u += (int)((t2 != t1) && (t2 != t0));
        if (wl >= 4) u += (int)((t3 != t2) && (t3 != t1) && (t3 != t0));
        if (wl >= 5) u += (int)((t4 != t3) && (t4 != t2) && (t4 != t1) && (t4 != t0));
      }
      int usum = wsumi(u);
      int denw = n - wl + 1; if (denw < 1) denw = 1;
      local = (float)usum / (float)wl / (float)denw;
    }

    float den1 = (float)((n - 1) >= 1 ? (n - 1) : 1);
    float repeat = (float)rep / den1;
    float per = (n >= 4) ? (float)per2 / (float)((n - 2) >= 1 ? (n - 2) : 1) : 0.f;
    float entz = (n > 1) ? ent : 0.f;
    float z = (n > 1) ? 1.f : 0.f;

    if (lane == 0) {
      ent_o[row] = entz;
      vlen_o[row] = (float)n;
      pat_o[row * 6 + 0] = repeat * z;
      pat_o[row * 6 + 1] = (float)incs / den1 * z;
      pat_o[row * 6 + 2] = (float)decs / den1 * z;
      pat_o[row * 6 + 3] = per * z;
      pat_o[row * 6 + 4] = (float)distinct * inv * z;
      pat_o[row * 6 + 5] = (float)maxrun * inv * z;
      cpx_o[row * 4 + 0] = (float)dc / den1 * z;
      cpx_o[row * 4 + 1] = entz / __logf((float)(n >= 2 ? n : 2)) * z;
      cpx_o[row * 4 + 2] = local * z;
      cpx_o[row * 4 + 3] = (1.f - repeat) * z;
    }
    for (int i = lane; i < 128; i += 64) {
      unsigned int p = cr[4 * i] | (cr[4 * i + 1] << 8) |
                       (cr[4 * i + 2] << 16) | (cr[4 * i + 3] << 24);
      cnt_o[row * 128 + i] = p;
    }
  } else if (bid < 1152) {
    // ---------------- G table, interleaved [v][u][gg] ----------------
    const int bx = bid - 1024;
    const int dir = bx >> 6;
    const int rem = bx & 63;
    const int v0 = (rem >> 2) * 32;
    const int j0 = (rem & 3) * 64;
    const float* W = dir ? wih_r : wih_f;
    const float* bi = dir ? bir : bif;
    const float* bh = dir ? bhr : bhf;
    float* G = dir ? G_r : G_f;
    const int vp = tid >> 4;
    const int jq = tid & 15;
    const int v = v0 + vp * 2;
    const int j = j0 + jq * 4;
    const int gg = j >> 6;
    const int u0 = j & 63;

    const float4* E0 = (const float4*)(emb + (size_t)v * 128);
    const float4* E1 = (const float4*)(emb + (size_t)(v + 1) * 128);
    const float4* W0 = (const float4*)(W + (size_t)j * 128);
    const float4* W1 = (const float4*)(W + (size_t)(j + 1) * 128);
    const float4* W2 = (const float4*)(W + (size_t)(j + 2) * 128);
    const float4* W3 = (const float4*)(W + (size_t)(j + 3) * 128);

    float a00 = 0.f, a01 = 0.f, a02 = 0.f, a03 = 0.f;
    float a10 = 0.f, a11 = 0.f, a12 = 0.f, a13 = 0.f;
    #pragma unroll 4
    for (int d4 = 0; d4 < 32; d4++) {
      float4 e0 = E0[d4], e1 = E1[d4];
      float4 w0 = W0[d4], w1 = W1[d4], w2 = W2[d4], w3 = W3[d4];
      a00 = dot4(e0, w0, a00); a01 = dot4(e0, w1, a01);
      a02 = dot4(e0, w2, a02); a03 = dot4(e0, w3, a03);
      a10 = dot4(e1, w0, a10); a11 = dot4(e1, w1, a11);
      a12 = dot4(e1, w2, a12); a13 = dot4(e1, w3, a13);
    }
    float b0v = bi[j] + bh[j], b1v = bi[j + 1] + bh[j + 1];
    float b2v = bi[j + 2] + bh[j + 2], b3v = bi[j + 3] + bh[j + 3];
    float* g0 = G + (size_t)v * 256 + u0 * 4 + gg;
    g0[0]  = a00 + b0v; g0[4]  = a01 + b1v;
    g0[8]  = a02 + b2v; g0[12] = a03 + b3v;
    float* g1 = g0 + 256;
    g1[0]  = a10 + b0v; g1[4]  = a11 + b1v;
    g1[8]  = a12 + b2v; g1[12] = a13 + b3v;
  } else if (bid < 1280) {
    // ---------------- A = g_w1 · out_w  (128 x 184), avb fold ----------------
    const int i = bid - 1152;
    const int j = tid;
    const float* g1r = g_w1 + (size_t)i * ADJ;
    if (j < ADJ) {
      float a0 = 0.f, a1 = 0.f, a2 = 0.f, a3 = 0.f;
      for (int k = 0; k < ADJ; k += 4) {
        a0 = fmaf(g1r[k],     out_w[(size_t)(k)     * ADJ + j], a0);
        a1 = fmaf(g1r[k + 1], out_w[(size_t)(k + 1) * ADJ + j], a1);
        a2 = fmaf(g1r[k + 2], out_w[(size_t)(k + 2) * ADJ + j], a2);
        a3 = fmaf(g1r[k + 3], out_w[(size_t)(k + 3) * ADJ + j], a3);
      }
      A[(size_t)i * ADJ + j] = (a0 + a1) + (a2 + a3);
    } else if (j == ADJ) {
      float a0 = 0.f;
      for (int k = 0; k < ADJ; k++) a0 = fmaf(g1r[k], out_b[k], a0);
      avb[i] = a0 + g_b1[i];
    }
  } else if (bid < 1464) {
    // ---------------- B = wv · fp_w  (184 x 180), vb fold ----------------
    const int k = bid - 1280;
    const int j = tid;
    const float* wvr = attn_w + (size_t)(2 * ADJ + k) * ADJ;
    if (j < 180) {
      float a0 = 0.f, a1 = 0.f, a2 = 0.f, a3 = 0.f;
      for (int m = 0; m < ADJ; m += 4) {
        a0 = fmaf(wvr[m],     fp_w[(size_t)(m)     * 180 + j], a0);
        a1 = fmaf(wvr[m + 1], fp_w[(size_t)(m + 1) * 180 + j], a1);
        a2 = fmaf(wvr[m + 2], fp_w[(size_t)(m + 2) * 180 + j], a2);
        a3 = fmaf(wvr[m + 3], fp_w[(size_t)(m + 3) * 180 + j], a3);
      }
      Bp[(size_t)k * 180 + j] = (a0 + a1) + (a2 + a3);
    } else if (j == 180) {
      float a0 = 0.f;
      for (int m = 0; m < ADJ; m++) a0 = fmaf(wvr[m], fp_b[m], a0);
      vb[k] = a0 + attn_b[2 * ADJ + k];
    }
  } else if (bid < 1480) {
    // ---------------- w_hh bf16 MFMA B-fragments ----------------
    const int id = (bid - 1464) * 256 + tid;
    const int lane = id & 63;
    const int fc = id >> 6;
    const int c = fc & 1;
    const int gg = (fc >> 1) & 3;
    const int w = (fc >> 3) & 3;
    const int dir = fc >> 5;
    const float* whh = dir ? whh_r : whh_f;
    const int n = gg * 64 + w * 16 + (lane & 15);
    const int kb = c * 32 + (lane >> 4) * 8;
    unsigned short* o = Wfrag + (size_t)id * 8;
    #pragma unroll
    for (int j = 0; j < 8; j++) o[j] = f2bf(whh[n * 64 + kb + j]);
  } else {
    // ---------------- transposes for the head ----------------
    for (int i = tid; i < 64 * 128; i += 256) {
      int o = i >> 7, k = i & 127;
      g_w2t[k * 64 + o] = g_w2[i];
    }
    for (int i = tid; i < 32 * 64; i += 256) {
      int o = i >> 6, k = i & 63;
      g_w3t[k * 32 + o] = g_w3[i];
    }
    if (tid < 128) {
      int o = tid >> 5, k = tid & 31;
      g_w4t[k * 4 + o] = g_w4[tid];
    }
  }
}

// ---------------------------------------------------------------------------
// k_prep2: C1t[j][i] = (A·B)^T  (180 x 128) and c1b[i] = A·vb + avb.
// Block i (128), threads 0..184. A-row broadcast, B coalesced over j.
// ---------------------------------------------------------------------------
__global__ __launch_bounds__(192) void k_prep2(
    const float* __restrict__ A, const float* __restrict__ avb,
    const float* __restrict__ Bp, const float* __restrict__ vb,
    float* __restrict__ C1t, float* __restrict__ c1b) {
  const int i = blockIdx.x, j = threadIdx.x;
  const float* Ar = A + (size_t)i * ADJ;
  if (j < 180) {
    float a0 = 0.f, a1 = 0.f, a2 = 0.f, a3 = 0.f;
    for (int k = 0; k < ADJ; k += 4) {
      a0 = fmaf(Ar[k],     Bp[(size_t)(k)     * 180 + j], a0);
      a1 = fmaf(Ar[k + 1], Bp[(size_t)(k + 1) * 180 + j], a1);
      a2 = fmaf(Ar[k + 2], Bp[(size_t)(k + 2) * 180 + j], a2);
      a3 = fmaf(Ar[k + 3], Bp[(size_t)(k + 3) * 180 + j], a3);
    }
    C1t[(size_t)j * 128 + i] = (a0 + a1) + (a2 + a3);
  } else if (j == 180) {
    float a0 = 0.f;
    for (int k = 0; k < ADJ; k++) a0 = fmaf(Ar[k], vb[k], a0);
    c1b[i] = a0 + avb[i];
  }
}

// ---------------------------------------------------------------------------
// k_lstm: MFMA recurrence, G interleaved [v][u][4 gates] -> dwordx4 gathers,
// t-loop unrolled x2 (ping-pong G prefetch regs), ds_read_b64 token fetch.
// ---------------------------------------------------------------------------
#define LSTM_STEP(T, CUR, NXT)                                                 \
  {                                                                            \
    const unsigned short* hb = hbuf[(T) & 1];                                  \
    short8 a0 = *(const short8*)(hb + ln * 72 + kg * 8);                       \
    short8 a1 = *(const short8*)(hb + ln * 72 + 32 + kg * 8);                  \
    if ((T) < 59) {                                                            \
      int tsn = dir ? (58 - (T)) : ((T) + 1);                                  \
      unsigned long long tp =                                                  \
          *(const unsigned long long*)(tokp + tsn * 16 + kg * 4);              \
      int ta = (int)(tp & 0xffffull), tb = (int)((tp >> 16) & 0xffffull);      \
      int tc = (int)((tp >> 32) & 0xffffull), td = (int)(tp >> 48);            \
      NXT[0] = *(const float4*)(G + (size_t)ta * 256 + u4);                    \
      NXT[1] = *(const float4*)(G + (size_t)tb * 256 + u4);                    \
      NXT[2] = *(const float4*)(G + (size_t)tc * 256 + u4);                    \
      NXT[3] = *(const float4*)(G + (size_t)td * 256 + u4);                    \
    }                                                                          \
    f32x4 z0 = {0.f, 0.f, 0.f, 0.f};                                           \
    f32x4 acc0 = z0, acc1 = z0, acc2 = z0, acc3 = z0;                          \
    acc0 = __builtin_amdgcn_mfma_f32_16x16x32_bf16(a0, bfr[0][0], acc0, 0, 0, 0); \
    acc1 = __builtin_amdgcn_mfma_f32_16x16x32_bf16(a0, bfr[1][0], acc1, 0, 0, 0); \
    acc2 = __builtin_amdgcn_mfma_f32_16x16x32_bf16(a0, bfr[2][0], acc2, 0, 0, 0); \
    acc3 = __builtin_amdgcn_mfma_f32_16x16x32_bf16(a0, bfr[3][0], acc3, 0, 0, 0); \
    acc0 = __builtin_amdgcn_mfma_f32_16x16x32_bf16(a1, bfr[0][1], acc0, 0, 0, 0); \
    acc1 = __builtin_amdgcn_mfma_f32_16x16x32_bf16(a1, bfr[1][1], acc1, 0, 0, 0); \
    acc2 = __builtin_amdgcn_mfma_f32_16x16x32_bf16(a1, bfr[2][1], acc2, 0, 0, 0); \
    acc3 = __builtin_amdgcn_mfma_f32_16x16x32_bf16(a1, bfr[3][1], acc3, 0, 0, 0); \
    unsigned short* hw = hbuf[((T) + 1) & 1];                                  \
    _Pragma("unroll")                                                          \
    for (int r = 0; r < 4; r++) {                                              \
      float gi = acc0[r] + CUR[r].x;                                           \
      float gf = acc1[r] + CUR[r].y;                                           \
      float gc = acc2[r] + CUR[r].z;                                           \
      float go = acc3[r] + CUR[r].w;                                           \
      float cn = sigm(gf) * cst[r] + sigm(gi) * tanh_(gc);                     \
      cst[r] = cn;                                                             \
      float h = sigm(go) * tanh_(cn);                                          \
      hw[(kg * 4 + r) * 72 + u] = f2bf(h);                                     \
      if ((T) == 59) ho[(size_t)(b0 + kg * 4 + r) * 64 + u] = h;               \
    }                                                                          \
    __syncthreads();                                                           \
  }

__global__ __launch_bounds__(256) void k_lstm(
    const int* __restrict__ x,
    const float* __restrict__ G_f, const float* __restrict__ G_r,
    const unsigned short* __restrict__ Wfrag,
    float* __restrict__ hf_o, float* __restrict__ hr_o) {
  __shared__ __align__(16) unsigned short hbuf[2][16 * 72];
  __shared__ __align__(8) unsigned short tokp[60 * 16];
  const int tid = threadIdx.x;
  const int lane = tid & 63;
  const int w = tid >> 6;
  const int dir = blockIdx.x >> 8;
  const int blk = blockIdx.x & 255;
  const int b0 = blk << 4;
  const float* G = dir ? G_r : G_f;
  float* ho = dir ? hr_o : hf_o;

  for (int i = tid; i < 960; i += 256) {
    int r = i / 60, t = i - r * 60;
    tokp[t * 16 + r] = (unsigned short)x[(size_t)(b0 + r) * 60 + t];
  }
  for (int i = tid; i < 16 * 72; i += 256) hbuf[0][i] = 0;

  short8 bfr[4][2];
  #pragma unroll
  for (int gg = 0; gg < 4; gg++)
    #pragma unroll
    for (int c = 0; c < 2; c++) {
      int idx = (((dir * 4 + w) * 4 + gg) * 2 + c) * 64 + lane;
      bfr[gg][c] = *(const short8*)(Wfrag + (size_t)idx * 8);
    }

  const int kg = lane >> 4;
  const int ln = lane & 15;
  const int u = w * 16 + ln;
  const int u4 = u * 4;
  float cst[4] = {0.f, 0.f, 0.f, 0.f};
  float4 gvA[4], gvB[4];

  __syncthreads();

  {
    int ts0 = dir ? 59 : 0;
    unsigned long long tp =
        *(const unsigned long long*)(tokp + ts0 * 16 + kg * 4);
    int ta = (int)(tp & 0xffffull), tb = (int)((tp >> 16) & 0xffffull);
    int tc = (int)((tp >> 32) & 0xffffull), td = (int)(tp >> 48);
    gvA[0] = *(const float4*)(G + (size_t)ta * 256 + u4);
    gvA[1] = *(const float4*)(G + (size_t)tb * 256 + u4);
    gvA[2] = *(const float4*)(G + (size_t)tc * 256 + u4);
    gvA[3] = *(const float4*)(G + (size_t)td * 256 + u4);
  }

  #pragma unroll 1
  for (int tt = 0; tt < 30; tt++) {
    const int t0 = tt * 2, t1 = tt * 2 + 1;
    LSTM_STEP(t0, gvA, gvB)
    LSTM_STEP(t1, gvB, gvA)
  }
}

// ---------------------------------------------------------------------------
// k_head: feature assembly + collapsed head, all weight streams transposed
// (lane-coalesced), counts staged to LDS floats, feat reads as b128 broadcast.
// 512 blocks x 256 threads, 8 rows/block.
// ---------------------------------------------------------------------------
#define FSTR 192
#define CFS  520

__global__ __launch_bounds__(256) void k_head(
    const float* __restrict__ hf, const float* __restrict__ hr,
    const float* __restrict__ ent, const float* __restrict__ vlen,
    const float* __restrict__ pat, const float* __restrict__ cpx,
    const unsigned int* __restrict__ cnts,
    const float* __restrict__ e_w1, const float* __restrict__ e_b1,
    const float* __restrict__ e_w2, const float* __restrict__ e_b2,
    const float* __restrict__ l_w1, const float* __restrict__ l_b1,
    const float* __restrict__ l_w2, const float* __restrict__ l_b2,
    const float* __restrict__ c_w1, const float* __restrict__ c_b1,
    const float* __restrict__ c_w2, const float* __restrict__ c_b2,
    const float* __restrict__ p_w1, const float* __restrict__ p_b1,
    const float* __restrict__ p_w2, const float* __restrict__ p_b2,
    const float* __restrict__ x_w1, const float* __restrict__ x_b1,
    const float* __restrict__ x_w2, const float* __restrict__ x_b2,
    const float* __restrict__ C1t, const float* __restrict__ c1b,
    const float* __restrict__ g_w2t, const float* __restrict__ g_b2,
    const float* __restrict__ g_w3t, const float* __restrict__ g_b3,
    const float* __restrict__ g_w4t, const float* __restrict__ g_b4,
    float* __restrict__ out) {
  __shared__ float feat[8 * FSTR];
  __shared__ float cf[8 * CFS];
  __shared__ float h1[8 * 128];
  __shared__ float h2[8 * 64];
  __shared__ float h3[8 * 32];
  __shared__ float h1c[8 * 33];
  __shared__ float lg[32];
  const int tid = threadIdx.x;
  const int b0 = blockIdx.x * 8;

  // h_f / h_r -> feat[0:128)
  if (tid < 128) {
    int r = tid >> 4, c = tid & 15;
    float4 vv = ((const float4*)(hf + (size_t)(b0 + r) * 64))[c];
    *(float4*)(feat + r * FSTR + c * 4) = vv;
  } else {
    int t = tid - 128;
    int r = t >> 4, c = t & 15;
    float4 vv = ((const float4*)(hr + (size_t)(b0 + r) * 64))[c];
    *(float4*)(feat + r * FSTR + 64 + c * 4) = vv;
  }
  // counts -> LDS floats (coalesced uint4 loads, byte unpack)
  {
    uint4 u4v = *(const uint4*)(cnts + (size_t)b0 * 128 + tid * 4);
    int r = tid >> 5, c0 = (tid & 31) * 16;
    float* dst = cf + r * CFS + c0;
    unsigned int uu[4] = {u4v.x, u4v.y, u4v.z, u4v.w};
    #pragma unroll
    for (int q = 0; q < 4; q++) {
      float4 f4;
      f4.x = (float)(uu[q] & 255u);
      f4.y = (float)((uu[q] >> 8) & 255u);
      f4.z = (float)((uu[q] >> 16) & 255u);
      f4.w = (float)(uu[q] >> 24);
      *(float4*)(dst + q * 4) = f4;
    }
  }
  __syncthreads();
  // c-MLP layer 1: o = tid>>3 (32), r = tid&7 (8). Weights broadcast per 8.
  {
    int o = tid >> 3, r = tid & 7;
    const float4* Wc = (const float4*)(c_w1 + (size_t)o * 512);
    const float4* cv = (const float4*)(cf + r * CFS);
    float a0 = 0.f, a1 = 0.f;
    #pragma unroll 4
    for (int k4 = 0; k4 < 128; k4 += 2) {
      a0 = dot4(Wc[k4], cv[k4], a0);
      a1 = dot4(Wc[k4 + 1], cv[k4 + 1], a1);
    }
    float invv = __builtin_amdgcn_rcpf(fmaxf(vlen[b0 + r], 1.f));
    h1c[r * 33 + o] = fmaxf((a0 + a1) * invv + c_b1[o], 0.f);
  }
  __syncthreads();
  // small MLPs (threads 0..31) + c-MLP layer 2 (threads 64..191)
  if (tid < 32) {
    const int m = tid & 3, r = tid >> 2, b = b0 + r;
    float tt[24];
    if (m == 0) {
      float ein = ent[b] * 0.25f;
      #pragma unroll
      for (int o = 0; o < 16; o++) tt[o] = fmaxf(e_w1[o] * ein + e_b1[o], 0.f);
      #pragma unroll
      for (int o = 0; o < 8; o++) {
        float a = e_b2[o];
        #pragma unroll
        for (int k = 0; k < 16; k++) a = fmaf(e_w2[o * 16 + k], tt[k], a);
        feat[r * FSTR + 128 + o] = a;
      }
    } else if (m == 1) {
      float lin = vlen[b] * (1.f / 60.f);
      #pragma unroll
      for (int o = 0; o < 16; o++) tt[o] = fmaxf(l_w1[o] * lin + l_b1[o], 0.f);
      #pragma unroll
      for (int o = 0; o < 8; o++) {
        float a = l_b2[o];
        #pragma unroll
        for (int k = 0; k < 16; k++) a = fmaf(l_w2[o * 16 + k], tt[k], a);
        feat[r * FSTR + 136 + o] = a;
      }
    } else if (m == 2) {
      float pin[6];
      #pragma unroll
      for (int k = 0; k < 6; k++) pin[k] = pat[b * 6 + k];
      #pragma unroll
      for (int o = 0; o < 24; o++) {
        float a = p_b1[o];
        #pragma unroll
        for (int k = 0; k < 6; k++) a = fmaf(p_w1[o * 6 + k], pin[k], a);
        tt[o] = fmaxf(a, 0.f);
      }
      #pragma unroll
      for (int o = 0; o < 12; o++) {
        float a = p_b2[o];
        #pragma unroll
        for (int k = 0; k < 24; k++) a = fmaf(p_w2[o * 24 + k], tt[k], a);
        feat[r * FSTR + 160 + o] = a;
      }
    } else {
      float xin[4];
      #pragma unroll
      for (int k = 0; k < 4; k++) xin[k] = cpx[b * 4 + k];
      #pragma unroll
      for (int o = 0; o < 16; o++) {
        float a = x_b1[o];
        #pragma unroll
        for (int k = 0; k < 4; k++) a = fmaf(x_w1[o * 4 + k], xin[k], a);
        tt[o] = fmaxf(a, 0.f);
      }
      #pragma unroll
      for (int o = 0; o < 8; o++) {
        float a = x_b2[o];
        #pragma unroll
        for (int k = 0; k < 16; k++) a = fmaf(x_w2[o * 16 + k], tt[k], a);
        feat[r * FSTR + 172 + o] = a;
      }
    }
  } else if (tid >= 64 && tid < 192) {
    int t = tid - 64;
    int r = t >> 4, o = t & 15;
    float a = c_b2[o];
    const float* hh = h1c + r * 33;
    #pragma unroll
    for (int k = 0; k < 32; k++) a = fmaf(c_w2[o * 32 + k], hh[k], a);
    feat[r * FSTR + 144 + o] = a;
  }
  __syncthreads();

  // L1: 180 -> 128 relu. C1t lane-coalesced, feat b128 broadcasts.
  {
    const int o = tid & 127, rg = tid >> 7;
    const float* f0p = feat + (rg * 4 + 0) * FSTR;
    const float* f1p = feat + (rg * 4 + 1) * FSTR;
    const float* f2p = feat + (rg * 4 + 2) * FSTR;
    const float* f3p = feat + (rg * 4 + 3) * FSTR;
    float a0 = 0.f, a1 = 0.f, a2 = 0.f, a3 = 0.f;
    #pragma unroll 3
    for (int k4 = 0; k4 < 45; k4++) {
      float w0 = C1t[(size_t)(k4 * 4 + 0) * 128 + o];
      float w1 = C1t[(size_t)(k4 * 4 + 1) * 128 + o];
      float w2 = C1t[(size_t)(k4 * 4 + 2) * 128 + o];
      float w3 = C1t[(size_t)(k4 * 4 + 3) * 128 + o];
      float4 f0 = *(const float4*)(f0p + k4 * 4);
      float4 f1 = *(const float4*)(f1p + k4 * 4);
      float4 f2 = *(const float4*)(f2p + k4 * 4);
      float4 f3 = *(const float4*)(f3p + k4 * 4);
      a0 = fmaf(w0, f0.x, a0); a0 = fmaf(w1, f0.y, a0);
      a0 = fmaf(w2, f0.z, a0); a0 = fmaf(w3, f0.w, a0);
      a1 = fmaf(w0, f1.x, a1); a1 = fmaf(w1, f1.y, a1);
      a1 = fmaf(w2, f1.z, a1); a1 = fmaf(w3, f1.w, a1);
      a2 = fmaf(w0, f2.x, a2); a2 = fmaf(w1, f2.y, a2);
      a2 = fmaf(w2, f2.z, a2); a2 = fmaf(w3, f2.w, a2);
      a3 = fmaf(w0, f3.x, a3); a3 = fmaf(w1, f3.y, a3);
      a3 = fmaf(w2, f3.z, a3); a3 = fmaf(w3, f3.w, a3);
    }
    float bb = c1b[o];
    h1[(rg * 4 + 0) * 128 + o] = fmaxf(a0 + bb, 0.f);
    h1[(rg * 4 + 1) * 128 + o] = fmaxf(a1 + bb, 0.f);
    h1[(rg * 4 + 2) * 128 + o] = fmaxf(a2 + bb, 0.f);
    h1[(rg * 4 + 3) * 128 + o] = fmaxf(a3 + bb, 0.f);
  }
  __syncthreads();
  // L2: 128 -> 64 relu
  {
    const int o = tid & 63, rg = tid >> 6;
    const float* f0p = h1 + (rg * 2 + 0) * 128;
    const float* f1p = h1 + (rg * 2 + 1) * 128;
    float a0 = 0.f, a1 = 0.f;
    #pragma unroll 4
    for (int k4 = 0; k4 < 32; k4++) {
      float w0 = g_w2t[(k4 * 4 + 0) * 64 + o];
      float w1 = g_w2t[(k4 * 4 + 1) * 64 + o];
      float w2 = g_w2t[(k4 * 4 + 2) * 64 + o];
      float w3 = g_w2t[(k4 * 4 + 3) * 64 + o];
      float4 f0 = *(const float4*)(f0p + k4 * 4);
      float4 f1 = *(const float4*)(f1p + k4 * 4);
      a0 = fmaf(w0, f0.x, a0); a0 = fmaf(w1, f0.y, a0);
      a0 = fmaf(w2, f0.z, a0); a0 = fmaf(w3, f0.w, a0);
      a1 = fmaf(w0, f1.x, a1); a1 = fmaf(w1, f1.y, a1);
      a1 = fmaf(w2, f1.z, a1); a1 = fmaf(w3, f1.w, a1);
    }
    float bb = g_b2[o];
    h2[(rg * 2 + 0) * 64 + o] = fmaxf(a0 + bb, 0.f);
    h2[(rg * 2 + 1) * 64 + o] = fmaxf(a1 + bb, 0.f);
  }
  __syncthreads();
  // L3: 64 -> 32 relu
  {
    const int o = tid & 31, rg = tid >> 5;
    const float* fp = h2 + rg * 64;
    float a = 0.f;
    #pragma unroll 4
    for (int k4 = 0; k4 < 16; k4++) {
      float w0 = g_w3t[(k4 * 4 + 0) * 32 + o];
      float w1 = g_w3t[(k4 * 4 + 1) * 32 + o];
      float w2 = g_w3t[(k4 * 4 + 2) * 32 + o];
      float w3 = g_w3t[(k4 * 4 + 3) * 32 + o];
      float4 f0 = *(const float4*)(fp + k4 * 4);
      a = fmaf(w0, f0.x, a); a = fmaf(w1, f0.y, a);
      a = fmaf(w2, f0.z, a); a = fmaf(w3, f0.w, a);
    }
    h3[rg * 32 + o] = fmaxf(a + g_b3[o], 0.f);
  }
  __syncthreads();
  // L4: 32 -> 4 logits
  if (tid < 32) {
    int r = tid >> 2, o = tid & 3;
    const float* hh = h3 + r * 32;
    float a = g_b4[o];
    #pragma unroll
    for (int k = 0; k < 32; k++) a = fmaf(g_w4t[k * 4 + o], hh[k], a);
    lg[tid] = a;
  }
  __syncthreads();
  if (tid < 8) {
    float l0 = lg[tid * 4 + 0], l1 = lg[tid * 4 + 1];
    float l2 = lg[tid * 4 + 2], l3 = lg[tid * 4 + 3];
    float m = fmaxf(fmaxf(l0, l1), fmaxf(l2, l3));
    float e0 = __expf(l0 - m), e1 = __expf(l1 - m);
    float e2 = __expf(l2 - m), e3 = __expf(l3 - m);
    float is = __builtin_amdgcn_rcpf(e0 + e1 + e2 + e3);
    float4 o4; o4.x = e0 * is; o4.y = e1 * is; o4.z = e2 * is; o4.w = e3 * is;
    *(float4*)(out + (size_t)(b0 + tid) * 4) = o4;
  }
}

// ---------------------------------------------------------------------------
extern "C" void kernel_launch(void* const* d_in, const int* in_sizes, int n_in,
                              void* d_out, int out_size, void* d_ws, size_t ws_size,
                              hipStream_t stream) {
  const int*   x     = (const int*)d_in[0];
  const float* emb   = (const float*)d_in[1];
  const float* wih_f = (const float*)d_in[2];
  const float* whh_f = (const float*)d_in[3];
  const float* bih_f = (const float*)d_in[4];
  const float* bhh_f = (const float*)d_in[5];
  const float* wih_r = (const float*)d_in[6];
  const float* whh_r = (const float*)d_in[7];
  const float* bih_r = (const float*)d_in[8];
  const float* bhh_r = (const float*)d_in[9];
  const float* e_w1 = (const float*)d_in[10]; const float* e_b1 = (const float*)d_in[11];
  const float* e_w2 = (const float*)d_in[12]; const float* e_b2 = (const float*)d_in[13];
  const float* l_w1 = (const float*)d_in[14]; const float* l_b1 = (const float*)d_in[15];
  const float* l_w2 = (const float*)d_in[16]; const float* l_b2 = (const float*)d_in[17];
  const float* c_w1 = (const float*)d_in[18]; const float* c_b1 = (const float*)d_in[19];
  const float* c_w2 = (const float*)d_in[20]; const float* c_b2 = (const float*)d_in[21];
  const float* p_w1 = (const float*)d_in[22]; const float* p_b1 = (const float*)d_in[23];
  const float* p_w2 = (const float*)d_in[24]; const float* p_b2 = (const float*)d_in[25];
  const float* x_w1 = (const float*)d_in[26]; const float* x_b1 = (const float*)d_in[27];
  const float* x_w2 = (const float*)d_in[28]; const float* x_b2 = (const float*)d_in[29];
  const float* fp_w = (const float*)d_in[30]; const float* fp_b = (const float*)d_in[31];
  const float* attn_w = (const float*)d_in[32]; const float* attn_b = (const float*)d_in[33];
  const float* out_w = (const float*)d_in[34]; const float* out_b = (const float*)d_in[35];
  const float* g_w1 = (const float*)d_in[36]; const float* g_b1 = (const float*)d_in[37];
  const float* g_w2 = (const float*)d_in[38]; const float* g_b2 = (const float*)d_in[39];
  const float* g_w3 = (const float*)d_in[40]; const float* g_b3 = (const float*)d_in[41];
  const float* g_w4 = (const float*)d_in[42]; const float* g_b4 = (const float*)d_in[43];

  float* ws   = (float*)d_ws;
  float* G_f  = ws;                       // 512*256
  float* G_r  = G_f  + 512 * 256;
  float* hfw  = G_r  + 512 * 256;         // B*64
  float* hrw  = hfw  + BATCH * 64;
  float* entw = hrw  + BATCH * 64;        // B
  float* vlnw = entw + BATCH;
  float* patw = vlnw + BATCH;             // B*6
  float* cpxw = patw + BATCH * 6;         // B*4
  unsigned int* cntw = (unsigned int*)(cpxw + BATCH * 4);  // B*128 uints
  float* Aw   = (float*)(cntw + BATCH * 128);  // 128*184
  float* avbw = Aw + 128 * ADJ;                // 128
  float* Bpw  = avbw + 128;                    // 184*180
  float* vbw  = Bpw + ADJ * 180;               // 184
  float* C1t  = vbw + ADJ;                     // 180*128
  float* c1b  = C1t + 180 * 128;               // 128
  float* g2t  = c1b + 128;                     // 128*64
  float* g3t  = g2t + 128 * 64;                // 64*32
  float* g4t  = g3t + 64 * 32;                 // 32*4
  unsigned short* Wfrag = (unsigned short*)(g4t + 32 * 4);  // 32768 bf16

  k_mega<<<dim3(1481), dim3(256), 0, stream>>>(
      x, emb, wih_f, bih_f, bhh_f, wih_r, bih_r, bhh_r, whh_f, whh_r,
      g_w1, g_b1, out_w, out_b, attn_w, attn_b, fp_w, fp_b,
      g_w2, g_w3, g_w4,
      entw, vlnw, patw, cpxw, cntw, G_f, G_r, Wfrag,
      Aw, avbw, Bpw, vbw, g2t, g3t, g4t);
  k_prep2<<<dim3(128), dim3(192), 0, stream>>>(Aw, avbw, Bpw, vbw, C1t, c1b);
  k_lstm<<<dim3(512), dim3(256), 0, stream>>>(x, G_f, G_r, Wfrag, hfw, hrw);
  k_head<<<dim3(BATCH / 8), dim3(256), 0, stream>>>(
      hfw, hrw, entw, vlnw, patw, cpxw, cntw,
      e_w1, e_b1, e_w2, e_b2, l_w1, l_b1, l_w2, l_b2,
      c_w1, c_b1, c_w2, c_b2, p_w1, p_b1, p_w2, p_b2,
      x_w1, x_b1, x_w2, x_b2, C1t, c1b,
      g2t, g_b2, g3t, g_b3, g4t, g_b4,
      (float*)d_out);
}

// Round 5
// 260.383 us; speedup vs baseline: 5.1164x; 1.0653x over previous
//
#include <hip/hip_runtime.h>

// Problem constants
#define BATCH 4096
#define SEQL  60
#define VOC   512
#define EMBD  128
#define HID   64
#define GATES 256
#define ADJ   184

typedef __attribute__((ext_vector_type(8))) short short8;
typedef __attribute__((ext_vector_type(4))) float f32x4;

__device__ __forceinline__ float sigm(float x) {
  return __builtin_amdgcn_rcpf(1.f + __expf(-x));
}
__device__ __forceinline__ float tanh_(float x) {
  float e = __expf(2.f * x);
  return 1.f - 2.f * __builtin_amdgcn_rcpf(e + 1.f);
}
__device__ __forceinline__ unsigned short f2bf(float f) {
  unsigned int u = __float_as_uint(f);
  unsigned int r = (u + 0x7fffu + ((u >> 16) & 1u)) >> 16;
  return (unsigned short)r;
}
__device__ __forceinline__ float dot4(float4 a, float4 b, float acc) {
  acc = fmaf(a.x, b.x, acc); acc = fmaf(a.y, b.y, acc);
  acc = fmaf(a.z, b.z, acc); acc = fmaf(a.w, b.w, acc);
  return acc;
}
__device__ __forceinline__ float wsumf(float v) {
  #pragma unroll
  for (int s = 32; s > 0; s >>= 1) v += __shfl_xor(v, s, 64);
  return v;
}
__device__ __forceinline__ int wsumi(int v) {
  #pragma unroll
  for (int s = 32; s > 0; s >>= 1) v += __shfl_xor(v, s, 64);
  return v;
}
__device__ __forceinline__ int wmaxi(int v) {
  #pragma unroll
  for (int s = 32; s > 0; s >>= 1) v = max(v, __shfl_xor(v, s, 64));
  return v;
}

// ---------------------------------------------------------------------------
// MEGA kernel: all mutually-independent prep work in ONE launch.
//   [0,1024)      stats (wave-per-row; bigram-unique via lane broadcast)
//   [1024,1152)   G table (interleaved [v][u][4 gates])
//   [1152,1280)   A = g_w1·out_w (+ avb bias fold)
//   [1280,1464)   B = wv·fp_w    (+ vb bias fold)
//   [1464,1480)   Wfrag (bf16 MFMA B-operand fragments of w_hh)
//   [1480]        transposes of g_w2/g_w3/g_w4
//   [1481,1489)   transpose c_w1 -> c_w1t[512][32]
// ---------------------------------------------------------------------------
__global__ __launch_bounds__(256) void k_mega(
    const int* __restrict__ x, const float* __restrict__ emb,
    const float* __restrict__ wih_f, const float* __restrict__ bif, const float* __restrict__ bhf,
    const float* __restrict__ wih_r, const float* __restrict__ bir, const float* __restrict__ bhr,
    const float* __restrict__ whh_f, const float* __restrict__ whh_r,
    const float* __restrict__ g_w1, const float* __restrict__ g_b1,
    const float* __restrict__ out_w, const float* __restrict__ out_b,
    const float* __restrict__ attn_w, const float* __restrict__ attn_b,
    const float* __restrict__ fp_w, const float* __restrict__ fp_b,
    const float* __restrict__ g_w2, const float* __restrict__ g_w3,
    const float* __restrict__ g_w4, const float* __restrict__ c_w1,
    float* __restrict__ ent_o, float* __restrict__ vlen_o,
    float* __restrict__ pat_o, float* __restrict__ cpx_o,
    unsigned int* __restrict__ cnt_o,
    float* __restrict__ G_f, float* __restrict__ G_r,
    unsigned short* __restrict__ Wfrag,
    float* __restrict__ A, float* __restrict__ avb,
    float* __restrict__ Bp, float* __restrict__ vb,
    float* __restrict__ g_w2t, float* __restrict__ g_w3t, float* __restrict__ g_w4t,
    float* __restrict__ c_w1t) {
  __shared__ unsigned int cnt[4][512];
  __shared__ unsigned short q[4][68];
  const int bid = blockIdx.x;
  const int tid = threadIdx.x;

  if (bid < 1024) {
    // ---------------- per-row sequence statistics ----------------
    const int lane = tid & 63;
    const int wid = tid >> 6;
    const int row = bid * 4 + wid;
    unsigned int* cr = cnt[wid];
    unsigned short* qr = q[wid];

    for (int i = lane; i < 512; i += 64) cr[i] = 0u;
    qr[lane] = 0;
    if (lane < 4) qr[64 + lane] = 0;
    int v = (lane < 60) ? x[row * 60 + lane] : 0;
    bool act = (v != 0);
    unsigned long long amask = __ballot(act);
    int n = __popcll(amask);
    __syncthreads();
    if (act) {
      int pos = __popcll(amask & ((1ull << lane) - 1ull));
      qr[pos] = (unsigned short)v;
      atomicAdd(&cr[v], 1u);
    }
    __syncthreads();

    float vlenf = (float)(n >= 1 ? n : 1);
    float inv = 1.f / vlenf;

    float ent = 0.f; int distinct = 0;
    #pragma unroll
    for (int j = 0; j < 8; j++) {
      unsigned int c = cr[lane + j * 64];
      if (c) {
        distinct++;
        float p = (float)c * inv;
        ent -= p * __logf(p + 1e-8f);
      }
    }
    ent = wsumf(ent);
    distinct = wsumi(distinct);

    int a = qr[lane], b = qr[lane + 1], c2 = qr[lane + 2];
    bool v1 = (lane + 1 < n);
    bool v2 = (lane + 2 < n);
    int rep  = __popcll(__ballot(v1 && (a == b)));
    int incs = __popcll(__ballot(v1 && (b > a)));
    int decs = __popcll(__ballot(v1 && (b < a)));
    int per2 = __popcll(__ballot(v2 && (a == c2)));

    int prev = (lane > 0) ? (int)qr[lane - 1] : -1;
    bool isst = (lane < n) && (lane == 0 || a != prev);
    unsigned long long smask = __ballot(isst);
    int len = 0;
    if (isst) {
      unsigned long long hi = (lane < 63) ? (smask >> (lane + 1)) : 0ull;
      int next = hi ? (lane + __ffsll((unsigned long long)hi)) : n;
      len = next - lane;
    }
    int maxrun = wmaxi(len);

    // distinct bigrams: lane i keeps its code in-register; compare against
    // broadcast of earlier lanes' codes (no LDS, no divergence).
    int code = v1 ? (a * VOC + b) : -1;
    int unique = v1 ? 1 : 0;
    #pragma unroll 1
    for (int j = 0; j < 58; j++) {
      int cj = __shfl(code, j, 64);
      if (j < lane && cj == code) unique = 0;
    }
    int dc = __popcll(__ballot(unique != 0));

    int wl = n >> 1; if (wl > 5) wl = 5;
    float local = 0.f;
    if (wl >= 2) {
      bool pv = (lane + wl <= n);
      int u = 0;
      if (pv) {
        int t0 = qr[lane], t1 = qr[lane + 1], t2 = qr[lane + 2];
        int t3 = qr[lane + 3], t4 = qr[lane + 4];
        u = 1;
        u += (t1 != t0);
        if (wl >= 3) u += (int)((t2 != t1) && (t2 != t0));
        if (wl >= 4) u += (int)((t3 != t2) && (t3 != t1) && (t3 != t0));
        if (wl >= 5) u += (int)((t4 != t3) && (t4 != t2) && (t4 != t1) && (t4 != t0));
      }
      int usum = wsumi(u);
      int denw = n - wl + 1; if (denw < 1) denw = 1;
      local = (float)usum / (float)wl / (float)denw;
    }

    float den1 = (float)((n - 1) >= 1 ? (n - 1) : 1);
    float repeat = (float)rep / den1;
    float per = (n >= 4) ? (float)per2 / (float)((n - 2) >= 1 ? (n - 2) : 1) : 0.f;
    float entz = (n > 1) ? ent : 0.f;
    float z = (n > 1) ? 1.f : 0.f;

    if (lane == 0) {
      ent_o[row] = entz;
      vlen_o[row] = (float)n;
      pat_o[row * 6 + 0] = repeat * z;
      pat_o[row * 6 + 1] = (float)incs / den1 * z;
      pat_o[row * 6 + 2] = (float)decs / den1 * z;
      pat_o[row * 6 + 3] = per * z;
      pat_o[row * 6 + 4] = (float)distinct * inv * z;
      pat_o[row * 6 + 5] = (float)maxrun * inv * z;
      cpx_o[row * 4 + 0] = (float)dc / den1 * z;
      cpx_o[row * 4 + 1] = entz / __logf((float)(n >= 2 ? n : 2)) * z;
      cpx_o[row * 4 + 2] = local * z;
      cpx_o[row * 4 + 3] = (1.f - repeat) * z;
    }
    for (int i = lane; i < 128; i += 64) {
      unsigned int p = cr[4 * i] | (cr[4 * i + 1] << 8) |
                       (cr[4 * i + 2] << 16) | (cr[4 * i + 3] << 24);
      cnt_o[row * 128 + i] = p;
    }
  } else if (bid < 1152) {
    // ---------------- G table, interleaved [v][u][gg] ----------------
    const int bx = bid - 1024;
    const int dir = bx >> 6;
    const int rem = bx & 63;
    const int v0 = (rem >> 2) * 32;
    const int j0 = (rem & 3) * 64;
    const float* W = dir ? wih_r : wih_f;
    const float* bi = dir ? bir : bif;
    const float* bh = dir ? bhr : bhf;
    float* G = dir ? G_r : G_f;
    const int vp = tid >> 4;
    const int jq = tid & 15;
    const int v = v0 + vp * 2;
    const int j = j0 + jq * 4;
    const int gg = j >> 6;
    const int u0 = j & 63;

    const float4* E0 = (const float4*)(emb + (size_t)v * 128);
    const float4* E1 = (const float4*)(emb + (size_t)(v + 1) * 128);
    const float4* W0 = (const float4*)(W + (size_t)j * 128);
    const float4* W1 = (const float4*)(W + (size_t)(j + 1) * 128);
    const float4* W2 = (const float4*)(W + (size_t)(j + 2) * 128);
    const float4* W3 = (const float4*)(W + (size_t)(j + 3) * 128);

    float a00 = 0.f, a01 = 0.f, a02 = 0.f, a03 = 0.f;
    float a10 = 0.f, a11 = 0.f, a12 = 0.f, a13 = 0.f;
    #pragma unroll 4
    for (int d4 = 0; d4 < 32; d4++) {
      float4 e0 = E0[d4], e1 = E1[d4];
      float4 w0 = W0[d4], w1 = W1[d4], w2 = W2[d4], w3 = W3[d4];
      a00 = dot4(e0, w0, a00); a01 = dot4(e0, w1, a01);
      a02 = dot4(e0, w2, a02); a03 = dot4(e0, w3, a03);
      a10 = dot4(e1, w0, a10); a11 = dot4(e1, w1, a11);
      a12 = dot4(e1, w2, a12); a13 = dot4(e1, w3, a13);
    }
    float b0v = bi[j] + bh[j], b1v = bi[j + 1] + bh[j + 1];
    float b2v = bi[j + 2] + bh[j + 2], b3v = bi[j + 3] + bh[j + 3];
    float* g0 = G + (size_t)v * 256 + u0 * 4 + gg;
    g0[0]  = a00 + b0v; g0[4]  = a01 + b1v;
    g0[8]  = a02 + b2v; g0[12] = a03 + b3v;
    float* g1 = g0 + 256;
    g1[0]  = a10 + b0v; g1[4]  = a11 + b1v;
    g1[8]  = a12 + b2v; g1[12] = a13 + b3v;
  } else if (bid < 1280) {
    // ---------------- A = g_w1 · out_w  (128 x 184), avb fold ----------------
    const int i = bid - 1152;
    const int j = tid;
    const float* g1r = g_w1 + (size_t)i * ADJ;
    if (j < ADJ) {
      float a0 = 0.f, a1 = 0.f, a2 = 0.f, a3 = 0.f;
      for (int k = 0; k < ADJ; k += 4) {
        a0 = fmaf(g1r[k],     out_w[(size_t)(k)     * ADJ + j], a0);
        a1 = fmaf(g1r[k + 1], out_w[(size_t)(k + 1) * ADJ + j], a1);
        a2 = fmaf(g1r[k + 2], out_w[(size_t)(k + 2) * ADJ + j], a2);
        a3 = fmaf(g1r[k + 3], out_w[(size_t)(k + 3) * ADJ + j], a3);
      }
      A[(size_t)i * ADJ + j] = (a0 + a1) + (a2 + a3);
    } else if (j == ADJ) {
      float a0 = 0.f;
      for (int k = 0; k < ADJ; k++) a0 = fmaf(g1r[k], out_b[k], a0);
      avb[i] = a0 + g_b1[i];
    }
  } else if (bid < 1464) {
    // ---------------- B = wv · fp_w  (184 x 180), vb fold ----------------
    const int k = bid - 1280;
    const int j = tid;
    const float* wvr = attn_w + (size_t)(2 * ADJ + k) * ADJ;
    if (j < 180) {
      float a0 = 0.f, a1 = 0.f, a2 = 0.f, a3 = 0.f;
      for (int m = 0; m < ADJ; m += 4) {
        a0 = fmaf(wvr[m],     fp_w[(size_t)(m)     * 180 + j], a0);
        a1 = fmaf(wvr[m + 1], fp_w[(size_t)(m + 1) * 180 + j], a1);
        a2 = fmaf(wvr[m + 2], fp_w[(size_t)(m + 2) * 180 + j], a2);
        a3 = fmaf(wvr[m + 3], fp_w[(size_t)(m + 3) * 180 + j], a3);
      }
      Bp[(size_t)k * 180 + j] = (a0 + a1) + (a2 + a3);
    } else if (j == 180) {
      float a0 = 0.f;
      for (int m = 0; m < ADJ; m++) a0 = fmaf(wvr[m], fp_b[m], a0);
      vb[k] = a0 + attn_b[2 * ADJ + k];
    }
  } else if (bid < 1480) {
    // ---------------- w_hh bf16 MFMA B-fragments ----------------
    const int id = (bid - 1464) * 256 + tid;
    const int lane = id & 63;
    const int fc = id >> 6;
    const int c = fc & 1;
    const int gg = (fc >> 1) & 3;
    const int w = (fc >> 3) & 3;
    const int dir = fc >> 5;
    const float* whh = dir ? whh_r : whh_f;
    const int n = gg * 64 + w * 16 + (lane & 15);
    const int kb = c * 32 + (lane >> 4) * 8;
    unsigned short* o = Wfrag + (size_t)id * 8;
    #pragma unroll
    for (int j = 0; j < 8; j++) o[j] = f2bf(whh[n * 64 + kb + j]);
  } else if (bid == 1480) {
    // ---------------- transposes for the head ----------------
    for (int i = tid; i < 64 * 128; i += 256) {
      int o = i >> 7, k = i & 127;
      g_w2t[k * 64 + o] = g_w2[i];
    }
    for (int i = tid; i < 32 * 64; i += 256) {
      int o = i >> 6, k = i & 63;
      g_w3t[k * 32 + o] = g_w3[i];
    }
    if (tid < 128) {
      int o = tid >> 5, k = tid & 31;
      g_w4t[k * 4 + o] = g_w4[tid];
    }
  } else {
    // ---------------- transpose c_w1 (32x512) -> c_w1t (512x32) ----------------
    const int base = (bid - 1481) * 2048;   // 8 blocks x 2048 = 16384
    for (int i = tid; i < 2048; i += 256) {
      int idx = base + i;
      int o = idx >> 9, k = idx & 511;
      c_w1t[k * 32 + o] = c_w1[idx];
    }
  }
}

// ---------------------------------------------------------------------------
// k_lstm (+prep2): blocks [0,512) run the MFMA LSTM recurrence; blocks
// [512,640) run the head-collapse GEMM C1t = (A·B)^T (prep2) — independent
// of the LSTM, merged to save a launch.
// ---------------------------------------------------------------------------
#define LSTM_STEP(T, CUR, NXT)                                                 \
  {                                                                            \
    const unsigned short* hb = hbuf[(T) & 1];                                  \
    short8 a0 = *(const short8*)(hb + ln * 72 + kg * 8);                       \
    short8 a1 = *(const short8*)(hb + ln * 72 + 32 + kg * 8);                  \
    if ((T) < 59) {                                                            \
      int tsn = dir ? (58 - (T)) : ((T) + 1);                                  \
      uint4 of4 = *(const uint4*)(tokoff + tsn * 16 + kg * 4);                 \
      NXT[0] = *(const float4*)(Gb + of4.x + ub);                              \
      NXT[1] = *(const float4*)(Gb + of4.y + ub);                              \
      NXT[2] = *(const float4*)(Gb + of4.z + ub);                              \
      NXT[3] = *(const float4*)(Gb + of4.w + ub);                              \
    }                                                                          \
    f32x4 z0 = {0.f, 0.f, 0.f, 0.f};                                           \
    f32x4 acc0 = z0, acc1 = z0, acc2 = z0, acc3 = z0;                          \
    acc0 = __builtin_amdgcn_mfma_f32_16x16x32_bf16(a0, bfr[0][0], acc0, 0, 0, 0); \
    acc1 = __builtin_amdgcn_mfma_f32_16x16x32_bf16(a0, bfr[1][0], acc1, 0, 0, 0); \
    acc2 = __builtin_amdgcn_mfma_f32_16x16x32_bf16(a0, bfr[2][0], acc2, 0, 0, 0); \
    acc3 = __builtin_amdgcn_mfma_f32_16x16x32_bf16(a0, bfr[3][0], acc3, 0, 0, 0); \
    acc0 = __builtin_amdgcn_mfma_f32_16x16x32_bf16(a1, bfr[0][1], acc0, 0, 0, 0); \
    acc1 = __builtin_amdgcn_mfma_f32_16x16x32_bf16(a1, bfr[1][1], acc1, 0, 0, 0); \
    acc2 = __builtin_amdgcn_mfma_f32_16x16x32_bf16(a1, bfr[2][1], acc2, 0, 0, 0); \
    acc3 = __builtin_amdgcn_mfma_f32_16x16x32_bf16(a1, bfr[3][1], acc3, 0, 0, 0); \
    unsigned short* hw = hbuf[((T) + 1) & 1];                                  \
    _Pragma("unroll")                                                          \
    for (int r = 0; r < 4; r++) {                                              \
      float gi = acc0[r] + CUR[r].x;                                           \
      float gf = acc1[r] + CUR[r].y;                                           \
      float gc = acc2[r] + CUR[r].z;                                           \
      float go = acc3[r] + CUR[r].w;                                           \
      float cn = sigm(gf) * cst[r] + sigm(gi) * tanh_(gc);                     \
      cst[r] = cn;                                                             \
      float h = sigm(go) * tanh_(cn);                                          \
      hw[(kg * 4 + r) * 72 + u] = f2bf(h);                                     \
      if ((T) == 59) ho[(size_t)(b0 + kg * 4 + r) * 64 + u] = h;               \
    }                                                                          \
    __syncthreads();                                                           \
  }

__global__ __launch_bounds__(256) void k_lstm(
    const int* __restrict__ x,
    const float* __restrict__ G_f, const float* __restrict__ G_r,
    const unsigned short* __restrict__ Wfrag,
    const float* __restrict__ A, const float* __restrict__ avb,
    const float* __restrict__ Bp, const float* __restrict__ vb,
    float* __restrict__ C1t, float* __restrict__ c1b,
    float* __restrict__ hf_o, float* __restrict__ hr_o) {
  __shared__ __align__(16) unsigned short hbuf[2][16 * 72];
  __shared__ __align__(16) unsigned int tokoff[60 * 16];
  const int tid = threadIdx.x;

  if (blockIdx.x >= 512) {
    // -------- prep2: C1t[j][i] = (A·B)^T, c1b[i] = A·vb + avb --------
    const int i = blockIdx.x - 512, j = tid;
    const float* Ar = A + (size_t)i * ADJ;
    if (j < 180) {
      float a0 = 0.f, a1 = 0.f, a2 = 0.f, a3 = 0.f;
      for (int k = 0; k < ADJ; k += 4) {
        a0 = fmaf(Ar[k],     Bp[(size_t)(k)     * 180 + j], a0);
        a1 = fmaf(Ar[k + 1], Bp[(size_t)(k + 1) * 180 + j], a1);
        a2 = fmaf(Ar[k + 2], Bp[(size_t)(k + 2) * 180 + j], a2);
        a3 = fmaf(Ar[k + 3], Bp[(size_t)(k + 3) * 180 + j], a3);
      }
      C1t[(size_t)j * 128 + i] = (a0 + a1) + (a2 + a3);
    } else if (j == 180) {
      float a0 = 0.f;
      for (int k = 0; k < ADJ; k++) a0 = fmaf(Ar[k], vb[k], a0);
      c1b[i] = a0 + avb[i];
    }
    return;
  }

  const int lane = tid & 63;
  const int w = tid >> 6;
  const int dir = blockIdx.x >> 8;
  const int blk = blockIdx.x & 255;
  const int b0 = blk << 4;
  const float* G = dir ? G_r : G_f;
  const char* Gb = (const char*)G;
  float* ho = dir ? hr_o : hf_o;

  // token byte-offsets into G (token * 256 floats * 4B), transposed [t][row]
  for (int i = tid; i < 960; i += 256) {
    int r = i / 60, t = i - r * 60;
    tokoff[t * 16 + r] = ((unsigned int)x[(size_t)(b0 + r) * 60 + t]) << 10;
  }
  for (int i = tid; i < 16 * 72; i += 256) hbuf[0][i] = 0;

  short8 bfr[4][2];
  #pragma unroll
  for (int gg = 0; gg < 4; gg++)
    #pragma unroll
    for (int c = 0; c < 2; c++) {
      int idx = (((dir * 4 + w) * 4 + gg) * 2 + c) * 64 + lane;
      bfr[gg][c] = *(const short8*)(Wfrag + (size_t)idx * 8);
    }

  const int kg = lane >> 4;
  const int ln = lane & 15;
  const int u = w * 16 + ln;
  const unsigned int ub = (unsigned int)u * 16;  // byte offset of u4 within G row
  float cst[4] = {0.f, 0.f, 0.f, 0.f};
  float4 gvA[4], gvB[4];

  __syncthreads();

  {
    int ts0 = dir ? 59 : 0;
    uint4 of4 = *(const uint4*)(tokoff + ts0 * 16 + kg * 4);
    gvA[0] = *(const float4*)(Gb + of4.x + ub);
    gvA[1] = *(const float4*)(Gb + of4.y + ub);
    gvA[2] = *(const float4*)(Gb + of4.z + ub);
    gvA[3] = *(const float4*)(Gb + of4.w + ub);
  }

  #pragma unroll 1
  for (int tt = 0; tt < 30; tt++) {
    const int t0 = tt * 2, t1 = tt * 2 + 1;
    LSTM_STEP(t0, gvA, gvB)
    LSTM_STEP(t1, gvB, gvA)
  }
}

// ---------------------------------------------------------------------------
// k_head: feature assembly + collapsed head. c-MLP L1 now reads transposed
// c_w1t (fully coalesced) with LDS-broadcast counts.
// 512 blocks x 256 threads, 8 rows/block.
// ---------------------------------------------------------------------------
#define FSTR 192
#define CFS  520

__global__ __launch_bounds__(256) void k_head(
    const float* __restrict__ hf, const float* __restrict__ hr,
    const float* __restrict__ ent, const float* __restrict__ vlen,
    const float* __restrict__ pat, const float* __restrict__ cpx,
    const unsigned int* __restrict__ cnts,
    const float* __restrict__ e_w1, const float* __restrict__ e_b1,
    const float* __restrict__ e_w2, const float* __restrict__ e_b2,
    const float* __restrict__ l_w1, const float* __restrict__ l_b1,
    const float* __restrict__ l_w2, const float* __restrict__ l_b2,
    const float* __restrict__ c_w1t, const float* __restrict__ c_b1,
    const float* __restrict__ c_w2, const float* __restrict__ c_b2,
    const float* __restrict__ p_w1, const float* __restrict__ p_b1,
    const float* __restrict__ p_w2, const float* __restrict__ p_b2,
    const float* __restrict__ x_w1, const float* __restrict__ x_b1,
    const float* __restrict__ x_w2, const float* __restrict__ x_b2,
    const float* __restrict__ C1t, const float* __restrict__ c1b,
    const float* __restrict__ g_w2t, const float* __restrict__ g_b2,
    const float* __restrict__ g_w3t, const float* __restrict__ g_b3,
    const float* __restrict__ g_w4t, const float* __restrict__ g_b4,
    float* __restrict__ out) {
  __shared__ float feat[8 * FSTR];
  __shared__ float cf[8 * CFS];
  __shared__ float h1[8 * 128];
  __shared__ float h2[8 * 64];
  __shared__ float h3[8 * 32];
  __shared__ float h1c[8 * 33];
  __shared__ float lg[32];
  const int tid = threadIdx.x;
  const int b0 = blockIdx.x * 8;

  // h_f / h_r -> feat[0:128)
  if (tid < 128) {
    int r = tid >> 4, c = tid & 15;
    float4 vv = ((const float4*)(hf + (size_t)(b0 + r) * 64))[c];
    *(float4*)(feat + r * FSTR + c * 4) = vv;
  } else {
    int t = tid - 128;
    int r = t >> 4, c = t & 15;
    float4 vv = ((const float4*)(hr + (size_t)(b0 + r) * 64))[c];
    *(float4*)(feat + r * FSTR + 64 + c * 4) = vv;
  }
  // counts -> LDS floats (coalesced uint4 loads, byte unpack)
  {
    uint4 u4v = *(const uint4*)(cnts + (size_t)b0 * 128 + tid * 4);
    int r = tid >> 5, c0 = (tid & 31) * 16;
    float* dst = cf + r * CFS + c0;
    unsigned int uu[4] = {u4v.x, u4v.y, u4v.z, u4v.w};
    #pragma unroll
    for (int qq = 0; qq < 4; qq++) {
      float4 f4;
      f4.x = (float)(uu[qq] & 255u);
      f4.y = (float)((uu[qq] >> 8) & 255u);
      f4.z = (float)((uu[qq] >> 16) & 255u);
      f4.w = (float)(uu[qq] >> 24);
      *(float4*)(dst + qq * 4) = f4;
    }
  }
  __syncthreads();
  // c-MLP layer 1: o = tid&31 (coalesced c_w1t), r = tid>>5 (LDS broadcast)
  {
    int o = tid & 31, r = tid >> 5;
    const float* cv = cf + r * CFS;
    float a0 = 0.f, a1 = 0.f, a2 = 0.f, a3 = 0.f;
    #pragma unroll 4
    for (int k = 0; k < 512; k += 4) {
      float4 c4 = *(const float4*)(cv + k);
      a0 = fmaf(c_w1t[(k + 0) * 32 + o], c4.x, a0);
      a1 = fmaf(c_w1t[(k + 1) * 32 + o], c4.y, a1);
      a2 = fmaf(c_w1t[(k + 2) * 32 + o], c4.z, a2);
      a3 = fmaf(c_w1t[(k + 3) * 32 + o], c4.w, a3);
    }
    float invv = __builtin_amdgcn_rcpf(fmaxf(vlen[b0 + r], 1.f));
    h1c[r * 33 + o] = fmaxf(((a0 + a1) + (a2 + a3)) * invv + c_b1[o], 0.f);
  }
  __syncthreads();
  // small MLPs (threads 0..31) + c-MLP layer 2 (threads 64..191)
  if (tid < 32) {
    const int m = tid & 3, r = tid >> 2, b = b0 + r;
    float tt[24];
    if (m == 0) {
      float ein = ent[b] * 0.25f;
      #pragma unroll
      for (int o = 0; o < 16; o++) tt[o] = fmaxf(e_w1[o] * ein + e_b1[o], 0.f);
      #pragma unroll
      for (int o = 0; o < 8; o++) {
        float a = e_b2[o];
        #pragma unroll
        for (int k = 0; k < 16; k++) a = fmaf(e_w2[o * 16 + k], tt[k], a);
        feat[r * FSTR + 128 + o] = a;
      }
    } else if (m == 1) {
      float lin = vlen[b] * (1.f / 60.f);
      #pragma unroll
      for (int o = 0; o < 16; o++) tt[o] = fmaxf(l_w1[o] * lin + l_b1[o], 0.f);
      #pragma unroll
      for (int o = 0; o < 8; o++) {
        float a = l_b2[o];
        #pragma unroll
        for (int k = 0; k < 16; k++) a = fmaf(l_w2[o * 16 + k], tt[k], a);
        feat[r * FSTR + 136 + o] = a;
      }
    } else if (m == 2) {
      float pin[6];
      #pragma unroll
      for (int k = 0; k < 6; k++) pin[k] = pat[b * 6 + k];
      #pragma unroll
      for (int o = 0; o < 24; o++) {
        float a = p_b1[o];
        #pragma unroll
        for (int k = 0; k < 6; k++) a = fmaf(p_w1[o * 6 + k], pin[k], a);
        tt[o] = fmaxf(a, 0.f);
      }
      #pragma unroll
      for (int o = 0; o < 12; o++) {
        float a = p_b2[o];
        #pragma unroll
        for (int k = 0; k < 24; k++) a = fmaf(p_w2[o * 24 + k], tt[k], a);
        feat[r * FSTR + 160 + o] = a;
      }
    } else {
      float xin[4];
      #pragma unroll
      for (int k = 0; k < 4; k++) xin[k] = cpx[b * 4 + k];
      #pragma unroll
      for (int o = 0; o < 16; o++) {
        float a = x_b1[o];
        #pragma unroll
        for (int k = 0; k < 4; k++) a = fmaf(x_w1[o * 4 + k], xin[k], a);
        tt[o] = fmaxf(a, 0.f);
      }
      #pragma unroll
      for (int o = 0; o < 8; o++) {
        float a = x_b2[o];
        #pragma unroll
        for (int k = 0; k < 16; k++) a = fmaf(x_w2[o * 16 + k], tt[k], a);
        feat[r * FSTR + 172 + o] = a;
      }
    }
  } else if (tid >= 64 && tid < 192) {
    int t = tid - 64;
    int r = t >> 4, o = t & 15;
    float a = c_b2[o];
    const float* hh = h1c + r * 33;
    #pragma unroll
    for (int k = 0; k < 32; k++) a = fmaf(c_w2[o * 32 + k], hh[k], a);
    feat[r * FSTR + 144 + o] = a;
  }
  __syncthreads();

  // L1: 180 -> 128 relu. C1t lane-coalesced, feat b128 broadcasts.
  {
    const int o = tid & 127, rg = tid >> 7;
    const float* f0p = feat + (rg * 4 + 0) * FSTR;
    const float* f1p = feat + (rg * 4 + 1) * FSTR;
    const float* f2p = feat + (rg * 4 + 2) * FSTR;
    const float* f3p = feat + (rg * 4 + 3) * FSTR;
    float a0 = 0.f, a1 = 0.f, a2 = 0.f, a3 = 0.f;
    #pragma unroll 3
    for (int k4 = 0; k4 < 45; k4++) {
      float w0 = C1t[(size_t)(k4 * 4 + 0) * 128 + o];
      float w1 = C1t[(size_t)(k4 * 4 + 1) * 128 + o];
      float w2 = C1t[(size_t)(k4 * 4 + 2) * 128 + o];
      float w3 = C1t[(size_t)(k4 * 4 + 3) * 128 + o];
      float4 f0 = *(const float4*)(f0p + k4 * 4);
      float4 f1 = *(const float4*)(f1p + k4 * 4);
      float4 f2 = *(const float4*)(f2p + k4 * 4);
      float4 f3 = *(const float4*)(f3p + k4 * 4);
      a0 = fmaf(w0, f0.x, a0); a0 = fmaf(w1, f0.y, a0);
      a0 = fmaf(w2, f0.z, a0); a0 = fmaf(w3, f0.w, a0);
      a1 = fmaf(w0, f1.x, a1); a1 = fmaf(w1, f1.y, a1);
      a1 = fmaf(w2, f1.z, a1); a1 = fmaf(w3, f1.w, a1);
      a2 = fmaf(w0, f2.x, a2); a2 = fmaf(w1, f2.y, a2);
      a2 = fmaf(w2, f2.z, a2); a2 = fmaf(w3, f2.w, a2);
      a3 = fmaf(w0, f3.x, a3); a3 = fmaf(w1, f3.y, a3);
      a3 = fmaf(w2, f3.z, a3); a3 = fmaf(w3, f3.w, a3);
    }
    float bb = c1b[o];
    h1[(rg * 4 + 0) * 128 + o] = fmaxf(a0 + bb, 0.f);
    h1[(rg * 4 + 1) * 128 + o] = fmaxf(a1 + bb, 0.f);
    h1[(rg * 4 + 2) * 128 + o] = fmaxf(a2 + bb, 0.f);
    h1[(rg * 4 + 3) * 128 + o] = fmaxf(a3 + bb, 0.f);
  }
  __syncthreads();
  // L2: 128 -> 64 relu
  {
    const int o = tid & 63, rg = tid >> 6;
    const float* f0p = h1 + (rg * 2 + 0) * 128;
    const float* f1p = h1 + (rg * 2 + 1) * 128;
    float a0 = 0.f, a1 = 0.f;
    #pragma unroll 4
    for (int k4 = 0; k4 < 32; k4++) {
      float w0 = g_w2t[(k4 * 4 + 0) * 64 + o];
      float w1 = g_w2t[(k4 * 4 + 1) * 64 + o];
      float w2 = g_w2t[(k4 * 4 + 2) * 64 + o];
      float w3 = g_w2t[(k4 * 4 + 3) * 64 + o];
      float4 f0 = *(const float4*)(f0p + k4 * 4);
      float4 f1 = *(const float4*)(f1p + k4 * 4);
      a0 = fmaf(w0, f0.x, a0); a0 = fmaf(w1, f0.y, a0);
      a0 = fmaf(w2, f0.z, a0); a0 = fmaf(w3, f0.w, a0);
      a1 = fmaf(w0, f1.x, a1); a1 = fmaf(w1, f1.y, a1);
      a1 = fmaf(w2, f1.z, a1); a1 = fmaf(w3, f1.w, a1);
    }
    float bb = g_b2[o];
    h2[(rg * 2 + 0) * 64 + o] = fmaxf(a0 + bb, 0.f);
    h2[(rg * 2 + 1) * 64 + o] = fmaxf(a1 + bb, 0.f);
  }
  __syncthreads();
  // L3: 64 -> 32 relu
  {
    const int o = tid & 31, rg = tid >> 5;
    const float* fp = h2 + rg * 64;
    float a = 0.f;
    #pragma unroll 4
    for (int k4 = 0; k4 < 16; k4++) {
      float w0 = g_w3t[(k4 * 4 + 0) * 32 + o];
      float w1 = g_w3t[(k4 * 4 + 1) * 32 + o];
      float w2 = g_w3t[(k4 * 4 + 2) * 32 + o];
      float w3 = g_w3t[(k4 * 4 + 3) * 32 + o];
      float4 f0 = *(const float4*)(fp + k4 * 4);
      a = fmaf(w0, f0.x, a); a = fmaf(w1, f0.y, a);
      a = fmaf(w2, f0.z, a); a = fmaf(w3, f0.w, a);
    }
    h3[rg * 32 + o] = fmaxf(a + g_b3[o], 0.f);
  }
  __syncthreads();
  // L4: 32 -> 4 logits
  if (tid < 32) {
    int r = tid >> 2, o = tid & 3;
    const float* hh = h3 + r * 32;
    float a = g_b4[o];
    #pragma unroll
    for (int k = 0; k < 32; k++) a = fmaf(g_w4t[k * 4 + o], hh[k], a);
    lg[tid] = a;
  }
  __syncthreads();
  if (tid < 8) {
    float l0 = lg[tid * 4 + 0], l1 = lg[tid * 4 + 1];
    float l2 = lg[tid * 4 + 2], l3 = lg[tid * 4 + 3];
    float m = fmaxf(fmaxf(l0, l1), fmaxf(l2, l3));
    float e0 = __expf(l0 - m), e1 = __expf(l1 - m);
    float e2 = __expf(l2 - m), e3 = __expf(l3 - m);
    float is = __builtin_amdgcn_rcpf(e0 + e1 + e2 + e3);
    float4 o4; o4.x = e0 * is; o4.y = e1 * is; o4.z = e2 * is; o4.w = e3 * is;
    *(float4*)(out + (size_t)(b0 + tid) * 4) = o4;
  }
}

// ---------------------------------------------------------------------------
extern "C" void kernel_launch(void* const* d_in, const int* in_sizes, int n_in,
                              void* d_out, int out_size, void* d_ws, size_t ws_size,
                              hipStream_t stream) {
  const int*   x     = (const int*)d_in[0];
  const float* emb   = (const float*)d_in[1];
  const float* wih_f = (const float*)d_in[2];
  const float* whh_f = (const float*)d_in[3];
  const float* bih_f = (const float*)d_in[4];
  const float* bhh_f = (const float*)d_in[5];
  const float* wih_r = (const float*)d_in[6];
  const float* whh_r = (const float*)d_in[7];
  const float* bih_r = (const float*)d_in[8];
  const float* bhh_r = (const float*)d_in[9];
  const float* e_w1 = (const float*)d_in[10]; const float* e_b1 = (const float*)d_in[11];
  const float* e_w2 = (const float*)d_in[12]; const float* e_b2 = (const float*)d_in[13];
  const float* l_w1 = (const float*)d_in[14]; const float* l_b1 = (const float*)d_in[15];
  const float* l_w2 = (const float*)d_in[16]; const float* l_b2 = (const float*)d_in[17];
  const float* c_w1 = (const float*)d_in[18]; const float* c_b1 = (const float*)d_in[19];
  const float* c_w2 = (const float*)d_in[20]; const float* c_b2 = (const float*)d_in[21];
  const float* p_w1 = (const float*)d_in[22]; const float* p_b1 = (const float*)d_in[23];
  const float* p_w2 = (const float*)d_in[24]; const float* p_b2 = (const float*)d_in[25];
  const float* x_w1 = (const float*)d_in[26]; const float* x_b1 = (const float*)d_in[27];
  const float* x_w2 = (const float*)d_in[28]; const float* x_b2 = (const float*)d_in[29];
  const float* fp_w = (const float*)d_in[30]; const float* fp_b = (const float*)d_in[31];
  const float* attn_w = (const float*)d_in[32]; const float* attn_b = (const float*)d_in[33];
  const float* out_w = (const float*)d_in[34]; const float* out_b = (const float*)d_in[35];
  const float* g_w1 = (const float*)d_in[36]; const float* g_b1 = (const float*)d_in[37];
  const float* g_w2 = (const float*)d_in[38]; const float* g_b2 = (const float*)d_in[39];
  const float* g_w3 = (const float*)d_in[40]; const float* g_b3 = (const float*)d_in[41];
  const float* g_w4 = (const float*)d_in[42]; const float* g_b4 = (const float*)d_in[43];

  float* ws   = (float*)d_ws;
  float* G_f  = ws;                       // 512*256
  float* G_r  = G_f  + 512 * 256;
  float* hfw  = G_r  + 512 * 256;         // B*64
  float* hrw  = hfw  + BATCH * 64;
  float* entw = hrw  + BATCH * 64;        // B
  float* vlnw = entw + BATCH;
  float* patw = vlnw + BATCH;             // B*6
  float* cpxw = patw + BATCH * 6;         // B*4
  unsigned int* cntw = (unsigned int*)(cpxw + BATCH * 4);  // B*128 uints
  float* Aw   = (float*)(cntw + BATCH * 128);  // 128*184
  float* avbw = Aw + 128 * ADJ;                // 128
  float* Bpw  = avbw + 128;                    // 184*180
  float* vbw  = Bpw + ADJ * 180;               // 184
  float* C1t  = vbw + ADJ;                     // 180*128
  float* c1b  = C1t + 180 * 128;               // 128
  float* g2t  = c1b + 128;                     // 128*64
  float* g3t  = g2t + 128 * 64;                // 64*32
  float* g4t  = g3t + 64 * 32;                 // 32*4
  float* cw1t = g4t + 32 * 4;                  // 512*32
  unsigned short* Wfrag = (unsigned short*)(cw1t + 512 * 32);  // 32768 bf16

  k_mega<<<dim3(1489), dim3(256), 0, stream>>>(
      x, emb, wih_f, bih_f, bhh_f, wih_r, bih_r, bhh_r, whh_f, whh_r,
      g_w1, g_b1, out_w, out_b, attn_w, attn_b, fp_w, fp_b,
      g_w2, g_w3, g_w4, c_w1,
      entw, vlnw, patw, cpxw, cntw, G_f, G_r, Wfrag,
      Aw, avbw, Bpw, vbw, g2t, g3t, g4t, cw1t);
  k_lstm<<<dim3(640), dim3(256), 0, stream>>>(
      x, G_f, G_r, Wfrag, Aw, avbw, Bpw, vbw, C1t, c1b, hfw, hrw);
  k_head<<<dim3(BATCH / 8), dim3(256), 0, stream>>>(
      hfw, hrw, entw, vlnw, patw, cpxw, cntw,
      e_w1, e_b1, e_w2, e_b2, l_w1, l_b1, l_w2, l_b2,
      cw1t, c_b1, c_w2, c_b2, p_w1, p_b1, p_w2, p_b2,
      x_w1, x_b1, x_w2, x_b2, C1t, c1b,
      g2t, g_b2, g3t, g_b3, g4t, g_b4,
      (float*)d_out);
}

// Round 6
// 247.275 us; speedup vs baseline: 5.3876x; 1.0530x over previous
//
#include <hip/hip_runtime.h>

// Problem constants
#define BATCH 4096
#define SEQL  60
#define VOC   512
#define EMBD  128
#define HID   64
#define GATES 256
#define ADJ   184

typedef __attribute__((ext_vector_type(8))) short short8;
typedef __attribute__((ext_vector_type(4))) float f32x4;

__device__ __forceinline__ float sigm(float x) {
  return __builtin_amdgcn_rcpf(1.f + __expf(-x));
}
__device__ __forceinline__ float tanh_(float x) {
  float e = __expf(2.f * x);
  return 1.f - 2.f * __builtin_amdgcn_rcpf(e + 1.f);
}
__device__ __forceinline__ unsigned short f2bf_rne(float f) {
  unsigned int u = __float_as_uint(f);
  unsigned int r = (u + 0x7fffu + ((u >> 16) & 1u)) >> 16;
  return (unsigned short)r;
}
__device__ __forceinline__ unsigned short f2bf(float f) {
  // round-half-up: 2 VALU ops (vs 5 for RNE); <=1/2 ulp extra error on |h|<1
  return (unsigned short)((__float_as_uint(f) + 0x8000u) >> 16);
}
__device__ __forceinline__ float dot4(float4 a, float4 b, float acc) {
  acc = fmaf(a.x, b.x, acc); acc = fmaf(a.y, b.y, acc);
  acc = fmaf(a.z, b.z, acc); acc = fmaf(a.w, b.w, acc);
  return acc;
}
__device__ __forceinline__ float wsumf(float v) {
  #pragma unroll
  for (int s = 32; s > 0; s >>= 1) v += __shfl_xor(v, s, 64);
  return v;
}
__device__ __forceinline__ int wsumi(int v) {
  #pragma unroll
  for (int s = 32; s > 0; s >>= 1) v += __shfl_xor(v, s, 64);
  return v;
}
__device__ __forceinline__ int wmaxi(int v) {
  #pragma unroll
  for (int s = 32; s > 0; s >>= 1) v = max(v, __shfl_xor(v, s, 64));
  return v;
}

// ---------------------------------------------------------------------------
// k_prep: weight-only prep (everything with no dependence on x):
//   [0,128)    G table (interleaved [v][u][4 gates], both dirs)
//   [128,144)  Wfrag (bf16 MFMA B-operand fragments of w_hh)
//   [144,272)  A = g_w1·out_w (+ avb bias fold)
//   [272,456)  B = wv·fp_w    (+ vb bias fold)
//   [456]      transposes g_w2t/g_w3t/g_w4t
//   [457,465)  transpose c_w1 -> c_w1t[512][32], row 0 zeroed (token-0 mask)
// ---------------------------------------------------------------------------
__global__ __launch_bounds__(256) void k_prep(
    const float* __restrict__ emb,
    const float* __restrict__ wih_f, const float* __restrict__ bif, const float* __restrict__ bhf,
    const float* __restrict__ wih_r, const float* __restrict__ bir, const float* __restrict__ bhr,
    const float* __restrict__ whh_f, const float* __restrict__ whh_r,
    const float* __restrict__ g_w1, const float* __restrict__ g_b1,
    const float* __restrict__ out_w, const float* __restrict__ out_b,
    const float* __restrict__ attn_w, const float* __restrict__ attn_b,
    const float* __restrict__ fp_w, const float* __restrict__ fp_b,
    const float* __restrict__ g_w2, const float* __restrict__ g_w3,
    const float* __restrict__ g_w4, const float* __restrict__ c_w1,
    float* __restrict__ G_f, float* __restrict__ G_r,
    unsigned short* __restrict__ Wfrag,
    float* __restrict__ A, float* __restrict__ avb,
    float* __restrict__ Bp, float* __restrict__ vb,
    float* __restrict__ g_w2t, float* __restrict__ g_w3t, float* __restrict__ g_w4t,
    float* __restrict__ c_w1t) {
  const int bid = blockIdx.x;
  const int tid = threadIdx.x;

  if (bid < 128) {
    // ---------------- G table, interleaved [v][u][gg] ----------------
    const int dir = bid >> 6;
    const int rem = bid & 63;
    const int v0 = (rem >> 2) * 32;
    const int j0 = (rem & 3) * 64;
    const float* W = dir ? wih_r : wih_f;
    const float* bi = dir ? bir : bif;
    const float* bh = dir ? bhr : bhf;
    float* G = dir ? G_r : G_f;
    const int vp = tid >> 4;
    const int jq = tid & 15;
    const int v = v0 + vp * 2;
    const int j = j0 + jq * 4;
    const int gg = j >> 6;
    const int u0 = j & 63;

    const float4* E0 = (const float4*)(emb + (size_t)v * 128);
    const float4* E1 = (const float4*)(emb + (size_t)(v + 1) * 128);
    const float4* W0 = (const float4*)(W + (size_t)j * 128);
    const float4* W1 = (const float4*)(W + (size_t)(j + 1) * 128);
    const float4* W2 = (const float4*)(W + (size_t)(j + 2) * 128);
    const float4* W3 = (const float4*)(W + (size_t)(j + 3) * 128);

    float a00 = 0.f, a01 = 0.f, a02 = 0.f, a03 = 0.f;
    float a10 = 0.f, a11 = 0.f, a12 = 0.f, a13 = 0.f;
    #pragma unroll 4
    for (int d4 = 0; d4 < 32; d4++) {
      float4 e0 = E0[d4], e1 = E1[d4];
      float4 w0 = W0[d4], w1 = W1[d4], w2 = W2[d4], w3 = W3[d4];
      a00 = dot4(e0, w0, a00); a01 = dot4(e0, w1, a01);
      a02 = dot4(e0, w2, a02); a03 = dot4(e0, w3, a03);
      a10 = dot4(e1, w0, a10); a11 = dot4(e1, w1, a11);
      a12 = dot4(e1, w2, a12); a13 = dot4(e1, w3, a13);
    }
    float b0v = bi[j] + bh[j], b1v = bi[j + 1] + bh[j + 1];
    float b2v = bi[j + 2] + bh[j + 2], b3v = bi[j + 3] + bh[j + 3];
    float* g0 = G + (size_t)v * 256 + u0 * 4 + gg;
    g0[0]  = a00 + b0v; g0[4]  = a01 + b1v;
    g0[8]  = a02 + b2v; g0[12] = a03 + b3v;
    float* g1 = g0 + 256;
    g1[0]  = a10 + b0v; g1[4]  = a11 + b1v;
    g1[8]  = a12 + b2v; g1[12] = a13 + b3v;
  } else if (bid < 144) {
    // ---------------- w_hh bf16 MFMA B-fragments ----------------
    const int id = (bid - 128) * 256 + tid;
    const int lane = id & 63;
    const int fc = id >> 6;
    const int c = fc & 1;
    const int gg = (fc >> 1) & 3;
    const int w = (fc >> 3) & 3;
    const int dir = fc >> 5;
    const float* whh = dir ? whh_r : whh_f;
    const int n = gg * 64 + w * 16 + (lane & 15);
    const int kb = c * 32 + (lane >> 4) * 8;
    unsigned short* o = Wfrag + (size_t)id * 8;
    #pragma unroll
    for (int j = 0; j < 8; j++) o[j] = f2bf_rne(whh[n * 64 + kb + j]);
  } else if (bid < 272) {
    // ---------------- A = g_w1 · out_w  (128 x 184), avb fold ----------------
    const int i = bid - 144;
    const int j = tid;
    const float* g1r = g_w1 + (size_t)i * ADJ;
    if (j < ADJ) {
      float a0 = 0.f, a1 = 0.f, a2 = 0.f, a3 = 0.f;
      for (int k = 0; k < ADJ; k += 4) {
        a0 = fmaf(g1r[k],     out_w[(size_t)(k)     * ADJ + j], a0);
        a1 = fmaf(g1r[k + 1], out_w[(size_t)(k + 1) * ADJ + j], a1);
        a2 = fmaf(g1r[k + 2], out_w[(size_t)(k + 2) * ADJ + j], a2);
        a3 = fmaf(g1r[k + 3], out_w[(size_t)(k + 3) * ADJ + j], a3);
      }
      A[(size_t)i * ADJ + j] = (a0 + a1) + (a2 + a3);
    } else if (j == ADJ) {
      float a0 = 0.f;
      for (int k = 0; k < ADJ; k++) a0 = fmaf(g1r[k], out_b[k], a0);
      avb[i] = a0 + g_b1[i];
    }
  } else if (bid < 456) {
    // ---------------- B = wv · fp_w  (184 x 180), vb fold ----------------
    const int k = bid - 272;
    const int j = tid;
    const float* wvr = attn_w + (size_t)(2 * ADJ + k) * ADJ;
    if (j < 180) {
      float a0 = 0.f, a1 = 0.f, a2 = 0.f, a3 = 0.f;
      for (int m = 0; m < ADJ; m += 4) {
        a0 = fmaf(wvr[m],     fp_w[(size_t)(m)     * 180 + j], a0);
        a1 = fmaf(wvr[m + 1], fp_w[(size_t)(m + 1) * 180 + j], a1);
        a2 = fmaf(wvr[m + 2], fp_w[(size_t)(m + 2) * 180 + j], a2);
        a3 = fmaf(wvr[m + 3], fp_w[(size_t)(m + 3) * 180 + j], a3);
      }
      Bp[(size_t)k * 180 + j] = (a0 + a1) + (a2 + a3);
    } else if (j == 180) {
      float a0 = 0.f;
      for (int m = 0; m < ADJ; m++) a0 = fmaf(wvr[m], fp_b[m], a0);
      vb[k] = a0 + attn_b[2 * ADJ + k];
    }
  } else if (bid == 456) {
    // ---------------- transposes for the head ----------------
    for (int i = tid; i < 64 * 128; i += 256) {
      int o = i >> 7, k = i & 127;
      g_w2t[k * 64 + o] = g_w2[i];
    }
    for (int i = tid; i < 32 * 64; i += 256) {
      int o = i >> 6, k = i & 63;
      g_w3t[k * 32 + o] = g_w3[i];
    }
    if (tid < 128) {
      int o = tid >> 5, k = tid & 31;
      g_w4t[k * 4 + o] = g_w4[tid];
    }
  } else {
    // -------- transpose c_w1 (32x512) -> c_w1t (512x32), row 0 zeroed --------
    const int base = (bid - 457) * 2048;   // 8 blocks x 2048 = 16384
    for (int i = tid; i < 2048; i += 256) {
      int idx = base + i;
      int o = idx >> 9, k = idx & 511;
      c_w1t[k * 32 + o] = k ? c_w1[o * 512 + k] : 0.f;
    }
  }
}

// ---------------------------------------------------------------------------
// k_main: fused launch.
//   [0,512)      MFMA LSTM recurrence (grid-capped at 8 waves/CU -> the
//                stats blocks below co-schedule into the idle wave slots)
//   [512,1536)   per-row sequence statistics (wave-per-row)
//   [1536,1664)  prep2: C1t = (A·B)^T, c1b fold
// ---------------------------------------------------------------------------
#define LSTM_STEP(T, CUR, NXT)                                                 \
  {                                                                            \
    const unsigned short* hb = hbuf[(T) & 1];                                  \
    short8 a0 = *(const short8*)(hb + ln * 72 + kg * 8);                       \
    short8 a1 = *(const short8*)(hb + ln * 72 + 32 + kg * 8);                  \
    if ((T) < 59) {                                                            \
      int tsn = dir ? (58 - (T)) : ((T) + 1);                                  \
      uint4 of4 = *(const uint4*)(tokoff + tsn * 16 + kg * 4);                 \
      NXT[0] = *(const float4*)(Gb + of4.x + ub);                              \
      NXT[1] = *(const float4*)(Gb + of4.y + ub);                              \
      NXT[2] = *(const float4*)(Gb + of4.z + ub);                              \
      NXT[3] = *(const float4*)(Gb + of4.w + ub);                              \
    }                                                                          \
    f32x4 z0 = {0.f, 0.f, 0.f, 0.f};                                           \
    f32x4 acc0 = z0, acc1 = z0, acc2 = z0, acc3 = z0;                          \
    acc0 = __builtin_amdgcn_mfma_f32_16x16x32_bf16(a0, bfr[0][0], acc0, 0, 0, 0); \
    acc1 = __builtin_amdgcn_mfma_f32_16x16x32_bf16(a0, bfr[1][0], acc1, 0, 0, 0); \
    acc2 = __builtin_amdgcn_mfma_f32_16x16x32_bf16(a0, bfr[2][0], acc2, 0, 0, 0); \
    acc3 = __builtin_amdgcn_mfma_f32_16x16x32_bf16(a0, bfr[3][0], acc3, 0, 0, 0); \
    acc0 = __builtin_amdgcn_mfma_f32_16x16x32_bf16(a1, bfr[0][1], acc0, 0, 0, 0); \
    acc1 = __builtin_amdgcn_mfma_f32_16x16x32_bf16(a1, bfr[1][1], acc1, 0, 0, 0); \
    acc2 = __builtin_amdgcn_mfma_f32_16x16x32_bf16(a1, bfr[2][1], acc2, 0, 0, 0); \
    acc3 = __builtin_amdgcn_mfma_f32_16x16x32_bf16(a1, bfr[3][1], acc3, 0, 0, 0); \
    unsigned short* hw = hbuf[((T) + 1) & 1];                                  \
    _Pragma("unroll")                                                          \
    for (int r = 0; r < 4; r++) {                                              \
      float gi = acc0[r] + CUR[r].x;                                           \
      float gf = acc1[r] + CUR[r].y;                                           \
      float gc = acc2[r] + CUR[r].z;                                           \
      float go = acc3[r] + CUR[r].w;                                           \
      float cn = sigm(gf) * cst[r] + sigm(gi) * tanh_(gc);                     \
      cst[r] = cn;                                                             \
      float h = sigm(go) * tanh_(cn);                                          \
      hw[(kg * 4 + r) * 72 + u] = f2bf(h);                                     \
      if ((T) == 59) ho[(size_t)(b0 + kg * 4 + r) * 64 + u] = h;               \
    }                                                                          \
    __syncthreads();                                                           \
  }

__global__ __launch_bounds__(256) void k_main(
    const int* __restrict__ x,
    const float* __restrict__ G_f, const float* __restrict__ G_r,
    const unsigned short* __restrict__ Wfrag,
    const float* __restrict__ A, const float* __restrict__ avb,
    const float* __restrict__ Bp, const float* __restrict__ vb,
    float* __restrict__ C1t, float* __restrict__ c1b,
    float* __restrict__ hf_o, float* __restrict__ hr_o,
    float* __restrict__ ent_o, float* __restrict__ vlen_o,
    float* __restrict__ pat_o, float* __restrict__ cpx_o) {
  __shared__ __align__(16) unsigned short hbuf[2][16 * 72];
  __shared__ __align__(16) unsigned int tokoff[60 * 16];
  __shared__ unsigned int cnt[4][512];
  __shared__ unsigned short q[4][68];
  const int bid = blockIdx.x;
  const int tid = threadIdx.x;

  if (bid < 512) {
    // ======================= LSTM recurrence =======================
    const int lane = tid & 63;
    const int w = tid >> 6;
    const int dir = bid >> 8;
    const int blk = bid & 255;
    const int b0 = blk << 4;
    const float* G = dir ? G_r : G_f;
    const char* Gb = (const char*)G;
    float* ho = dir ? hr_o : hf_o;

    for (int i = tid; i < 960; i += 256) {
      int r = i / 60, t = i - r * 60;
      tokoff[t * 16 + r] = ((unsigned int)x[(size_t)(b0 + r) * 60 + t]) << 10;
    }
    for (int i = tid; i < 16 * 72; i += 256) hbuf[0][i] = 0;

    short8 bfr[4][2];
    #pragma unroll
    for (int gg = 0; gg < 4; gg++)
      #pragma unroll
      for (int c = 0; c < 2; c++) {
        int idx = (((dir * 4 + w) * 4 + gg) * 2 + c) * 64 + lane;
        bfr[gg][c] = *(const short8*)(Wfrag + (size_t)idx * 8);
      }

    const int kg = lane >> 4;
    const int ln = lane & 15;
    const int u = w * 16 + ln;
    const unsigned int ub = (unsigned int)u * 16;
    float cst[4] = {0.f, 0.f, 0.f, 0.f};
    float4 gvA[4], gvB[4];

    __syncthreads();

    {
      int ts0 = dir ? 59 : 0;
      uint4 of4 = *(const uint4*)(tokoff + ts0 * 16 + kg * 4);
      gvA[0] = *(const float4*)(Gb + of4.x + ub);
      gvA[1] = *(const float4*)(Gb + of4.y + ub);
      gvA[2] = *(const float4*)(Gb + of4.z + ub);
      gvA[3] = *(const float4*)(Gb + of4.w + ub);
    }

    #pragma unroll 1
    for (int tt = 0; tt < 30; tt++) {
      const int t0 = tt * 2, t1 = tt * 2 + 1;
      LSTM_STEP(t0, gvA, gvB)
      LSTM_STEP(t1, gvB, gvA)
    }
  } else if (bid < 1536) {
    // ======================= sequence statistics =======================
    const int lane = tid & 63;
    const int wid = tid >> 6;
    const int row = (bid - 512) * 4 + wid;
    unsigned int* cr = cnt[wid];
    unsigned short* qr = q[wid];

    for (int i = lane; i < 512; i += 64) cr[i] = 0u;
    qr[lane] = 0;
    if (lane < 4) qr[64 + lane] = 0;
    int v = (lane < 60) ? x[row * 60 + lane] : 0;
    bool act = (v != 0);
    unsigned long long amask = __ballot(act);
    int n = __popcll(amask);
    __syncthreads();
    if (act) {
      int pos = __popcll(amask & ((1ull << lane) - 1ull));
      qr[pos] = (unsigned short)v;
      atomicAdd(&cr[v], 1u);
    }
    __syncthreads();

    float vlenf = (float)(n >= 1 ? n : 1);
    float inv = 1.f / vlenf;

    float ent = 0.f; int distinct = 0;
    #pragma unroll
    for (int j = 0; j < 8; j++) {
      unsigned int c = cr[lane + j * 64];
      if (c) {
        distinct++;
        float p = (float)c * inv;
        ent -= p * __logf(p + 1e-8f);
      }
    }
    ent = wsumf(ent);
    distinct = wsumi(distinct);

    int a = qr[lane], b = qr[lane + 1], c2 = qr[lane + 2];
    bool v1 = (lane + 1 < n);
    bool v2 = (lane + 2 < n);
    int rep  = __popcll(__ballot(v1 && (a == b)));
    int incs = __popcll(__ballot(v1 && (b > a)));
    int decs = __popcll(__ballot(v1 && (b < a)));
    int per2 = __popcll(__ballot(v2 && (a == c2)));

    int prev = (lane > 0) ? (int)qr[lane - 1] : -1;
    bool isst = (lane < n) && (lane == 0 || a != prev);
    unsigned long long smask = __ballot(isst);
    int len = 0;
    if (isst) {
      unsigned long long hi = (lane < 63) ? (smask >> (lane + 1)) : 0ull;
      int next = hi ? (lane + __ffsll((unsigned long long)hi)) : n;
      len = next - lane;
    }
    int maxrun = wmaxi(len);

    int code = v1 ? (a * VOC + b) : -1;
    int unique = v1 ? 1 : 0;
    #pragma unroll 1
    for (int j = 0; j < 58; j++) {
      int cj = __shfl(code, j, 64);
      if (j < lane && cj == code) unique = 0;
    }
    int dc = __popcll(__ballot(unique != 0));

    int wl = n >> 1; if (wl > 5) wl = 5;
    float local = 0.f;
    if (wl >= 2) {
      bool pv = (lane + wl <= n);
      int u = 0;
      if (pv) {
        int t0 = qr[lane], t1 = qr[lane + 1], t2 = qr[lane + 2];
        int t3 = qr[lane + 3], t4 = qr[lane + 4];
        u = 1;
        u += (t1 != t0);
        if (wl >= 3) u += (int)((t2 != t1) && (t2 != t0));
        if (wl >= 4) u += (int)((t3 != t2) && (t3 != t1) && (t3 != t0));
        if (wl >= 5) u += (int)((t4 != t3) && (t4 != t2) && (t4 != t1) && (t4 != t0));
      }
      int usum = wsumi(u);
      int denw = n - wl + 1; if (denw < 1) denw = 1;
      local = (float)usum / (float)wl / (float)denw;
    }

    float den1 = (float)((n - 1) >= 1 ? (n - 1) : 1);
    float repeat = (float)rep / den1;
    float per = (n >= 4) ? (float)per2 / (float)((n - 2) >= 1 ? (n - 2) : 1) : 0.f;
    float entz = (n > 1) ? ent : 0.f;
    float z = (n > 1) ? 1.f : 0.f;

    if (lane == 0) {
      ent_o[row] = entz;
      vlen_o[row] = (float)n;
      pat_o[row * 6 + 0] = repeat * z;
      pat_o[row * 6 + 1] = (float)incs / den1 * z;
      pat_o[row * 6 + 2] = (float)decs / den1 * z;
      pat_o[row * 6 + 3] = per * z;
      pat_o[row * 6 + 4] = (float)distinct * inv * z;
      pat_o[row * 6 + 5] = (float)maxrun * inv * z;
      cpx_o[row * 4 + 0] = (float)dc / den1 * z;
      cpx_o[row * 4 + 1] = entz / __logf((float)(n >= 2 ? n : 2)) * z;
      cpx_o[row * 4 + 2] = local * z;
      cpx_o[row * 4 + 3] = (1.f - repeat) * z;
    }
  } else {
    // ======================= prep2 (head collapse) =======================
    const int i = bid - 1536, j = tid;
    const float* Ar = A + (size_t)i * ADJ;
    if (j < 180) {
      float a0 = 0.f, a1 = 0.f, a2 = 0.f, a3 = 0.f;
      for (int k = 0; k < ADJ; k += 4) {
        a0 = fmaf(Ar[k],     Bp[(size_t)(k)     * 180 + j], a0);
        a1 = fmaf(Ar[k + 1], Bp[(size_t)(k + 1) * 180 + j], a1);
        a2 = fmaf(Ar[k + 2], Bp[(size_t)(k + 2) * 180 + j], a2);
        a3 = fmaf(Ar[k + 3], Bp[(size_t)(k + 3) * 180 + j], a3);
      }
      C1t[(size_t)j * 128 + i] = (a0 + a1) + (a2 + a3);
    } else if (j == 180) {
      float a0 = 0.f;
      for (int k = 0; k < ADJ; k++) a0 = fmaf(Ar[k], vb[k], a0);
      c1b[i] = a0 + avb[i];
    }
  }
}

// ---------------------------------------------------------------------------
// k_head: feature assembly + collapsed head. c-MLP L1 is a sparse gather:
// counts·W == sum_t W[x_t] (row 0 of c_w1t zeroed), 60 gathers vs 512 streams.
// 512 blocks x 256 threads, 8 rows/block.
// ---------------------------------------------------------------------------
#define FSTR 192

__global__ __launch_bounds__(256) void k_head(
    const int* __restrict__ x,
    const float* __restrict__ hf, const float* __restrict__ hr,
    const float* __restrict__ ent, const float* __restrict__ vlen,
    const float* __restrict__ pat, const float* __restrict__ cpx,
    const float* __restrict__ e_w1, const float* __restrict__ e_b1,
    const float* __restrict__ e_w2, const float* __restrict__ e_b2,
    const float* __restrict__ l_w1, const float* __restrict__ l_b1,
    const float* __restrict__ l_w2, const float* __restrict__ l_b2,
    const float* __restrict__ c_w1t, const float* __restrict__ c_b1,
    const float* __restrict__ c_w2, const float* __restrict__ c_b2,
    const float* __restrict__ p_w1, const float* __restrict__ p_b1,
    const float* __restrict__ p_w2, const float* __restrict__ p_b2,
    const float* __restrict__ x_w1, const float* __restrict__ x_b1,
    const float* __restrict__ x_w2, const float* __restrict__ x_b2,
    const float* __restrict__ C1t, const float* __restrict__ c1b,
    const float* __restrict__ g_w2t, const float* __restrict__ g_b2,
    const float* __restrict__ g_w3t, const float* __restrict__ g_b3,
    const float* __restrict__ g_w4t, const float* __restrict__ g_b4,
    float* __restrict__ out) {
  __shared__ float feat[8 * FSTR];
  __shared__ unsigned short tk[8 * 64];
  __shared__ float h1[8 * 128];
  __shared__ float h2[8 * 64];
  __shared__ float h3[8 * 32];
  __shared__ float h1c[8 * 33];
  __shared__ float lg[32];
  const int tid = threadIdx.x;
  const int b0 = blockIdx.x * 8;

  // h_f / h_r -> feat[0:128)
  if (tid < 128) {
    int r = tid >> 4, c = tid & 15;
    float4 vv = ((const float4*)(hf + (size_t)(b0 + r) * 64))[c];
    *(float4*)(feat + r * FSTR + c * 4) = vv;
  } else {
    int t = tid - 128;
    int r = t >> 4, c = t & 15;
    float4 vv = ((const float4*)(hr + (size_t)(b0 + r) * 64))[c];
    *(float4*)(feat + r * FSTR + 64 + c * 4) = vv;
  }
  // tokens -> LDS (8 rows x 60)
  for (int i = tid; i < 480; i += 256) {
    int r = i / 60, t = i - r * 60;
    tk[r * 64 + t] = (unsigned short)x[(size_t)(b0 + r) * 60 + t];
  }
  __syncthreads();
  // c-MLP layer 1 sparse: o = tid&31 (coalesced gather), r = tid>>5
  {
    int o = tid & 31, r = tid >> 5;
    const unsigned short* tkr = tk + r * 64;
    float a0 = 0.f, a1 = 0.f, a2 = 0.f, a3 = 0.f;
    #pragma unroll 5
    for (int t = 0; t < 60; t += 4) {
      int t0 = tkr[t], t1 = tkr[t + 1], t2 = tkr[t + 2], t3 = tkr[t + 3];
      a0 += c_w1t[t0 * 32 + o];
      a1 += c_w1t[t1 * 32 + o];
      a2 += c_w1t[t2 * 32 + o];
      a3 += c_w1t[t3 * 32 + o];
    }
    float invv = __builtin_amdgcn_rcpf(fmaxf(vlen[b0 + r], 1.f));
    h1c[r * 33 + o] = fmaxf(((a0 + a1) + (a2 + a3)) * invv + c_b1[o], 0.f);
  }
  __syncthreads();
  // small MLPs (threads 0..31) + c-MLP layer 2 (threads 64..191)
  if (tid < 32) {
    const int m = tid & 3, r = tid >> 2, b = b0 + r;
    float tt[24];
    if (m == 0) {
      float ein = ent[b] * 0.25f;
      #pragma unroll
      for (int o = 0; o < 16; o++) tt[o] = fmaxf(e_w1[o] * ein + e_b1[o], 0.f);
      #pragma unroll
      for (int o = 0; o < 8; o++) {
        float a = e_b2[o];
        #pragma unroll
        for (int k = 0; k < 16; k++) a = fmaf(e_w2[o * 16 + k], tt[k], a);
        feat[r * FSTR + 128 + o] = a;
      }
    } else if (m == 1) {
      float lin = vlen[b] * (1.f / 60.f);
      #pragma unroll
      for (int o = 0; o < 16; o++) tt[o] = fmaxf(l_w1[o] * lin + l_b1[o], 0.f);
      #pragma unroll
      for (int o = 0; o < 8; o++) {
        float a = l_b2[o];
        #pragma unroll
        for (int k = 0; k < 16; k++) a = fmaf(l_w2[o * 16 + k], tt[k], a);
        feat[r * FSTR + 136 + o] = a;
      }
    } else if (m == 2) {
      float pin[6];
      #pragma unroll
      for (int k = 0; k < 6; k++) pin[k] = pat[b * 6 + k];
      #pragma unroll
      for (int o = 0; o < 24; o++) {
        float a = p_b1[o];
        #pragma unroll
        for (int k = 0; k < 6; k++) a = fmaf(p_w1[o * 6 + k], pin[k], a);
        tt[o] = fmaxf(a, 0.f);
      }
      #pragma unroll
      for (int o = 0; o < 12; o++) {
        float a = p_b2[o];
        #pragma unroll
        for (int k = 0; k < 24; k++) a = fmaf(p_w2[o * 24 + k], tt[k], a);
        feat[r * FSTR + 160 + o] = a;
      }
    } else {
      float xin[4];
      #pragma unroll
      for (int k = 0; k < 4; k++) xin[k] = cpx[b * 4 + k];
      #pragma unroll
      for (int o = 0; o < 16; o++) {
        float a = x_b1[o];
        #pragma unroll
        for (int k = 0; k < 4; k++) a = fmaf(x_w1[o * 4 + k], xin[k], a);
        tt[o] = fmaxf(a, 0.f);
      }
      #pragma unroll
      for (int o = 0; o < 8; o++) {
        float a = x_b2[o];
        #pragma unroll
        for (int k = 0; k < 16; k++) a = fmaf(x_w2[o * 16 + k], tt[k], a);
        feat[r * FSTR + 172 + o] = a;
      }
    }
  } else if (tid >= 64 && tid < 192) {
    int t = tid - 64;
    int r = t >> 4, o = t & 15;
    float a = c_b2[o];
    const float* hh = h1c + r * 33;
    #pragma unroll
    for (int k = 0; k < 32; k++) a = fmaf(c_w2[o * 32 + k], hh[k], a);
    feat[r * FSTR + 144 + o] = a;
  }
  __syncthreads();

  // L1: 180 -> 128 relu. C1t lane-coalesced, feat b128 broadcasts.
  {
    const int o = tid & 127, rg = tid >> 7;
    const float* f0p = feat + (rg * 4 + 0) * FSTR;
    const float* f1p = feat + (rg * 4 + 1) * FSTR;
    const float* f2p = feat + (rg * 4 + 2) * FSTR;
    const float* f3p = feat + (rg * 4 + 3) * FSTR;
    float a0 = 0.f, a1 = 0.f, a2 = 0.f, a3 = 0.f;
    #pragma unroll 3
    for (int k4 = 0; k4 < 45; k4++) {
      float w0 = C1t[(size_t)(k4 * 4 + 0) * 128 + o];
      float w1 = C1t[(size_t)(k4 * 4 + 1) * 128 + o];
      float w2 = C1t[(size_t)(k4 * 4 + 2) * 128 + o];
      float w3 = C1t[(size_t)(k4 * 4 + 3) * 128 + o];
      float4 f0 = *(const float4*)(f0p + k4 * 4);
      float4 f1 = *(const float4*)(f1p + k4 * 4);
      float4 f2 = *(const float4*)(f2p + k4 * 4);
      float4 f3 = *(const float4*)(f3p + k4 * 4);
      a0 = fmaf(w0, f0.x, a0); a0 = fmaf(w1, f0.y, a0);
      a0 = fmaf(w2, f0.z, a0); a0 = fmaf(w3, f0.w, a0);
      a1 = fmaf(w0, f1.x, a1); a1 = fmaf(w1, f1.y, a1);
      a1 = fmaf(w2, f1.z, a1); a1 = fmaf(w3, f1.w, a1);
      a2 = fmaf(w0, f2.x, a2); a2 = fmaf(w1, f2.y, a2);
      a2 = fmaf(w2, f2.z, a2); a2 = fmaf(w3, f2.w, a2);
      a3 = fmaf(w0, f3.x, a3); a3 = fmaf(w1, f3.y, a3);
      a3 = fmaf(w2, f3.z, a3); a3 = fmaf(w3, f3.w, a3);
    }
    float bb = c1b[o];
    h1[(rg * 4 + 0) * 128 + o] = fmaxf(a0 + bb, 0.f);
    h1[(rg * 4 + 1) * 128 + o] = fmaxf(a1 + bb, 0.f);
    h1[(rg * 4 + 2) * 128 + o] = fmaxf(a2 + bb, 0.f);
    h1[(rg * 4 + 3) * 128 + o] = fmaxf(a3 + bb, 0.f);
  }
  __syncthreads();
  // L2: 128 -> 64 relu
  {
    const int o = tid & 63, rg = tid >> 6;
    const float* f0p = h1 + (rg * 2 + 0) * 128;
    const float* f1p = h1 + (rg * 2 + 1) * 128;
    float a0 = 0.f, a1 = 0.f;
    #pragma unroll 4
    for (int k4 = 0; k4 < 32; k4++) {
      float w0 = g_w2t[(k4 * 4 + 0) * 64 + o];
      float w1 = g_w2t[(k4 * 4 + 1) * 64 + o];
      float w2 = g_w2t[(k4 * 4 + 2) * 64 + o];
      float w3 = g_w2t[(k4 * 4 + 3) * 64 + o];
      float4 f0 = *(const float4*)(f0p + k4 * 4);
      float4 f1 = *(const float4*)(f1p + k4 * 4);
      a0 = fmaf(w0, f0.x, a0); a0 = fmaf(w1, f0.y, a0);
      a0 = fmaf(w2, f0.z, a0); a0 = fmaf(w3, f0.w, a0);
      a1 = fmaf(w0, f1.x, a1); a1 = fmaf(w1, f1.y, a1);
      a1 = fmaf(w2, f1.z, a1); a1 = fmaf(w3, f1.w, a1);
    }
    float bb = g_b2[o];
    h2[(rg * 2 + 0) * 64 + o] = fmaxf(a0 + bb, 0.f);
    h2[(rg * 2 + 1) * 64 + o] = fmaxf(a1 + bb, 0.f);
  }
  __syncthreads();
  // L3: 64 -> 32 relu
  {
    const int o = tid & 31, rg = tid >> 5;
    const float* fp = h2 + rg * 64;
    float a = 0.f;
    #pragma unroll 4
    for (int k4 = 0; k4 < 16; k4++) {
      float w0 = g_w3t[(k4 * 4 + 0) * 32 + o];
      float w1 = g_w3t[(k4 * 4 + 1) * 32 + o];
      float w2 = g_w3t[(k4 * 4 + 2) * 32 + o];
      float w3 = g_w3t[(k4 * 4 + 3) * 32 + o];
      float4 f0 = *(const float4*)(fp + k4 * 4);
      a = fmaf(w0, f0.x, a); a = fmaf(w1, f0.y, a);
      a = fmaf(w2, f0.z, a); a = fmaf(w3, f0.w, a);
    }
    h3[rg * 32 + o] = fmaxf(a + g_b3[o], 0.f);
  }
  __syncthreads();
  // L4: 32 -> 4 logits
  if (tid < 32) {
    int r = tid >> 2, o = tid & 3;
    const float* hh = h3 + r * 32;
    float a = g_b4[o];
    #pragma unroll
    for (int k = 0; k < 32; k++) a = fmaf(g_w4t[k * 4 + o], hh[k], a);
    lg[tid] = a;
  }
  __syncthreads();
  if (tid < 8) {
    float l0 = lg[tid * 4 + 0], l1 = lg[tid * 4 + 1];
    float l2 = lg[tid * 4 + 2], l3 = lg[tid * 4 + 3];
    float m = fmaxf(fmaxf(l0, l1), fmaxf(l2, l3));
    float e0 = __expf(l0 - m), e1 = __expf(l1 - m);
    float e2 = __expf(l2 - m), e3 = __expf(l3 - m);
    float is = __builtin_amdgcn_rcpf(e0 + e1 + e2 + e3);
    float4 o4; o4.x = e0 * is; o4.y = e1 * is; o4.z = e2 * is; o4.w = e3 * is;
    *(float4*)(out + (size_t)(b0 + tid) * 4) = o4;
  }
}

// ---------------------------------------------------------------------------
extern "C" void kernel_launch(void* const* d_in, const int* in_sizes, int n_in,
                              void* d_out, int out_size, void* d_ws, size_t ws_size,
                              hipStream_t stream) {
  const int*   x     = (const int*)d_in[0];
  const float* emb   = (const float*)d_in[1];
  const float* wih_f = (const float*)d_in[2];
  const float* whh_f = (const float*)d_in[3];
  const float* bih_f = (const float*)d_in[4];
  const float* bhh_f = (const float*)d_in[5];
  const float* wih_r = (const float*)d_in[6];
  const float* whh_r = (const float*)d_in[7];
  const float* bih_r = (const float*)d_in[8];
  const float* bhh_r = (const float*)d_in[9];
  const float* e_w1 = (const float*)d_in[10]; const float* e_b1 = (const float*)d_in[11];
  const float* e_w2 = (const float*)d_in[12]; const float* e_b2 = (const float*)d_in[13];
  const float* l_w1 = (const float*)d_in[14]; const float* l_b1 = (const float*)d_in[15];
  const float* l_w2 = (const float*)d_in[16]; const float* l_b2 = (const float*)d_in[17];
  const float* c_w1 = (const float*)d_in[18]; const float* c_b1 = (const float*)d_in[19];
  const float* c_w2 = (const float*)d_in[20]; const float* c_b2 = (const float*)d_in[21];
  const float* p_w1 = (const float*)d_in[22]; const float* p_b1 = (const float*)d_in[23];
  const float* p_w2 = (const float*)d_in[24]; const float* p_b2 = (const float*)d_in[25];
  const float* x_w1 = (const float*)d_in[26]; const float* x_b1 = (const float*)d_in[27];
  const float* x_w2 = (const float*)d_in[28]; const float* x_b2 = (const float*)d_in[29];
  const float* fp_w = (const float*)d_in[30]; const float* fp_b = (const float*)d_in[31];
  const float* attn_w = (const float*)d_in[32]; const float* attn_b = (const float*)d_in[33];
  const float* out_w = (const float*)d_in[34]; const float* out_b = (const float*)d_in[35];
  const float* g_w1 = (const float*)d_in[36]; const float* g_b1 = (const float*)d_in[37];
  const float* g_w2 = (const float*)d_in[38]; const float* g_b2 = (const float*)d_in[39];
  const float* g_w3 = (const float*)d_in[40]; const float* g_b3 = (const float*)d_in[41];
  const float* g_w4 = (const float*)d_in[42]; const float* g_b4 = (const float*)d_in[43];

  float* ws   = (float*)d_ws;
  float* G_f  = ws;                       // 512*256
  float* G_r  = G_f  + 512 * 256;
  float* hfw  = G_r  + 512 * 256;         // B*64
  float* hrw  = hfw  + BATCH * 64;
  float* entw = hrw  + BATCH * 64;        // B
  float* vlnw = entw + BATCH;
  float* patw = vlnw + BATCH;             // B*6
  float* cpxw = patw + BATCH * 6;         // B*4
  float* Aw   = cpxw + BATCH * 4;         // 128*184
  float* avbw = Aw + 128 * ADJ;           // 128
  float* Bpw  = avbw + 128;               // 184*180
  float* vbw  = Bpw + ADJ * 180;          // 184
  float* C1t  = vbw + ADJ;                // 180*128
  float* c1b  = C1t + 180 * 128;          // 128
  float* g2t  = c1b + 128;                // 128*64
  float* g3t  = g2t + 128 * 64;           // 64*32
  float* g4t  = g3t + 64 * 32;            // 32*4
  float* cw1t = g4t + 32 * 4;             // 512*32
  unsigned short* Wfrag = (unsigned short*)(cw1t + 512 * 32);  // 32768 bf16

  k_prep<<<dim3(465), dim3(256), 0, stream>>>(
      emb, wih_f, bih_f, bhh_f, wih_r, bih_r, bhh_r, whh_f, whh_r,
      g_w1, g_b1, out_w, out_b, attn_w, attn_b, fp_w, fp_b,
      g_w2, g_w3, g_w4, c_w1,
      G_f, G_r, Wfrag, Aw, avbw, Bpw, vbw, g2t, g3t, g4t, cw1t);
  k_main<<<dim3(1664), dim3(256), 0, stream>>>(
      x, G_f, G_r, Wfrag, Aw, avbw, Bpw, vbw, C1t, c1b,
      hfw, hrw, entw, vlnw, patw, cpxw);
  k_head<<<dim3(BATCH / 8), dim3(256), 0, stream>>>(
      x, hfw, hrw, entw, vlnw, patw, cpxw,
      e_w1, e_b1, e_w2, e_b2, l_w1, l_b1, l_w2, l_b2,
      cw1t, c_b1, c_w2, c_b2, p_w1, p_b1, p_w2, p_b2,
      x_w1, x_b1, x_w2, x_b2, C1t, c1b,
      g2t, g_b2, g3t, g_b3, g4t, g_b4,
      (float*)d_out);
}